// Round 2
// baseline (58880.499 us; speedup 1.0000x reference)
//
#include <hip/hip_runtime.h>
#include <hip/hip_bf16.h>
#include <math.h>

// ---------------- problem constants ----------------
#define BB   8
#define CH   32
#define TT   504
#define FFp  168      // padded F
#define OF   161      // original F
#define KSZ  8
#define HID  256
#define NG   1024     // 4*H
#define NHh  4
#define EE   4
#define CVv  8
#define N1   4032     // B*T  (intra seqs)
#define N2   1344     // B*Fp (inter seqs)
#define LFi  21       // F/KS
#define LTi  63       // T/KS
#define MROWS 84672   // 21*4032 == 63*1344
#define EPSf 1e-5f

typedef __hip_bfloat16 bf16;
__device__ __forceinline__ float b2f(bf16 v) { return __bfloat162float(v); }
__device__ __forceinline__ bf16 f2b(float v) { return __float2bfloat16(v); }
__device__ __forceinline__ float us2f(unsigned short u) {
  return __uint_as_float(((unsigned)u) << 16);
}

__device__ __forceinline__ float sigm(float x) { return 1.f / (1.f + __expf(-x)); }
__device__ __forceinline__ float tanh_f(float x) {
  x = fminf(15.f, fmaxf(-15.f, x));
  float e = __expf(2.f * x);
  return (e - 1.f) / (e + 1.f);
}

// block = 256 threads (4 waves). red must be float[8] shared.
__device__ __forceinline__ void block_reduce2(float& s1, float& s2, float* red) {
#pragma unroll
  for (int off = 32; off > 0; off >>= 1) {
    s1 += __shfl_down(s1, off, 64);
    s2 += __shfl_down(s2, off, 64);
  }
  int lane = threadIdx.x & 63, wv = threadIdx.x >> 6;
  __syncthreads();
  if (lane == 0) { red[wv * 2] = s1; red[wv * 2 + 1] = s2; }
  __syncthreads();
  s1 = red[0] + red[2] + red[4] + red[6];
  s2 = red[1] + red[3] + red[5] + red[7];
}

// ---------------- K1: input conv 2->32, 3x3, pad 1 ----------------
__global__ __launch_bounds__(256) void conv_in_k(const float* __restrict__ x,
                                                 const float* __restrict__ w,
                                                 const float* __restrict__ bias,
                                                 bf16* __restrict__ out) {
  int gid = blockIdx.x * 256 + threadIdx.x;       // B*CH*TT*OF = 20,772,864 exact
  int f = gid % OF;
  int t = (gid / OF) % TT;
  int co = (gid / (OF * TT)) % CH;
  int b = gid / (OF * TT * CH);
  float acc = bias[co];
#pragma unroll
  for (int ci = 0; ci < 2; ci++)
#pragma unroll
    for (int kh = 0; kh < 3; kh++) {
      int tt = t + kh - 1;
      if (tt < 0 || tt >= TT) continue;
#pragma unroll
      for (int kw = 0; kw < 3; kw++) {
        int ff = f + kw - 1;
        if (ff < 0 || ff >= OF) continue;
        acc += x[((size_t)(b * 2 + ci) * TT + tt) * OF + ff] * w[((co * 2 + ci) * 3 + kh) * 3 + kw];
      }
    }
  out[gid] = f2b(acc);
}

// ---------------- K2/K3: global per-batch norm ----------------
__global__ __launch_bounds__(256) void gn_reduce_k(const bf16* __restrict__ xin,
                                                   float* __restrict__ stats) {
  const int M = CH * TT * OF;   // 2,596,608
  int b = blockIdx.x >> 6;
  int part = blockIdx.x & 63;
  const bf16* p = xin + (size_t)b * M;
  float s1 = 0.f, s2 = 0.f;
  for (int i = part * 256 + threadIdx.x; i < M; i += 64 * 256) {
    float v = b2f(p[i]);
    s1 += v; s2 += v * v;
  }
  __shared__ float red[8];
  block_reduce2(s1, s2, red);
  if (threadIdx.x == 0) {
    atomicAdd(&stats[b * 2], s1);
    atomicAdd(&stats[b * 2 + 1], s2);
  }
}

__global__ __launch_bounds__(256) void gn_apply_k(const bf16* __restrict__ xin,
                                                  const float* __restrict__ stats,
                                                  const float* __restrict__ g,
                                                  const float* __restrict__ bb,
                                                  bf16* __restrict__ act) {
  int gid = blockIdx.x * 256 + threadIdx.x;       // B*CH*TT*FFp = 21,676,032 exact
  int f = gid % FFp;
  int t = (gid / FFp) % TT;
  int c = (gid / (FFp * TT)) % CH;
  int b = gid / (FFp * TT * CH);
  float v = 0.f;
  if (f < OF) {
    const float M = (float)(CH * TT * OF);
    float mu = stats[b * 2] / M;
    float var = stats[b * 2 + 1] / M - mu * mu;
    float xv = b2f(xin[((size_t)(b * CH + c) * TT + t) * OF + f]);
    v = (xv - mu) * rsqrtf(var + EPSf) * g[c] + bb[c];   // NOTE: no outer +eps here
  }
  act[gid] = f2b(v);
}

// ---------------- K4: ln over channels + unfold to time-major LSTM input ----------------
// mode 0 (intra): out[(f/8)*N1 + b*TT+t][c*8 + f%8]
// mode 1 (inter): out[(t/8)*N2 + b*FFp+f][c*8 + t%8]
__global__ __launch_bounds__(256) void ln_unfold_k(const bf16* __restrict__ xin,
                                                   const float* __restrict__ g,
                                                   const float* __restrict__ bb,
                                                   bf16* __restrict__ out, int mode) {
  __shared__ float sm[CH * FFp];
  __shared__ float mu_s[FFp], rs_s[FFp];
  int bt = blockIdx.x;
  int b = bt / TT, t = bt % TT;
  const bf16* base = xin + ((size_t)b * CH * TT + t) * FFp;
  for (int idx = threadIdx.x; idx < CH * FFp; idx += 256) {
    int c = idx / FFp, f = idx % FFp;
    sm[idx] = b2f(base[(size_t)c * TT * FFp + f]);
  }
  __syncthreads();
  if (threadIdx.x < FFp) {
    int f = threadIdx.x;
    float s1 = 0.f, s2 = 0.f;
#pragma unroll
    for (int c = 0; c < CH; c++) { float v = sm[c * FFp + f]; s1 += v; s2 += v * v; }
    float mu = s1 / CH;
    float var = s2 / CH - mu * mu;
    mu_s[f] = mu;
    rs_s[f] = 1.f / (sqrtf(var + EPSf) + EPSf);
  }
  __syncthreads();
  for (int idx = threadIdx.x; idx < CH * FFp; idx += 256) {
    int c = idx / FFp, f = idx % FFp;
    float v = (sm[idx] - mu_s[f]) * rs_s[f] * g[c] + bb[c];
    size_t o;
    if (mode == 0) {
      o = ((size_t)(f >> 3) * N1 + bt) * 256 + c * 8 + (f & 7);
    } else {
      int n = b * FFp + f;
      o = ((size_t)(t >> 3) * N2 + n) * 256 + c * 8 + (t & 7);
    }
    out[o] = f2b(v);
  }
}

// ---------------- K5: fused LSTM (input proj + recurrence), per-sequence blocks --------
// xz time-major: (Ls, N, 256) bf16. hout time-major: (Ls, N, hstride) bf16 at col dir*256.
// thread tid owns gate element e=tid for gates i,f,g,o (rows q*256+tid of wih/whh).
// Recurrence state (h, c) stays fp32 in LDS; only global staging is bf16.
template <int G>
__global__ __launch_bounds__(256) void lstm_fused_k(const bf16* __restrict__ xz,
                                                    const float* __restrict__ wih0,
                                                    const float* __restrict__ whh0,
                                                    const float* __restrict__ bih0,
                                                    const float* __restrict__ bhh0,
                                                    bf16* __restrict__ hout,
                                                    int N, int Ls, int hstride, int bidir) {
  __shared__ float xh[G * 512];     // per seq: [0:256) x_t, [256:512) h
  __shared__ float cst[G * 256];
  int tid = threadIdx.x;
  int dir = blockIdx.y;
  const float* wih = wih0 + (size_t)dir * NG * 256;
  const float* whh = whh0 + (size_t)dir * NG * 256;
  const float* bih = bih0 + dir * NG;
  const float* bhh = bhh0 + dir * NG;
  int hoff = dir * 256;
  int n0 = blockIdx.x * G;

  for (int i = tid; i < G * 256; i += 256) {
    xh[(i >> 8) * 512 + 256 + (i & 255)] = 0.f;
    cst[i] = 0.f;
  }
  float bsum[4];
#pragma unroll
  for (int q = 0; q < 4; q++) bsum[q] = bih[q * 256 + tid] + bhh[q * 256 + tid];

  for (int st = 0; st < Ls; st++) {
    int t = (bidir && dir) ? (Ls - 1 - st) : st;
    for (int i = tid; i < G * 256; i += 256) {
      int s = i >> 8, k = i & 255;
      xh[s * 512 + k] = b2f(xz[((size_t)t * N + n0 + s) * 256 + k]);
    }
    __syncthreads();

    float acc[4][G];
#pragma unroll
    for (int q = 0; q < 4; q++)
#pragma unroll
      for (int s = 0; s < G; s++) acc[q][s] = bsum[q];

    for (int kb = 0; kb < 256; kb += 4) {          // x part
      float4 wq[4];
#pragma unroll
      for (int q = 0; q < 4; q++) wq[q] = *(const float4*)(wih + (size_t)(q * 256 + tid) * 256 + kb);
#pragma unroll
      for (int s = 0; s < G; s++) {
        float4 xv = *(const float4*)(&xh[s * 512 + kb]);
#pragma unroll
        for (int q = 0; q < 4; q++)
          acc[q][s] += wq[q].x * xv.x + wq[q].y * xv.y + wq[q].z * xv.z + wq[q].w * xv.w;
      }
    }
    for (int kb = 0; kb < 256; kb += 4) {          // h part
      float4 wq[4];
#pragma unroll
      for (int q = 0; q < 4; q++) wq[q] = *(const float4*)(whh + (size_t)(q * 256 + tid) * 256 + kb);
#pragma unroll
      for (int s = 0; s < G; s++) {
        float4 xv = *(const float4*)(&xh[s * 512 + 256 + kb]);
#pragma unroll
        for (int q = 0; q < 4; q++)
          acc[q][s] += wq[q].x * xv.x + wq[q].y * xv.y + wq[q].z * xv.z + wq[q].w * xv.w;
      }
    }
    __syncthreads();   // all reads of h done before updating h

#pragma unroll
    for (int s = 0; s < G; s++) {
      float iv = sigm(acc[0][s]);
      float fv = sigm(acc[1][s]);
      float gv = tanh_f(acc[2][s]);
      float ov = sigm(acc[3][s]);
      float c = fv * cst[s * 256 + tid] + iv * gv;
      cst[s * 256 + tid] = c;
      float h = ov * tanh_f(c);
      xh[s * 512 + 256 + tid] = h;
      hout[((size_t)t * N + n0 + s) * hstride + hoff + tid] = f2b(h);
    }
  }
}

// ---------------- K6: fold GEMM (M=84672, N=256) + bias + residual, scatter epilogue ---
// mode 0 (intra): res[b,c,t,l*8+k] = val + linb[c] + act[...]
// mode 1 (inter): if f<161: interc[b,c,l*8+k,f] = val + linb[c] + res[...]
__global__ __launch_bounds__(256) void fold_gemm_k(const bf16* __restrict__ A,
                                                   const float* __restrict__ Bw,
                                                   const float* __restrict__ linb,
                                                   const bf16* __restrict__ resid,
                                                   bf16* __restrict__ outp,
                                                   int K, int mode) {
  __shared__ float As[16 * 64];
  __shared__ float Bs[16 * 64];
  int tid = threadIdx.x;
  int n0 = blockIdx.x * 64;
  int m0 = blockIdx.y * 64;
  int tr = tid >> 4, tc = tid & 15;
  float acc[4][4] = {};
  int arow = tid >> 2, akg = (tid & 3) * 4;
  int bkk = tid >> 4, bc4 = (tid & 15) * 4;
  for (int k0 = 0; k0 < K; k0 += 16) {
    ushort4 avu = *(const ushort4*)((const unsigned short*)A + (size_t)(m0 + arow) * K + k0 + akg);
    float4 bv = *(const float4*)(Bw + (size_t)(k0 + bkk) * 256 + n0 + bc4);
    __syncthreads();
    As[(akg + 0) * 64 + arow] = us2f(avu.x);
    As[(akg + 1) * 64 + arow] = us2f(avu.y);
    As[(akg + 2) * 64 + arow] = us2f(avu.z);
    As[(akg + 3) * 64 + arow] = us2f(avu.w);
    *(float4*)(&Bs[bkk * 64 + bc4]) = bv;
    __syncthreads();
#pragma unroll
    for (int kk = 0; kk < 16; kk++) {
      float4 a4 = *(const float4*)(&As[kk * 64 + tr * 4]);
      float4 b4 = *(const float4*)(&Bs[kk * 64 + tc * 4]);
      float aa[4] = {a4.x, a4.y, a4.z, a4.w};
      float bb_[4] = {b4.x, b4.y, b4.z, b4.w};
#pragma unroll
      for (int i = 0; i < 4; i++)
#pragma unroll
        for (int j = 0; j < 4; j++) acc[i][j] += aa[i] * bb_[j];
    }
  }
#pragma unroll
  for (int i = 0; i < 4; i++) {
    int r = m0 + tr * 4 + i;
#pragma unroll
    for (int j = 0; j < 4; j++) {
      int col = n0 + tc * 4 + j;
      int c = col >> 3, kp = col & 7;
      float v = acc[i][j] + linb[c];
      if (mode == 0) {
        int l = r / N1, n = r % N1;
        int b = n / TT, t = n % TT;
        size_t o = ((size_t)(b * CH + c) * TT + t) * FFp + (l * 8 + kp);
        outp[o] = f2b(v + b2f(resid[o]));
      } else {
        int l = r / N2, n = r % N2;
        int b = n / FFp, fq = n % FFp;
        int t = l * 8 + kp;
        if (fq < OF) {
          size_t o = ((size_t)(b * CH + c) * TT + t) * OF + fq;
          size_t ri = ((size_t)(b * CH + c) * TT + t) * FFp + fq;
          outp[o] = f2b(v + b2f(resid[ri]));
        }
      }
    }
  }
}

// ---------------- K8: fused QKV projection + prelu + ln_cf_head ----------------
__global__ __launch_bounds__(256) void qkv_k(const bf16* __restrict__ interc,
    const float* __restrict__ qw, const float* __restrict__ qb, const float* __restrict__ qa,
    const float* __restrict__ qg, const float* __restrict__ qbeta,
    const float* __restrict__ kw, const float* __restrict__ kb, const float* __restrict__ ka,
    const float* __restrict__ kg, const float* __restrict__ kbeta,
    const float* __restrict__ vw, const float* __restrict__ vb, const float* __restrict__ va,
    const float* __restrict__ vg, const float* __restrict__ vbeta,
    bf16* __restrict__ qo, bf16* __restrict__ ko, bf16* __restrict__ vo) {
  __shared__ float sm[CH * OF];     // 5152
  __shared__ float wb[16 * 32];
  __shared__ float wbias[16];
  __shared__ float yb[16 * OF];     // 2576: [0:4) Q-e, [4:8) K-e, [8:16) V-cv
  __shared__ float red[8];
  int bt = blockIdx.x, h = blockIdx.y;
  int b = bt / TT, t = bt % TT;
  int tid = threadIdx.x;
  const bf16* src = interc + ((size_t)b * CH * TT + t) * OF;
  for (int idx = tid; idx < CH * OF; idx += 256) {
    int c = idx / OF, f = idx % OF;
    sm[idx] = b2f(src[(size_t)c * TT * OF + f]);
  }
  for (int idx = tid; idx < 512; idx += 256) {
    int e = idx >> 5, c = idx & 31;
    float w;
    if (e < 4) w = qw[(h * 4 + e) * 32 + c];
    else if (e < 8) w = kw[(h * 4 + e - 4) * 32 + c];
    else w = vw[(h * 8 + e - 8) * 32 + c];
    wb[idx] = w;
  }
  if (tid < 16) {
    float bv;
    if (tid < 4) bv = qb[h * 4 + tid];
    else if (tid < 8) bv = kb[h * 4 + tid - 4];
    else bv = vb[h * 8 + tid - 8];
    wbias[tid] = bv;
  }
  __syncthreads();
  float aQ = qa[h], aK = ka[h], aV = va[h];
  for (int idx = tid; idx < 16 * OF; idx += 256) {
    int e = idx / OF, f = idx % OF;
    float accv = wbias[e];
#pragma unroll
    for (int c = 0; c < 32; c++) accv += sm[c * OF + f] * wb[e * 32 + c];
    float a = e < 4 ? aQ : (e < 8 ? aK : aV);
    yb[idx] = accv >= 0.f ? accv : a * accv;
  }
  __syncthreads();
  for (int seg = 0; seg < 3; seg++) {
    int s0 = (seg == 0) ? 0 : ((seg == 1) ? 644 : 1288);
    int len = (seg == 2) ? 1288 : 644;
    float s1 = 0.f, s2 = 0.f;
    for (int i = tid; i < len; i += 256) { float v = yb[s0 + i]; s1 += v; s2 += v * v; }
    block_reduce2(s1, s2, red);
    float mu = s1 / len;
    float var = s2 / len - mu * mu;
    float rs = 1.f / (sqrtf(var + EPSf) + EPSf);
    const float* gp; const float* bp; bf16* op; int nch;
    if (seg == 0) { gp = qg; bp = qbeta; op = qo; nch = 4; }
    else if (seg == 1) { gp = kg; bp = kbeta; op = ko; nch = 4; }
    else { gp = vg; bp = vbeta; op = vo; nch = 8; }
    for (int i = tid; i < len; i += 256) {
      int e = i / OF, f = i % OF;
      float v = (yb[s0 + i] - mu) * rs * gp[(h * nch + e) * OF + f] + bp[(h * nch + e) * OF + f];
      op[(((size_t)(h * BB + b) * nch + e) * TT + t) * OF + f] = f2b(v);
    }
  }
}

// ---------------- K9: banded causal attention (lookback 5) ----------------
__global__ __launch_bounds__(256) void attn_k(const bf16* __restrict__ Q,
                                              const bf16* __restrict__ Kt,
                                              const bf16* __restrict__ V,
                                              bf16* __restrict__ O) {
  int t = blockIdx.x;
  int hb = blockIdx.y;            // h*8 + b
  int h = hb >> 3, b = hb & 7;
  int tid = threadIdx.x;
  int nv = min(t, 5) + 1;
  const float scale = 0.0394055201f;   // 1/sqrt(644)
  __shared__ float redl[24];
  float part[6] = {0, 0, 0, 0, 0, 0};
  size_t qkbase = ((size_t)(h * BB + b) * EE) * TT * OF;
  for (int i = tid; i < EE * OF; i += 256) {
    int e = i / OF, f = i % OF;
    float qv = b2f(Q[qkbase + ((size_t)e * TT + t) * OF + f]);
#pragma unroll
    for (int d = 0; d < 6; d++)
      if (d < nv) part[d] += qv * b2f(Kt[qkbase + ((size_t)e * TT + (t - d)) * OF + f]);
  }
#pragma unroll
  for (int d = 0; d < 6; d++)
#pragma unroll
    for (int off = 32; off > 0; off >>= 1) part[d] += __shfl_down(part[d], off, 64);
  int lane = tid & 63, wv = tid >> 6;
  if (lane == 0) {
#pragma unroll
    for (int d = 0; d < 6; d++) redl[wv * 6 + d] = part[d];
  }
  __syncthreads();
  float a[6], sv[6];
  float m = -1e30f;
#pragma unroll
  for (int d = 0; d < 6; d++)
    if (d < nv) {
      float s = (redl[d] + redl[6 + d] + redl[12 + d] + redl[18 + d]) * scale;
      sv[d] = s;
      m = fmaxf(m, s);
    }
  float denom = 0.f;
#pragma unroll
  for (int d = 0; d < 6; d++)
    if (d < nv) { a[d] = __expf(sv[d] - m); denom += a[d]; }
  float inv = 1.f / denom;
  size_t vbase = ((size_t)(h * BB + b) * CVv) * TT * OF;
  for (int i = tid; i < CVv * OF; i += 256) {
    int cv = i / OF, f = i % OF;
    float o = 0.f;
#pragma unroll
    for (int d = 0; d < 6; d++)
      if (d < nv) o += a[d] * b2f(V[vbase + ((size_t)cv * TT + (t - d)) * OF + f]);
    O[(((size_t)b * CH + h * CVv + cv) * TT + t) * OF + f] = f2b(o * inv);
  }
}

// ---------------- K10: proj + prelu + ln_cf_proj + residual + re-pad ----------------
__global__ __launch_bounds__(256) void proj_k(const bf16* __restrict__ ob,
                                              const float* __restrict__ pw,
                                              const float* __restrict__ pb,
                                              const float* __restrict__ pa,
                                              const float* __restrict__ pg,
                                              const float* __restrict__ pbeta,
                                              const bf16* __restrict__ interc,
                                              bf16* __restrict__ act) {
  __shared__ float sm[CH * OF];
  __shared__ float wsm[CH * CH];
  __shared__ float yb[CH * OF];
  __shared__ float red[8];
  int bt = blockIdx.x;
  int b = bt / TT, t = bt % TT;
  int tid = threadIdx.x;
  const bf16* src = ob + ((size_t)b * CH * TT + t) * OF;
  for (int idx = tid; idx < CH * OF; idx += 256) {
    int c = idx / OF, f = idx % OF;
    sm[idx] = b2f(src[(size_t)c * TT * OF + f]);
  }
  for (int idx = tid; idx < CH * CH; idx += 256) wsm[idx] = pw[idx];
  __syncthreads();
  float aP = pa[0];
  for (int idx = tid; idx < CH * OF; idx += 256) {
    int d = idx / OF, f = idx % OF;
    float accv = pb[d];
#pragma unroll
    for (int c = 0; c < 32; c++) accv += sm[c * OF + f] * wsm[d * 32 + c];
    yb[idx] = accv >= 0.f ? accv : aP * accv;
  }
  __syncthreads();
  float s1 = 0.f, s2 = 0.f;
  for (int i = tid; i < CH * OF; i += 256) { float v = yb[i]; s1 += v; s2 += v * v; }
  block_reduce2(s1, s2, red);
  const float Mn = (float)(CH * OF);
  float mu = s1 / Mn;
  float var = s2 / Mn - mu * mu;
  float rs = 1.f / (sqrtf(var + EPSf) + EPSf);
  for (int idx = tid; idx < CH * FFp; idx += 256) {
    int d = idx / FFp, f = idx % FFp;
    float v = 0.f;
    if (f < OF) {
      float y = (yb[d * OF + f] - mu) * rs * pg[d * OF + f] + pbeta[d * OF + f];
      v = y + b2f(interc[((size_t)(b * CH + d) * TT + t) * OF + f]);
    }
    act[((size_t)(b * CH + d) * TT + t) * FFp + f] = f2b(v);
  }
}

// ---------------- K11: output deconv (flipped transposed conv == 3x3 conv) ------------
__global__ __launch_bounds__(256) void deconv_k(const bf16* __restrict__ act,
                                                const float* __restrict__ w,
                                                const float* __restrict__ bias,
                                                float* __restrict__ out) {
  int gid = blockIdx.x * 256 + threadIdx.x;
  if (gid >= BB * 2 * TT * OF) return;
  int f = gid % OF;
  int t = (gid / OF) % TT;
  int co = (gid / (OF * TT)) % 2;
  int b = gid / (OF * TT * 2);
  float acc = bias[co];
  for (int ci = 0; ci < CH; ci++)
#pragma unroll
    for (int kh = 0; kh < 3; kh++) {
      int tt = t + kh - 1;
      if (tt < 0 || tt >= TT) continue;
#pragma unroll
      for (int kw = 0; kw < 3; kw++) {
        int ff = f + kw - 1;
        if (ff < 0) continue;               // ff==161 reads zeroed pad column: correct
        acc += b2f(act[((size_t)(b * CH + ci) * TT + tt) * FFp + ff]) *
               w[((ci * 2 + co) * 3 + (2 - kh)) * 3 + (2 - kw)];
      }
    }
  out[gid] = acc;
}

// ---------------- host launch ----------------
extern "C" void kernel_launch(void* const* d_in, const int* in_sizes, int n_in,
                              void* d_out, int out_size, void* d_ws, size_t ws_size,
                              hipStream_t stream) {
  const float* x            = (const float*)d_in[0];
  const float* conv_w       = (const float*)d_in[1];
  const float* conv_b       = (const float*)d_in[2];
  const float* gn_g         = (const float*)d_in[3];
  const float* gn_b         = (const float*)d_in[4];
  const float* intra_norm_g = (const float*)d_in[5];
  const float* intra_norm_b = (const float*)d_in[6];
  const float* intra_wih    = (const float*)d_in[7];
  const float* intra_whh    = (const float*)d_in[8];
  const float* intra_bih    = (const float*)d_in[9];
  const float* intra_bhh    = (const float*)d_in[10];
  const float* intra_lin_w  = (const float*)d_in[11];
  const float* intra_lin_b  = (const float*)d_in[12];
  const float* inter_norm_g = (const float*)d_in[13];
  const float* inter_norm_b = (const float*)d_in[14];
  const float* inter_wih    = (const float*)d_in[15];
  const float* inter_whh    = (const float*)d_in[16];
  const float* inter_bih    = (const float*)d_in[17];
  const float* inter_bhh    = (const float*)d_in[18];
  const float* inter_lin_w  = (const float*)d_in[19];
  const float* inter_lin_b  = (const float*)d_in[20];
  const float* q_w    = (const float*)d_in[21];
  const float* q_b    = (const float*)d_in[22];
  const float* q_a    = (const float*)d_in[23];
  const float* q_g    = (const float*)d_in[24];
  const float* q_beta = (const float*)d_in[25];
  const float* k_w    = (const float*)d_in[26];
  const float* k_b    = (const float*)d_in[27];
  const float* k_a    = (const float*)d_in[28];
  const float* k_g    = (const float*)d_in[29];
  const float* k_beta = (const float*)d_in[30];
  const float* v_w    = (const float*)d_in[31];
  const float* v_b    = (const float*)d_in[32];
  const float* v_a    = (const float*)d_in[33];
  const float* v_g    = (const float*)d_in[34];
  const float* v_beta = (const float*)d_in[35];
  const float* proj_w    = (const float*)d_in[36];
  const float* proj_b    = (const float*)d_in[37];
  const float* proj_a    = (const float*)d_in[38];
  const float* proj_g    = (const float*)d_in[39];
  const float* proj_beta = (const float*)d_in[40];
  const float* deconv_w  = (const float*)d_in[41];
  const float* deconv_b  = (const float*)d_in[42];

  // workspace: 256 B fp32 stats + bf16 arena of 129,153,024 elems = 246.3 MiB total.
  // Liveness-based aliasing:
  //   A act(21.676M)  B tmp(21.676M)  C hbuf(43.352M)  D res(21.676M)  E interc(20.773M)
  //   conv-out->E, qbuf->A, kbuf->B, vbuf->D, obuf->C (all dead at point of reuse)
  float* stats = (float*)d_ws;
  bf16* arena  = (bf16*)((char*)d_ws + 256);
  bf16* act    = arena;                  // A
  bf16* tmp    = arena + 21676032;       // B
  bf16* hbuf   = arena + 43352064;       // C
  bf16* res    = arena + 86704128;       // D
  bf16* interc = arena + 108380160;      // E  (end: 129,153,024)
  bf16* convout = interc;
  bf16* qbuf = act;
  bf16* kbuf = tmp;
  bf16* vbuf = res;
  bf16* obuf = hbuf;

  hipMemsetAsync(stats, 0, 64 * sizeof(float), stream);
  conv_in_k<<<81144, 256, 0, stream>>>(x, conv_w, conv_b, convout);
  gn_reduce_k<<<512, 256, 0, stream>>>(convout, stats);
  gn_apply_k<<<84672, 256, 0, stream>>>(convout, stats, gn_g, gn_b, act);

  for (int l = 0; l < 4; l++) {
    ln_unfold_k<<<4032, 256, 0, stream>>>(act, intra_norm_g + l * 32, intra_norm_b + l * 32, tmp, 0);
    lstm_fused_k<16><<<dim3(252, 2), 256, 0, stream>>>(
        tmp, intra_wih + (size_t)l * 524288, intra_whh + (size_t)l * 524288,
        intra_bih + l * 2048, intra_bhh + l * 2048, hbuf, N1, LFi, 512, 1);
    fold_gemm_k<<<dim3(4, 1323), 256, 0, stream>>>(
        hbuf, intra_lin_w + (size_t)l * 131072, intra_lin_b + l * 32, act, res, 512, 0);
    ln_unfold_k<<<4032, 256, 0, stream>>>(res, inter_norm_g + l * 32, inter_norm_b + l * 32, tmp, 1);
    lstm_fused_k<8><<<dim3(168, 1), 256, 0, stream>>>(
        tmp, inter_wih + (size_t)l * 262144, inter_whh + (size_t)l * 262144,
        inter_bih + l * 1024, inter_bhh + l * 1024, hbuf, N2, LTi, 256, 0);
    fold_gemm_k<<<dim3(4, 1323), 256, 0, stream>>>(
        hbuf, inter_lin_w + (size_t)l * 65536, inter_lin_b + l * 32, res, interc, 256, 1);
    qkv_k<<<dim3(4032, 4), 256, 0, stream>>>(interc,
        q_w + l * 512, q_b + l * 16, q_a + l * 4, q_g + l * 2576, q_beta + l * 2576,
        k_w + l * 512, k_b + l * 16, k_a + l * 4, k_g + l * 2576, k_beta + l * 2576,
        v_w + l * 1024, v_b + l * 32, v_a + l * 4, v_g + l * 5152, v_beta + l * 5152,
        qbuf, kbuf, vbuf);
    attn_k<<<dim3(504, 32), 256, 0, stream>>>(qbuf, kbuf, vbuf, obuf);
    proj_k<<<4032, 256, 0, stream>>>(obuf, proj_w + l * 1024, proj_b + l * 32, proj_a + l,
                                     proj_g + l * 5152, proj_beta + l * 5152, interc, act);
  }
  deconv_k<<<5072, 256, 0, stream>>>(act, deconv_w, deconv_b, (float*)d_out);
}

// Round 3
// 37692.780 us; speedup vs baseline: 1.5621x; 1.5621x over previous
//
#include <hip/hip_runtime.h>
#include <hip/hip_bf16.h>
#include <math.h>

// ---------------- problem constants ----------------
#define BB   8
#define CH   32
#define TT   504
#define FFp  168      // padded F
#define OF   161      // original F
#define KSZ  8
#define HID  256
#define NG   1024     // 4*H
#define NHh  4
#define EE   4
#define CVv  8
#define N1   4032     // B*T  (intra seqs)
#define N2   1344     // B*Fp (inter seqs)
#define LFi  21       // F/KS
#define LTi  63       // T/KS
#define EPSf 1e-5f

typedef __hip_bfloat16 bf16;
typedef __attribute__((ext_vector_type(8))) short s16x8;
typedef __attribute__((ext_vector_type(4))) float f32x4;

__device__ __forceinline__ float b2f(bf16 v) { return __bfloat162float(v); }
__device__ __forceinline__ bf16 f2b(float v) { return __float2bfloat16(v); }
__device__ __forceinline__ float us2f(unsigned short u) {
  return __uint_as_float(((unsigned)u) << 16);
}
__device__ __forceinline__ unsigned short f2bu(float v) {   // RNE bf16 bits
  unsigned u = __float_as_uint(v);
  unsigned r = u + 0x7fffu + ((u >> 16) & 1u);
  return (unsigned short)(r >> 16);
}

__device__ __forceinline__ float sigm(float x) { return 1.f / (1.f + __expf(-x)); }
__device__ __forceinline__ float tanh_f(float x) {
  x = fminf(15.f, fmaxf(-15.f, x));
  float e = __expf(2.f * x);
  return (e - 1.f) / (e + 1.f);
}

// block = 256 threads (4 waves). red must be float[8] shared.
__device__ __forceinline__ void block_reduce2(float& s1, float& s2, float* red) {
#pragma unroll
  for (int off = 32; off > 0; off >>= 1) {
    s1 += __shfl_down(s1, off, 64);
    s2 += __shfl_down(s2, off, 64);
  }
  int lane = threadIdx.x & 63, wv = threadIdx.x >> 6;
  __syncthreads();
  if (lane == 0) { red[wv * 2] = s1; red[wv * 2 + 1] = s2; }
  __syncthreads();
  s1 = red[0] + red[2] + red[4] + red[6];
  s2 = red[1] + red[3] + red[5] + red[7];
}

// ---------------- K1: input conv 2->32, 3x3, pad 1 ----------------
__global__ __launch_bounds__(256) void conv_in_k(const float* __restrict__ x,
                                                 const float* __restrict__ w,
                                                 const float* __restrict__ bias,
                                                 bf16* __restrict__ out) {
  int gid = blockIdx.x * 256 + threadIdx.x;       // B*CH*TT*OF = 20,772,864 exact
  int f = gid % OF;
  int t = (gid / OF) % TT;
  int co = (gid / (OF * TT)) % CH;
  int b = gid / (OF * TT * CH);
  float acc = bias[co];
#pragma unroll
  for (int ci = 0; ci < 2; ci++)
#pragma unroll
    for (int kh = 0; kh < 3; kh++) {
      int tt = t + kh - 1;
      if (tt < 0 || tt >= TT) continue;
#pragma unroll
      for (int kw = 0; kw < 3; kw++) {
        int ff = f + kw - 1;
        if (ff < 0 || ff >= OF) continue;
        acc += x[((size_t)(b * 2 + ci) * TT + tt) * OF + ff] * w[((co * 2 + ci) * 3 + kh) * 3 + kw];
      }
    }
  out[gid] = f2b(acc);
}

// ---------------- K2/K3: global per-batch norm ----------------
__global__ __launch_bounds__(256) void gn_reduce_k(const bf16* __restrict__ xin,
                                                   float* __restrict__ stats) {
  const int M = CH * TT * OF;   // 2,596,608
  int b = blockIdx.x >> 6;
  int part = blockIdx.x & 63;
  const bf16* p = xin + (size_t)b * M;
  float s1 = 0.f, s2 = 0.f;
  for (int i = part * 256 + threadIdx.x; i < M; i += 64 * 256) {
    float v = b2f(p[i]);
    s1 += v; s2 += v * v;
  }
  __shared__ float red[8];
  block_reduce2(s1, s2, red);
  if (threadIdx.x == 0) {
    atomicAdd(&stats[b * 2], s1);
    atomicAdd(&stats[b * 2 + 1], s2);
  }
}

__global__ __launch_bounds__(256) void gn_apply_k(const bf16* __restrict__ xin,
                                                  const float* __restrict__ stats,
                                                  const float* __restrict__ g,
                                                  const float* __restrict__ bb,
                                                  bf16* __restrict__ act) {
  int gid = blockIdx.x * 256 + threadIdx.x;       // B*CH*TT*FFp = 21,676,032 exact
  int f = gid % FFp;
  int t = (gid / FFp) % TT;
  int c = (gid / (FFp * TT)) % CH;
  int b = gid / (FFp * TT * CH);
  float v = 0.f;
  if (f < OF) {
    const float M = (float)(CH * TT * OF);
    float mu = stats[b * 2] / M;
    float var = stats[b * 2 + 1] / M - mu * mu;
    float xv = b2f(xin[((size_t)(b * CH + c) * TT + t) * OF + f]);
    v = (xv - mu) * rsqrtf(var + EPSf) * g[c] + bb[c];   // NOTE: no outer +eps here
  }
  act[gid] = f2b(v);
}

// ---------------- K4: ln over channels + unfold to time-major LSTM input ----------------
// mode 0 (intra): out[(f/8)*N1 + b*TT+t][c*8 + f%8]
// mode 1 (inter): out[(t/8)*N2 + b*FFp+f][c*8 + t%8]
__global__ __launch_bounds__(256) void ln_unfold_k(const bf16* __restrict__ xin,
                                                   const float* __restrict__ g,
                                                   const float* __restrict__ bb,
                                                   bf16* __restrict__ out, int mode) {
  __shared__ float sm[CH * FFp];
  __shared__ float mu_s[FFp], rs_s[FFp];
  int bt = blockIdx.x;
  int b = bt / TT, t = bt % TT;
  const bf16* base = xin + ((size_t)b * CH * TT + t) * FFp;
  for (int idx = threadIdx.x; idx < CH * FFp; idx += 256) {
    int c = idx / FFp, f = idx % FFp;
    sm[idx] = b2f(base[(size_t)c * TT * FFp + f]);
  }
  __syncthreads();
  if (threadIdx.x < FFp) {
    int f = threadIdx.x;
    float s1 = 0.f, s2 = 0.f;
#pragma unroll
    for (int c = 0; c < CH; c++) { float v = sm[c * FFp + f]; s1 += v; s2 += v * v; }
    float mu = s1 / CH;
    float var = s2 / CH - mu * mu;
    mu_s[f] = mu;
    rs_s[f] = 1.f / (sqrtf(var + EPSf) + EPSf);
  }
  __syncthreads();
  for (int idx = threadIdx.x; idx < CH * FFp; idx += 256) {
    int c = idx / FFp, f = idx % FFp;
    float v = (sm[idx] - mu_s[f]) * rs_s[f] * g[c] + bb[c];
    size_t o;
    if (mode == 0) {
      o = ((size_t)(f >> 3) * N1 + bt) * 256 + c * 8 + (f & 7);
    } else {
      int n = b * FFp + f;
      o = ((size_t)(t >> 3) * N2 + n) * 256 + c * 8 + (t & 7);
    }
    out[o] = f2b(v);
  }
}

// ---------------- K5a: weight prep — reorder W=[wih|whh] into B-fragment blob ---------
// blob[nt(64)][ks(16)][lane(64)][j(8)], value = Wcat[n][k]:
//   n = nt*16 + (lane&15), k = ks*32 + (lane>>4)*8 + j
//   Wcat[n][k] = k<256 ? wih[n][k] : whh[n][k-256]
__global__ __launch_bounds__(256) void lstm_prep_k(const float* __restrict__ wih0,
                                                   const float* __restrict__ whh0,
                                                   bf16* __restrict__ blob0) {
  int dir = blockIdx.y;
  const float* wih = wih0 + (size_t)dir * 262144;
  const float* whh = whh0 + (size_t)dir * 262144;
  unsigned short* blob = (unsigned short*)(blob0 + (size_t)dir * 524288);
  int gid = blockIdx.x * 256 + threadIdx.x;     // 0..65535
  int lane = gid & 63;
  int ks = (gid >> 6) & 15;
  int nt = gid >> 10;
  int n = nt * 16 + (lane & 15);
  int kb = ks * 32 + (lane >> 4) * 8;
  unsigned short o8[8];
#pragma unroll
  for (int j = 0; j < 8; j++) {
    int k = kb + j;
    float v = (k < 256) ? wih[n * 256 + k] : whh[n * 256 + (k - 256)];
    o8[j] = f2bu(v);
  }
  *(uint4*)(blob + (size_t)gid * 8) = *(uint4*)o8;
}

// ---------------- K5b: MFMA LSTM (fused input proj + recurrence) ----------------------
// Per block: 16 sequences, full 1024 gates via mfma_f32_16x16x32_bf16.
// Wave w owns N-tiles {c*4+w : c in 0..15}; acc[c] row m=(lane>>4)*4+reg, col n-in-tile=lane&15.
// All 4 gates of (m, d) land in one lane (chunks q*4+dd) -> lane-local nonlinearity,
// c-state in 16 regs/lane. A=[x_t;h] staged in LDS in A-frag order; B streams from
// pre-reordered global blob directly into VGPR fragments (coalesced dwordx4).
__global__ __launch_bounds__(256, 2) void lstm_mfma_k(const bf16* __restrict__ xz,
                                                      const bf16* __restrict__ blob0,
                                                      const float* __restrict__ bih0,
                                                      const float* __restrict__ bhh0,
                                                      bf16* __restrict__ hout,
                                                      int N, int Ls, int hstride, int bidir) {
  __shared__ short afr[16 * 64 * 8];     // 16 KB; slot = ks*64 + kg*16 + m  (ks0-7: x, 8-15: h)
  int tid = threadIdx.x;
  int w = tid >> 6, lane = tid & 63;
  int l15 = lane & 15, lq = lane >> 4;
  int dir = blockIdx.y;
  const short* blob = (const short*)(blob0 + (size_t)dir * 524288);
  const float* bih = bih0 + dir * NG;
  const float* bhh = bhh0 + dir * NG;
  int hoff = dir * 256;
  int n0 = blockIdx.x * 16;
  unsigned short* houtu = (unsigned short*)hout;
  const short* xzs = (const short*)xz;

  float bias[16];
#pragma unroll
  for (int c = 0; c < 16; c++) {
    int n = c * 64 + w * 16 + l15;
    bias[c] = bih[n] + bhh[n];
  }
  for (int i = tid; i < 8 * 64 * 8; i += 256) afr[8 * 64 * 8 + i] = 0;   // h frags = 0
  float cst[16];
#pragma unroll
  for (int i = 0; i < 16; i++) cst[i] = 0.f;

  for (int st = 0; st < Ls; st++) {
    int t = (bidir && dir) ? (Ls - 1 - st) : st;
    // stage x_t fragments (8 KB): thread p -> (m = p&15, k8 = p>>4)
#pragma unroll
    for (int pp = 0; pp < 2; pp++) {
      int p = tid + pp * 256;
      int m = p & 15, k8 = p >> 4;
      s16x8 v = *(const s16x8*)(xzs + ((size_t)t * N + n0 + m) * 256 + k8 * 8);
      int slot = (k8 >> 2) * 64 + (k8 & 3) * 16 + m;
      *(s16x8*)(&afr[slot * 8]) = v;
    }
    __syncthreads();                       // x staged + prev h-writes visible
    s16x8 af[16];
#pragma unroll
    for (int ks = 0; ks < 16; ks++) af[ks] = *(const s16x8*)(&afr[(ks * 64 + lane) * 8]);
    __syncthreads();                       // all A-frag reads done before h overwrite

    f32x4 acc[16];
#pragma unroll
    for (int c = 0; c < 16; c++) acc[c] = (f32x4){bias[c], bias[c], bias[c], bias[c]};
#pragma unroll
    for (int c = 0; c < 16; c++) {
      const short* bp = blob + ((size_t)(c * 4 + w) * 8192) + lane * 8;
#pragma unroll
      for (int ks = 0; ks < 16; ks++) {
        s16x8 bq = *(const s16x8*)(bp + ks * 512);
        acc[c] = __builtin_amdgcn_mfma_f32_16x16x32_bf16(af[ks], bq, acc[c], 0, 0, 0);
      }
    }
    // epilogue: gates -> (h, c); h to global + h-frag LDS
#pragma unroll
    for (int dd = 0; dd < 4; dd++) {
      int d = dd * 64 + w * 16 + l15;
#pragma unroll
      for (int r = 0; r < 4; r++) {
        int m = lq * 4 + r;
        float iv = sigm(acc[dd][r]);
        float fv = sigm(acc[4 + dd][r]);
        float gv = tanh_f(acc[8 + dd][r]);
        float ov = sigm(acc[12 + dd][r]);
        float c = fv * cst[dd * 4 + r] + iv * gv;
        cst[dd * 4 + r] = c;
        float h = ov * tanh_f(c);
        unsigned short hb = f2bu(h);
        houtu[((size_t)t * N + n0 + m) * hstride + hoff + d] = hb;
        int slot = (8 + (d >> 5)) * 64 + ((d >> 3) & 3) * 16 + m;
        afr[slot * 8 + (d & 7)] = (short)hb;
      }
    }
  }
}

// ---------------- K6: fold GEMM (M=84672, N=256) + bias + residual, scatter epilogue ---
// mode 0 (intra): res[b,c,t,l*8+k] = val + linb[c] + act[...]
// mode 1 (inter): if f<161: interc[b,c,l*8+k,f] = val + linb[c] + res[...]
__global__ __launch_bounds__(256) void fold_gemm_k(const bf16* __restrict__ A,
                                                   const float* __restrict__ Bw,
                                                   const float* __restrict__ linb,
                                                   const bf16* __restrict__ resid,
                                                   bf16* __restrict__ outp,
                                                   int K, int mode) {
  __shared__ float As[16 * 64];
  __shared__ float Bs[16 * 64];
  int tid = threadIdx.x;
  int n0 = blockIdx.x * 64;
  int m0 = blockIdx.y * 64;
  int tr = tid >> 4, tc = tid & 15;
  float acc[4][4] = {};
  int arow = tid >> 2, akg = (tid & 3) * 4;
  int bkk = tid >> 4, bc4 = (tid & 15) * 4;
  for (int k0 = 0; k0 < K; k0 += 16) {
    ushort4 avu = *(const ushort4*)((const unsigned short*)A + (size_t)(m0 + arow) * K + k0 + akg);
    float4 bv = *(const float4*)(Bw + (size_t)(k0 + bkk) * 256 + n0 + bc4);
    __syncthreads();
    As[(akg + 0) * 64 + arow] = us2f(avu.x);
    As[(akg + 1) * 64 + arow] = us2f(avu.y);
    As[(akg + 2) * 64 + arow] = us2f(avu.z);
    As[(akg + 3) * 64 + arow] = us2f(avu.w);
    *(float4*)(&Bs[bkk * 64 + bc4]) = bv;
    __syncthreads();
#pragma unroll
    for (int kk = 0; kk < 16; kk++) {
      float4 a4 = *(const float4*)(&As[kk * 64 + tr * 4]);
      float4 b4 = *(const float4*)(&Bs[kk * 64 + tc * 4]);
      float aa[4] = {a4.x, a4.y, a4.z, a4.w};
      float bb_[4] = {b4.x, b4.y, b4.z, b4.w};
#pragma unroll
      for (int i = 0; i < 4; i++)
#pragma unroll
        for (int j = 0; j < 4; j++) acc[i][j] += aa[i] * bb_[j];
    }
  }
#pragma unroll
  for (int i = 0; i < 4; i++) {
    int r = m0 + tr * 4 + i;
#pragma unroll
    for (int j = 0; j < 4; j++) {
      int col = n0 + tc * 4 + j;
      int c = col >> 3, kp = col & 7;
      float v = acc[i][j] + linb[c];
      if (mode == 0) {
        int l = r / N1, n = r % N1;
        int b = n / TT, t = n % TT;
        size_t o = ((size_t)(b * CH + c) * TT + t) * FFp + (l * 8 + kp);
        outp[o] = f2b(v + b2f(resid[o]));
      } else {
        int l = r / N2, n = r % N2;
        int b = n / FFp, fq = n % FFp;
        int t = l * 8 + kp;
        if (fq < OF) {
          size_t o = ((size_t)(b * CH + c) * TT + t) * OF + fq;
          size_t ri = ((size_t)(b * CH + c) * TT + t) * FFp + fq;
          outp[o] = f2b(v + b2f(resid[ri]));
        }
      }
    }
  }
}

// ---------------- K8: fused QKV projection + prelu + ln_cf_head ----------------
__global__ __launch_bounds__(256) void qkv_k(const bf16* __restrict__ interc,
    const float* __restrict__ qw, const float* __restrict__ qb, const float* __restrict__ qa,
    const float* __restrict__ qg, const float* __restrict__ qbeta,
    const float* __restrict__ kw, const float* __restrict__ kb, const float* __restrict__ ka,
    const float* __restrict__ kg, const float* __restrict__ kbeta,
    const float* __restrict__ vw, const float* __restrict__ vb, const float* __restrict__ va,
    const float* __restrict__ vg, const float* __restrict__ vbeta,
    bf16* __restrict__ qo, bf16* __restrict__ ko, bf16* __restrict__ vo) {
  __shared__ float sm[CH * OF];     // 5152
  __shared__ float wb[16 * 32];
  __shared__ float wbias[16];
  __shared__ float yb[16 * OF];     // 2576: [0:4) Q-e, [4:8) K-e, [8:16) V-cv
  __shared__ float red[8];
  int bt = blockIdx.x, h = blockIdx.y;
  int b = bt / TT, t = bt % TT;
  int tid = threadIdx.x;
  const bf16* src = interc + ((size_t)b * CH * TT + t) * OF;
  for (int idx = tid; idx < CH * OF; idx += 256) {
    int c = idx / OF, f = idx % OF;
    sm[idx] = b2f(src[(size_t)c * TT * OF + f]);
  }
  for (int idx = tid; idx < 512; idx += 256) {
    int e = idx >> 5, c = idx & 31;
    float w;
    if (e < 4) w = qw[(h * 4 + e) * 32 + c];
    else if (e < 8) w = kw[(h * 4 + e - 4) * 32 + c];
    else w = vw[(h * 8 + e - 8) * 32 + c];
    wb[idx] = w;
  }
  if (tid < 16) {
    float bv;
    if (tid < 4) bv = qb[h * 4 + tid];
    else if (tid < 8) bv = kb[h * 4 + tid - 4];
    else bv = vb[h * 8 + tid - 8];
    wbias[tid] = bv;
  }
  __syncthreads();
  float aQ = qa[h], aK = ka[h], aV = va[h];
  for (int idx = tid; idx < 16 * OF; idx += 256) {
    int e = idx / OF, f = idx % OF;
    float accv = wbias[e];
#pragma unroll
    for (int c = 0; c < 32; c++) accv += sm[c * OF + f] * wb[e * 32 + c];
    float a = e < 4 ? aQ : (e < 8 ? aK : aV);
    yb[idx] = accv >= 0.f ? accv : a * accv;
  }
  __syncthreads();
  for (int seg = 0; seg < 3; seg++) {
    int s0 = (seg == 0) ? 0 : ((seg == 1) ? 644 : 1288);
    int len = (seg == 2) ? 1288 : 644;
    float s1 = 0.f, s2 = 0.f;
    for (int i = tid; i < len; i += 256) { float v = yb[s0 + i]; s1 += v; s2 += v * v; }
    block_reduce2(s1, s2, red);
    float mu = s1 / len;
    float var = s2 / len - mu * mu;
    float rs = 1.f / (sqrtf(var + EPSf) + EPSf);
    const float* gp; const float* bp; bf16* op; int nch;
    if (seg == 0) { gp = qg; bp = qbeta; op = qo; nch = 4; }
    else if (seg == 1) { gp = kg; bp = kbeta; op = ko; nch = 4; }
    else { gp = vg; bp = vbeta; op = vo; nch = 8; }
    for (int i = tid; i < len; i += 256) {
      int e = i / OF, f = i % OF;
      float v = (yb[s0 + i] - mu) * rs * gp[(h * nch + e) * OF + f] + bp[(h * nch + e) * OF + f];
      op[(((size_t)(h * BB + b) * nch + e) * TT + t) * OF + f] = f2b(v);
    }
  }
}

// ---------------- K9: banded causal attention (lookback 5) ----------------
__global__ __launch_bounds__(256) void attn_k(const bf16* __restrict__ Q,
                                              const bf16* __restrict__ Kt,
                                              const bf16* __restrict__ V,
                                              bf16* __restrict__ O) {
  int t = blockIdx.x;
  int hb = blockIdx.y;            // h*8 + b
  int h = hb >> 3, b = hb & 7;
  int tid = threadIdx.x;
  int nv = min(t, 5) + 1;
  const float scale = 0.0394055201f;   // 1/sqrt(644)
  __shared__ float redl[24];
  float part[6] = {0, 0, 0, 0, 0, 0};
  size_t qkbase = ((size_t)(h * BB + b) * EE) * TT * OF;
  for (int i = tid; i < EE * OF; i += 256) {
    int e = i / OF, f = i % OF;
    float qv = b2f(Q[qkbase + ((size_t)e * TT + t) * OF + f]);
#pragma unroll
    for (int d = 0; d < 6; d++)
      if (d < nv) part[d] += qv * b2f(Kt[qkbase + ((size_t)e * TT + (t - d)) * OF + f]);
  }
#pragma unroll
  for (int d = 0; d < 6; d++)
#pragma unroll
    for (int off = 32; off > 0; off >>= 1) part[d] += __shfl_down(part[d], off, 64);
  int lane = tid & 63, wv = tid >> 6;
  if (lane == 0) {
#pragma unroll
    for (int d = 0; d < 6; d++) redl[wv * 6 + d] = part[d];
  }
  __syncthreads();
  float a[6], sv[6];
  float m = -1e30f;
#pragma unroll
  for (int d = 0; d < 6; d++)
    if (d < nv) {
      float s = (redl[d] + redl[6 + d] + redl[12 + d] + redl[18 + d]) * scale;
      sv[d] = s;
      m = fmaxf(m, s);
    }
  float denom = 0.f;
#pragma unroll
  for (int d = 0; d < 6; d++)
    if (d < nv) { a[d] = __expf(sv[d] - m); denom += a[d]; }
  float inv = 1.f / denom;
  size_t vbase = ((size_t)(h * BB + b) * CVv) * TT * OF;
  for (int i = tid; i < CVv * OF; i += 256) {
    int cv = i / OF, f = i % OF;
    float o = 0.f;
#pragma unroll
    for (int d = 0; d < 6; d++)
      if (d < nv) o += a[d] * b2f(V[vbase + ((size_t)cv * TT + (t - d)) * OF + f]);
    O[(((size_t)b * CH + h * CVv + cv) * TT + t) * OF + f] = f2b(o * inv);
  }
}

// ---------------- K10: proj + prelu + ln_cf_proj + residual + re-pad ----------------
__global__ __launch_bounds__(256) void proj_k(const bf16* __restrict__ ob,
                                              const float* __restrict__ pw,
                                              const float* __restrict__ pb,
                                              const float* __restrict__ pa,
                                              const float* __restrict__ pg,
                                              const float* __restrict__ pbeta,
                                              const bf16* __restrict__ interc,
                                              bf16* __restrict__ act) {
  __shared__ float sm[CH * OF];
  __shared__ float wsm[CH * CH];
  __shared__ float yb[CH * OF];
  __shared__ float red[8];
  int bt = blockIdx.x;
  int b = bt / TT, t = bt % TT;
  int tid = threadIdx.x;
  const bf16* src = ob + ((size_t)b * CH * TT + t) * OF;
  for (int idx = tid; idx < CH * OF; idx += 256) {
    int c = idx / OF, f = idx % OF;
    sm[idx] = b2f(src[(size_t)c * TT * OF + f]);
  }
  for (int idx = tid; idx < CH * CH; idx += 256) wsm[idx] = pw[idx];
  __syncthreads();
  float aP = pa[0];
  for (int idx = tid; idx < CH * OF; idx += 256) {
    int d = idx / OF, f = idx % OF;
    float accv = pb[d];
#pragma unroll
    for (int c = 0; c < 32; c++) accv += sm[c * OF + f] * wsm[d * 32 + c];
    yb[idx] = accv >= 0.f ? accv : aP * accv;
  }
  __syncthreads();
  float s1 = 0.f, s2 = 0.f;
  for (int i = tid; i < CH * OF; i += 256) { float v = yb[i]; s1 += v; s2 += v * v; }
  block_reduce2(s1, s2, red);
  const float Mn = (float)(CH * OF);
  float mu = s1 / Mn;
  float var = s2 / Mn - mu * mu;
  float rs = 1.f / (sqrtf(var + EPSf) + EPSf);
  for (int idx = tid; idx < CH * FFp; idx += 256) {
    int d = idx / FFp, f = idx % FFp;
    float v = 0.f;
    if (f < OF) {
      float y = (yb[d * OF + f] - mu) * rs * pg[d * OF + f] + pbeta[d * OF + f];
      v = y + b2f(interc[((size_t)(b * CH + d) * TT + t) * OF + f]);
    }
    act[((size_t)(b * CH + d) * TT + t) * FFp + f] = f2b(v);
  }
}

// ---------------- K11: output deconv (flipped transposed conv == 3x3 conv) ------------
__global__ __launch_bounds__(256) void deconv_k(const bf16* __restrict__ act,
                                                const float* __restrict__ w,
                                                const float* __restrict__ bias,
                                                float* __restrict__ out) {
  int gid = blockIdx.x * 256 + threadIdx.x;
  if (gid >= BB * 2 * TT * OF) return;
  int f = gid % OF;
  int t = (gid / OF) % TT;
  int co = (gid / (OF * TT)) % 2;
  int b = gid / (OF * TT * 2);
  float acc = bias[co];
  for (int ci = 0; ci < CH; ci++)
#pragma unroll
    for (int kh = 0; kh < 3; kh++) {
      int tt = t + kh - 1;
      if (tt < 0 || tt >= TT) continue;
#pragma unroll
      for (int kw = 0; kw < 3; kw++) {
        int ff = f + kw - 1;
        if (ff < 0) continue;               // ff==161 reads zeroed pad column: correct
        acc += b2f(act[((size_t)(b * CH + ci) * TT + tt) * FFp + ff]) *
               w[((ci * 2 + co) * 3 + (2 - kh)) * 3 + (2 - kw)];
      }
    }
  out[gid] = acc;
}

// ---------------- host launch ----------------
extern "C" void kernel_launch(void* const* d_in, const int* in_sizes, int n_in,
                              void* d_out, int out_size, void* d_ws, size_t ws_size,
                              hipStream_t stream) {
  const float* x            = (const float*)d_in[0];
  const float* conv_w       = (const float*)d_in[1];
  const float* conv_b       = (const float*)d_in[2];
  const float* gn_g         = (const float*)d_in[3];
  const float* gn_b         = (const float*)d_in[4];
  const float* intra_norm_g = (const float*)d_in[5];
  const float* intra_norm_b = (const float*)d_in[6];
  const float* intra_wih    = (const float*)d_in[7];
  const float* intra_whh    = (const float*)d_in[8];
  const float* intra_bih    = (const float*)d_in[9];
  const float* intra_bhh    = (const float*)d_in[10];
  const float* intra_lin_w  = (const float*)d_in[11];
  const float* intra_lin_b  = (const float*)d_in[12];
  const float* inter_norm_g = (const float*)d_in[13];
  const float* inter_norm_b = (const float*)d_in[14];
  const float* inter_wih    = (const float*)d_in[15];
  const float* inter_whh    = (const float*)d_in[16];
  const float* inter_bih    = (const float*)d_in[17];
  const float* inter_bhh    = (const float*)d_in[18];
  const float* inter_lin_w  = (const float*)d_in[19];
  const float* inter_lin_b  = (const float*)d_in[20];
  const float* q_w    = (const float*)d_in[21];
  const float* q_b    = (const float*)d_in[22];
  const float* q_a    = (const float*)d_in[23];
  const float* q_g    = (const float*)d_in[24];
  const float* q_beta = (const float*)d_in[25];
  const float* k_w    = (const float*)d_in[26];
  const float* k_b    = (const float*)d_in[27];
  const float* k_a    = (const float*)d_in[28];
  const float* k_g    = (const float*)d_in[29];
  const float* k_beta = (const float*)d_in[30];
  const float* v_w    = (const float*)d_in[31];
  const float* v_b    = (const float*)d_in[32];
  const float* v_a    = (const float*)d_in[33];
  const float* v_g    = (const float*)d_in[34];
  const float* v_beta = (const float*)d_in[35];
  const float* proj_w    = (const float*)d_in[36];
  const float* proj_b    = (const float*)d_in[37];
  const float* proj_a    = (const float*)d_in[38];
  const float* proj_g    = (const float*)d_in[39];
  const float* proj_beta = (const float*)d_in[40];
  const float* deconv_w  = (const float*)d_in[41];
  const float* deconv_b  = (const float*)d_in[42];

  // workspace: 256 B fp32 stats + bf16 arena of 129,153,024 elems = 246.3 MiB total.
  // Liveness-based aliasing:
  //   A act(21.676M)  B tmp(21.676M)  C hbuf(43.352M)  D res(21.676M)  E interc(20.773M)
  //   conv-out->E, qbuf->A, kbuf->B, vbuf->D, obuf->C (all dead at point of reuse)
  //   LSTM weight blobs overlay dead regions: intra blob -> D (dead until fold0),
  //   inter blob -> E (dead until fold1). Zero extra workspace.
  float* stats = (float*)d_ws;
  bf16* arena  = (bf16*)((char*)d_ws + 256);
  bf16* act    = arena;                  // A
  bf16* tmp    = arena + 21676032;       // B
  bf16* hbuf   = arena + 43352064;       // C
  bf16* res    = arena + 86704128;       // D
  bf16* interc = arena + 108380160;      // E  (end: 129,153,024)
  bf16* convout = interc;
  bf16* qbuf = act;
  bf16* kbuf = tmp;
  bf16* vbuf = res;
  bf16* obuf = hbuf;
  bf16* blob_intra = res;                // 2 x 524,288 bf16 = 2 MiB, dead until fold0
  bf16* blob_inter = interc;             // 524,288 bf16 = 1 MiB, dead until fold1

  hipMemsetAsync(stats, 0, 64 * sizeof(float), stream);
  conv_in_k<<<81144, 256, 0, stream>>>(x, conv_w, conv_b, convout);
  gn_reduce_k<<<512, 256, 0, stream>>>(convout, stats);
  gn_apply_k<<<84672, 256, 0, stream>>>(convout, stats, gn_g, gn_b, act);

  for (int l = 0; l < 4; l++) {
    lstm_prep_k<<<dim3(256, 2), 256, 0, stream>>>(
        intra_wih + (size_t)l * 524288, intra_whh + (size_t)l * 524288, blob_intra);
    ln_unfold_k<<<4032, 256, 0, stream>>>(act, intra_norm_g + l * 32, intra_norm_b + l * 32, tmp, 0);
    lstm_mfma_k<<<dim3(252, 2), 256, 0, stream>>>(
        tmp, blob_intra, intra_bih + l * 2048, intra_bhh + l * 2048, hbuf, N1, LFi, 512, 1);
    fold_gemm_k<<<dim3(4, 1323), 256, 0, stream>>>(
        hbuf, intra_lin_w + (size_t)l * 131072, intra_lin_b + l * 32, act, res, 512, 0);
    lstm_prep_k<<<dim3(256, 1), 256, 0, stream>>>(
        inter_wih + (size_t)l * 262144, inter_whh + (size_t)l * 262144, blob_inter);
    ln_unfold_k<<<4032, 256, 0, stream>>>(res, inter_norm_g + l * 32, inter_norm_b + l * 32, tmp, 1);
    lstm_mfma_k<<<dim3(84, 1), 256, 0, stream>>>(
        tmp, blob_inter, inter_bih + l * 1024, inter_bhh + l * 1024, hbuf, N2, LTi, 256, 0);
    fold_gemm_k<<<dim3(4, 1323), 256, 0, stream>>>(
        hbuf, inter_lin_w + (size_t)l * 65536, inter_lin_b + l * 32, res, interc, 256, 1);
    qkv_k<<<dim3(4032, 4), 256, 0, stream>>>(interc,
        q_w + l * 512, q_b + l * 16, q_a + l * 4, q_g + l * 2576, q_beta + l * 2576,
        k_w + l * 512, k_b + l * 16, k_a + l * 4, k_g + l * 2576, k_beta + l * 2576,
        v_w + l * 1024, v_b + l * 32, v_a + l * 4, v_g + l * 5152, v_beta + l * 5152,
        qbuf, kbuf, vbuf);
    attn_k<<<dim3(504, 32), 256, 0, stream>>>(qbuf, kbuf, vbuf, obuf);
    proj_k<<<4032, 256, 0, stream>>>(obuf, proj_w + l * 1024, proj_b + l * 32, proj_a + l,
                                     proj_g + l * 5152, proj_beta + l * 5152, interc, act);
  }
  deconv_k<<<5072, 256, 0, stream>>>(act, deconv_w, deconv_b, (float*)d_out);
}

// Round 5
// 20869.670 us; speedup vs baseline: 2.8213x; 1.8061x over previous
//
#include <hip/hip_runtime.h>
#include <hip/hip_bf16.h>
#include <math.h>

// ---------------- problem constants ----------------
#define BB   8
#define CH   32
#define TT   504
#define FFp  168      // padded F
#define OF   161      // original F
#define KSZ  8
#define HID  256
#define NG   1024     // 4*H
#define NHh  4
#define EE   4
#define CVv  8
#define N1   4032     // B*T  (intra seqs)
#define N2   1344     // B*Fp (inter seqs)
#define LFi  21       // F/KS
#define LTi  63       // T/KS
#define EPSf 1e-5f

typedef __hip_bfloat16 bf16;
typedef __attribute__((ext_vector_type(8))) short s16x8;
typedef __attribute__((ext_vector_type(4))) float f32x4;

__device__ __forceinline__ float b2f(bf16 v) { return __bfloat162float(v); }
__device__ __forceinline__ bf16 f2b(float v) { return __float2bfloat16(v); }
__device__ __forceinline__ float us2f(unsigned short u) {
  return __uint_as_float(((unsigned)u) << 16);
}
__device__ __forceinline__ unsigned short f2bu(float v) {   // RNE bf16 bits
  unsigned u = __float_as_uint(v);
  unsigned r = u + 0x7fffu + ((u >> 16) & 1u);
  return (unsigned short)(r >> 16);
}

__device__ __forceinline__ float sigm(float x) { return 1.f / (1.f + __expf(-x)); }
__device__ __forceinline__ float tanh_f(float x) {
  x = fminf(15.f, fmaxf(-15.f, x));
  float e = __expf(2.f * x);
  return (e - 1.f) / (e + 1.f);
}

// block = 256 threads (4 waves). red must be float[8] shared.
__device__ __forceinline__ void block_reduce2(float& s1, float& s2, float* red) {
#pragma unroll
  for (int off = 32; off > 0; off >>= 1) {
    s1 += __shfl_down(s1, off, 64);
    s2 += __shfl_down(s2, off, 64);
  }
  int lane = threadIdx.x & 63, wv = threadIdx.x >> 6;
  __syncthreads();
  if (lane == 0) { red[wv * 2] = s1; red[wv * 2 + 1] = s2; }
  __syncthreads();
  s1 = red[0] + red[2] + red[4] + red[6];
  s2 = red[1] + red[3] + red[5] + red[7];
}

// ---------------- K1: input conv 2->32, 3x3, pad 1 (LDS-tiled) ----------------
// block per (b,t); stage 2ci x 3 rows in LDS; thread owns f, reuses 18-val
// neighborhood in registers across all 32 output channels; weights via uniform s_loads.
__global__ __launch_bounds__(192) void conv_in_k(const float* __restrict__ x,
                                                 const float* __restrict__ w,
                                                 const float* __restrict__ bias,
                                                 bf16* __restrict__ out) {
  __shared__ float xs[2 * 3 * (OF + 3)];
  int bt = blockIdx.x;
  int b = bt / TT, t = bt % TT;
  int tid = threadIdx.x;
  for (int i = tid; i < 2 * 3 * (OF + 3); i += 192) {
    int ci = i / (3 * (OF + 3));
    int rem = i % (3 * (OF + 3));
    int rr = rem / (OF + 3);
    int f = rem % (OF + 3);
    int ts = t + rr - 1;
    float v = 0.f;
    if (ts >= 0 && ts < TT && f < OF) v = x[((size_t)(b * 2 + ci) * TT + ts) * OF + f];
    xs[i] = v;
  }
  __syncthreads();
  int f = tid;
  if (f < OF) {
    float xv[2][3][3];
#pragma unroll
    for (int ci = 0; ci < 2; ci++)
#pragma unroll
      for (int kh = 0; kh < 3; kh++)
#pragma unroll
        for (int kw = 0; kw < 3; kw++) {
          int ff = f + kw - 1;
          xv[ci][kh][kw] = (ff < 0) ? 0.f : xs[(ci * 3 + kh) * (OF + 3) + ff];
        }
    for (int co = 0; co < CH; co++) {
      float acc = bias[co];
#pragma unroll
      for (int ci = 0; ci < 2; ci++)
#pragma unroll
        for (int kh = 0; kh < 3; kh++)
#pragma unroll
          for (int kw = 0; kw < 3; kw++)
            acc += xv[ci][kh][kw] * w[((co * 2 + ci) * 3 + kh) * 3 + kw];
      out[((size_t)(b * CH + co) * TT + t) * OF + f] = f2b(acc);
    }
  }
}

// ---------------- K2/K3: global per-batch norm ----------------
__global__ __launch_bounds__(256) void gn_reduce_k(const bf16* __restrict__ xin,
                                                   float* __restrict__ stats) {
  const int M = CH * TT * OF;   // 2,596,608
  int b = blockIdx.x >> 6;
  int part = blockIdx.x & 63;
  const bf16* p = xin + (size_t)b * M;
  float s1 = 0.f, s2 = 0.f;
  for (int i = part * 256 + threadIdx.x; i < M; i += 64 * 256) {
    float v = b2f(p[i]);
    s1 += v; s2 += v * v;
  }
  __shared__ float red[8];
  block_reduce2(s1, s2, red);
  if (threadIdx.x == 0) {
    atomicAdd(&stats[b * 2], s1);
    atomicAdd(&stats[b * 2 + 1], s2);
  }
}

__global__ __launch_bounds__(256) void gn_apply_k(const bf16* __restrict__ xin,
                                                  const float* __restrict__ stats,
                                                  const float* __restrict__ g,
                                                  const float* __restrict__ bb,
                                                  bf16* __restrict__ act) {
  int gid = blockIdx.x * 256 + threadIdx.x;       // B*CH*TT*FFp = 21,676,032 exact
  int f = gid % FFp;
  int t = (gid / FFp) % TT;
  int c = (gid / (FFp * TT)) % CH;
  int b = gid / (FFp * TT * CH);
  float v = 0.f;
  if (f < OF) {
    const float M = (float)(CH * TT * OF);
    float mu = stats[b * 2] / M;
    float var = stats[b * 2 + 1] / M - mu * mu;
    float xv = b2f(xin[((size_t)(b * CH + c) * TT + t) * OF + f]);
    v = (xv - mu) * rsqrtf(var + EPSf) * g[c] + bb[c];   // NOTE: no outer +eps here
  }
  act[gid] = f2b(v);
}

// ---------------- K4: ln over channels + unfold to time-major LSTM input ----------------
// mode 0 (intra): out[(f/8)*N1 + b*TT+t][c*8 + f%8]
// mode 1 (inter): out[(t/8)*N2 + b*FFp+f][c*8 + t%8]
__global__ __launch_bounds__(256) void ln_unfold_k(const bf16* __restrict__ xin,
                                                   const float* __restrict__ g,
                                                   const float* __restrict__ bb,
                                                   bf16* __restrict__ out, int mode) {
  __shared__ float sm[CH * FFp];
  __shared__ float mu_s[FFp], rs_s[FFp];
  int bt = blockIdx.x;
  int b = bt / TT, t = bt % TT;
  const bf16* base = xin + ((size_t)b * CH * TT + t) * FFp;
  for (int idx = threadIdx.x; idx < CH * FFp; idx += 256) {
    int c = idx / FFp, f = idx % FFp;
    sm[idx] = b2f(base[(size_t)c * TT * FFp + f]);
  }
  __syncthreads();
  if (threadIdx.x < FFp) {
    int f = threadIdx.x;
    float s1 = 0.f, s2 = 0.f;
#pragma unroll
    for (int c = 0; c < CH; c++) { float v = sm[c * FFp + f]; s1 += v; s2 += v * v; }
    float mu = s1 / CH;
    float var = s2 / CH - mu * mu;
    mu_s[f] = mu;
    rs_s[f] = 1.f / (sqrtf(var + EPSf) + EPSf);
  }
  __syncthreads();
  for (int idx = threadIdx.x; idx < CH * FFp; idx += 256) {
    int c = idx / FFp, f = idx % FFp;
    float v = (sm[idx] - mu_s[f]) * rs_s[f] * g[c] + bb[c];
    size_t o;
    if (mode == 0) {
      o = ((size_t)(f >> 3) * N1 + bt) * 256 + c * 8 + (f & 7);
    } else {
      int n = b * FFp + f;
      o = ((size_t)(t >> 3) * N2 + n) * 256 + c * 8 + (t & 7);
    }
    out[o] = f2b(v);
  }
}

// ---------------- K5a: weight prep — reorder W=[wih|whh] into B-fragment blob ---------
// blob[nt(64)][ks(16)][lane(64)][j(8)], value = Wcat[n][k]:
//   n = nt*16 + (lane&15), k = ks*32 + (lane>>4)*8 + j
//   Wcat[n][k] = k<256 ? wih[n][k] : whh[n][k-256]
__global__ __launch_bounds__(256) void lstm_prep_k(const float* __restrict__ wih0,
                                                   const float* __restrict__ whh0,
                                                   bf16* __restrict__ blob0) {
  int dir = blockIdx.y;
  const float* wih = wih0 + (size_t)dir * 262144;
  const float* whh = whh0 + (size_t)dir * 262144;
  unsigned short* blob = (unsigned short*)(blob0 + (size_t)dir * 524288);
  int gid = blockIdx.x * 256 + threadIdx.x;     // 0..65535
  int lane = gid & 63;
  int ks = (gid >> 6) & 15;
  int nt = gid >> 10;
  int n = nt * 16 + (lane & 15);
  int kb = ks * 32 + (lane >> 4) * 8;
  unsigned short o8[8];
#pragma unroll
  for (int j = 0; j < 8; j++) {
    int k = kb + j;
    float v = (k < 256) ? wih[n * 256 + k] : whh[n * 256 + (k - 256)];
    o8[j] = f2bu(v);
  }
  *(uint4*)(blob + (size_t)gid * 8) = *(uint4*)o8;
}

// ---------------- K5b: MFMA LSTM, 512 threads (8 waves), double-buffered B stream -----
// Wave w owns n-tiles nt = q*16 + 2w + j (q=0..3 gate, j=0..1). acc[q][j]:
// row m=(lane>>4)*4+reg, d=(2w+j)*16+(lane&15). All 4 gates of (m,d) in one lane.
// A=[x_t;h] staged in LDS in frag order; B streamed from pre-reordered blob with
// 2-deep 8-frag prefetch (keeps ~16KB/wave in flight -> covers L2 latency).
__global__ __launch_bounds__(512) void lstm_mfma_k(const bf16* __restrict__ xz,
                                                   const bf16* __restrict__ blob0,
                                                   const float* __restrict__ bih0,
                                                   const float* __restrict__ bhh0,
                                                   bf16* __restrict__ hout,
                                                   int N, int Ls, int hstride, int bidir) {
  __shared__ short afr[16 * 64 * 8];     // 16 KB; slot = ks*64 + kg*16 + m (ks0-7 x, 8-15 h)
  int tid = threadIdx.x;
  int w = tid >> 6, lane = tid & 63;
  int l15 = lane & 15, lq = lane >> 4;
  int dir = blockIdx.y;
  const short* blob = (const short*)(blob0 + (size_t)dir * 524288);
  const float* bih = bih0 + dir * NG;
  const float* bhh = bhh0 + dir * NG;
  int hoff = dir * 256;
  int n0 = blockIdx.x * 16;
  unsigned short* houtu = (unsigned short*)hout;
  const short* xzs = (const short*)xz;

  float bias[4][2];
#pragma unroll
  for (int q = 0; q < 4; q++)
#pragma unroll
    for (int j = 0; j < 2; j++) {
      int n = q * 256 + (2 * w + j) * 16 + l15;
      bias[q][j] = bih[n] + bhh[n];
    }
  for (int i = tid; i < 8 * 64 * 8; i += 512) afr[8 * 64 * 8 + i] = 0;   // h frags = 0
  float cst[8];
#pragma unroll
  for (int i = 0; i < 8; i++) cst[i] = 0.f;

  int sm_ = tid & 15, sk8 = tid >> 4;                 // x-staging assignment (512 thr exact)
  int sslot = (sk8 >> 2) * 64 + (sk8 & 3) * 16 + sm_;

  for (int st = 0; st < Ls; st++) {
    int t = (bidir && dir) ? (Ls - 1 - st) : st;
    // stage x_t fragments (8 KB)
    {
      s16x8 v = *(const s16x8*)(xzs + ((size_t)t * N + n0 + sm_) * 256 + sk8 * 8);
      *(s16x8*)(&afr[sslot * 8]) = v;
    }
    // preload segment 0 of B (nt for q=0,j=0; ks 0..7) while barrier settles
    s16x8 bq[2][8];
    {
      const short* bp = blob + ((size_t)(2 * w) * 8192) + lane * 8;
#pragma unroll
      for (int k = 0; k < 8; k++) bq[0][k] = *(const s16x8*)(bp + k * 512);
    }
    __syncthreads();                       // x staged + prev h-writes visible
    s16x8 af[16];
#pragma unroll
    for (int ks = 0; ks < 16; ks++) af[ks] = *(const s16x8*)(&afr[(ks * 64 + lane) * 8]);
    __syncthreads();                       // all A-frag reads done before h overwrite

    f32x4 acc[4][2];
#pragma unroll
    for (int q = 0; q < 4; q++)
#pragma unroll
      for (int j = 0; j < 2; j++)
        acc[q][j] = (f32x4){bias[q][j], bias[q][j], bias[q][j], bias[q][j]};

    // 16 segments: seg s -> nt-idx = s>>1 (q=idx>>1, j=idx&1), ks half = s&1
#pragma unroll
    for (int s = 0; s < 16; s++) {
      int buf = s & 1;
      if (s < 15) {                        // prefetch next segment
        int i2 = (s + 1) >> 1;
        int q2 = i2 >> 1, j2 = i2 & 1;
        int nt2 = q2 * 16 + 2 * w + j2;
        const short* bp = blob + ((size_t)nt2 * 8192) + ((size_t)((s + 1) & 1) * 8) * 512 + lane * 8;
#pragma unroll
        for (int k = 0; k < 8; k++) bq[buf ^ 1][k] = *(const s16x8*)(bp + k * 512);
      }
      int idx = s >> 1;
      int q = idx >> 1, j = idx & 1;
      int kbase = (s & 1) * 8;
#pragma unroll
      for (int k = 0; k < 8; k++)
        acc[q][j] = __builtin_amdgcn_mfma_f32_16x16x32_bf16(af[kbase + k], bq[buf][k], acc[q][j], 0, 0, 0);
    }

    // epilogue: gates -> (h, c); h to global + h-frag LDS
#pragma unroll
    for (int j = 0; j < 2; j++) {
      int d = (2 * w + j) * 16 + l15;
      int slot = (8 + (d >> 5)) * 64 + ((d >> 3) & 3) * 16;
#pragma unroll
      for (int r = 0; r < 4; r++) {
        int m = lq * 4 + r;
        float iv = sigm(acc[0][j][r]);
        float fv = sigm(acc[1][j][r]);
        float gv = tanh_f(acc[2][j][r]);
        float ov = sigm(acc[3][j][r]);
        float c = fv * cst[j * 4 + r] + iv * gv;
        cst[j * 4 + r] = c;
        float h = ov * tanh_f(c);
        unsigned short hb = f2bu(h);
        houtu[((size_t)t * N + n0 + m) * hstride + hoff + d] = hb;
        afr[(slot + m) * 8 + (d & 7)] = (short)hb;
      }
    }
  }
}

// ---------------- K6: fold GEMM (M=84672, N=256) + bias + residual, scatter epilogue ---
// mode 0 (intra): res[b,c,t,l*8+k] = val + linb[c] + act[...]
// mode 1 (inter): if f<161: interc[b,c,l*8+k,f] = val + linb[c] + res[...]
__global__ __launch_bounds__(256) void fold_gemm_k(const bf16* __restrict__ A,
                                                   const float* __restrict__ Bw,
                                                   const float* __restrict__ linb,
                                                   const bf16* __restrict__ resid,
                                                   bf16* __restrict__ outp,
                                                   int K, int mode) {
  __shared__ float As[16 * 64];
  __shared__ float Bs[16 * 64];
  int tid = threadIdx.x;
  int n0 = blockIdx.x * 64;
  int m0 = blockIdx.y * 64;
  int tr = tid >> 4, tc = tid & 15;
  float acc[4][4] = {};
  int arow = tid >> 2, akg = (tid & 3) * 4;
  int bkk = tid >> 4, bc4 = (tid & 15) * 4;
  for (int k0 = 0; k0 < K; k0 += 16) {
    ushort4 avu = *(const ushort4*)((const unsigned short*)A + (size_t)(m0 + arow) * K + k0 + akg);
    float4 bv = *(const float4*)(Bw + (size_t)(k0 + bkk) * 256 + n0 + bc4);
    __syncthreads();
    As[(akg + 0) * 64 + arow] = us2f(avu.x);
    As[(akg + 1) * 64 + arow] = us2f(avu.y);
    As[(akg + 2) * 64 + arow] = us2f(avu.z);
    As[(akg + 3) * 64 + arow] = us2f(avu.w);
    *(float4*)(&Bs[bkk * 64 + bc4]) = bv;
    __syncthreads();
#pragma unroll
    for (int kk = 0; kk < 16; kk++) {
      float4 a4 = *(const float4*)(&As[kk * 64 + tr * 4]);
      float4 b4 = *(const float4*)(&Bs[kk * 64 + tc * 4]);
      float aa[4] = {a4.x, a4.y, a4.z, a4.w};
      float bb_[4] = {b4.x, b4.y, b4.z, b4.w};
#pragma unroll
      for (int i = 0; i < 4; i++)
#pragma unroll
        for (int j = 0; j < 4; j++) acc[i][j] += aa[i] * bb_[j];
    }
  }
#pragma unroll
  for (int i = 0; i < 4; i++) {
    int r = m0 + tr * 4 + i;
#pragma unroll
    for (int j = 0; j < 4; j++) {
      int col = n0 + tc * 4 + j;
      int c = col >> 3, kp = col & 7;
      float v = acc[i][j] + linb[c];
      if (mode == 0) {
        int l = r / N1, n = r % N1;
        int b = n / TT, t = n % TT;
        size_t o = ((size_t)(b * CH + c) * TT + t) * FFp + (l * 8 + kp);
        outp[o] = f2b(v + b2f(resid[o]));
      } else {
        int l = r / N2, n = r % N2;
        int b = n / FFp, fq = n % FFp;
        int t = l * 8 + kp;
        if (fq < OF) {
          size_t o = ((size_t)(b * CH + c) * TT + t) * OF + fq;
          size_t ri = ((size_t)(b * CH + c) * TT + t) * FFp + fq;
          outp[o] = f2b(v + b2f(resid[ri]));
        }
      }
    }
  }
}

// ---------------- K8: fused QKV projection + prelu + ln_cf_head ----------------
__global__ __launch_bounds__(256) void qkv_k(const bf16* __restrict__ interc,
    const float* __restrict__ qw, const float* __restrict__ qb, const float* __restrict__ qa,
    const float* __restrict__ qg, const float* __restrict__ qbeta,
    const float* __restrict__ kw, const float* __restrict__ kb, const float* __restrict__ ka,
    const float* __restrict__ kg, const float* __restrict__ kbeta,
    const float* __restrict__ vw, const float* __restrict__ vb, const float* __restrict__ va,
    const float* __restrict__ vg, const float* __restrict__ vbeta,
    bf16* __restrict__ qo, bf16* __restrict__ ko, bf16* __restrict__ vo) {
  __shared__ float sm[CH * OF];     // 5152
  __shared__ float wb[16 * 32];
  __shared__ float wbias[16];
  __shared__ float yb[16 * OF];     // 2576: [0:4) Q-e, [4:8) K-e, [8:16) V-cv
  __shared__ float red[8];
  int bt = blockIdx.x, h = blockIdx.y;
  int b = bt / TT, t = bt % TT;
  int tid = threadIdx.x;
  const bf16* src = interc + ((size_t)b * CH * TT + t) * OF;
  for (int idx = tid; idx < CH * OF; idx += 256) {
    int c = idx / OF, f = idx % OF;
    sm[idx] = b2f(src[(size_t)c * TT * OF + f]);
  }
  for (int idx = tid; idx < 512; idx += 256) {
    int e = idx >> 5, c = idx & 31;
    float w;
    if (e < 4) w = qw[(h * 4 + e) * 32 + c];
    else if (e < 8) w = kw[(h * 4 + e - 4) * 32 + c];
    else w = vw[(h * 8 + e - 8) * 32 + c];
    wb[idx] = w;
  }
  if (tid < 16) {
    float bv;
    if (tid < 4) bv = qb[h * 4 + tid];
    else if (tid < 8) bv = kb[h * 4 + tid - 4];
    else bv = vb[h * 8 + tid - 8];
    wbias[tid] = bv;
  }
  __syncthreads();
  float aQ = qa[h], aK = ka[h], aV = va[h];
  for (int idx = tid; idx < 16 * OF; idx += 256) {
    int e = idx / OF, f = idx % OF;
    float accv = wbias[e];
#pragma unroll
    for (int c = 0; c < 32; c++) accv += sm[c * OF + f] * wb[e * 32 + c];
    float a = e < 4 ? aQ : (e < 8 ? aK : aV);
    yb[idx] = accv >= 0.f ? accv : a * accv;
  }
  __syncthreads();
  for (int seg = 0; seg < 3; seg++) {
    int s0 = (seg == 0) ? 0 : ((seg == 1) ? 644 : 1288);
    int len = (seg == 2) ? 1288 : 644;
    float s1 = 0.f, s2 = 0.f;
    for (int i = tid; i < len; i += 256) { float v = yb[s0 + i]; s1 += v; s2 += v * v; }
    block_reduce2(s1, s2, red);
    float mu = s1 / len;
    float var = s2 / len - mu * mu;
    float rs = 1.f / (sqrtf(var + EPSf) + EPSf);
    const float* gp; const float* bp; bf16* op; int nch;
    if (seg == 0) { gp = qg; bp = qbeta; op = qo; nch = 4; }
    else if (seg == 1) { gp = kg; bp = kbeta; op = ko; nch = 4; }
    else { gp = vg; bp = vbeta; op = vo; nch = 8; }
    for (int i = tid; i < len; i += 256) {
      int e = i / OF, f = i % OF;
      float v = (yb[s0 + i] - mu) * rs * gp[(h * nch + e) * OF + f] + bp[(h * nch + e) * OF + f];
      op[(((size_t)(h * BB + b) * nch + e) * TT + t) * OF + f] = f2b(v);
    }
  }
}

// ---------------- K9: banded causal attention (lookback 5) ----------------
__global__ __launch_bounds__(256) void attn_k(const bf16* __restrict__ Q,
                                              const bf16* __restrict__ Kt,
                                              const bf16* __restrict__ V,
                                              bf16* __restrict__ O) {
  int t = blockIdx.x;
  int hb = blockIdx.y;            // h*8 + b
  int h = hb >> 3, b = hb & 7;
  int tid = threadIdx.x;
  int nv = min(t, 5) + 1;
  const float scale = 0.0394055201f;   // 1/sqrt(644)
  __shared__ float redl[24];
  float part[6] = {0, 0, 0, 0, 0, 0};
  size_t qkbase = ((size_t)(h * BB + b) * EE) * TT * OF;
  for (int i = tid; i < EE * OF; i += 256) {
    int e = i / OF, f = i % OF;
    float qv = b2f(Q[qkbase + ((size_t)e * TT + t) * OF + f]);
#pragma unroll
    for (int d = 0; d < 6; d++)
      if (d < nv) part[d] += qv * b2f(Kt[qkbase + ((size_t)e * TT + (t - d)) * OF + f]);
  }
#pragma unroll
  for (int d = 0; d < 6; d++)
#pragma unroll
    for (int off = 32; off > 0; off >>= 1) part[d] += __shfl_down(part[d], off, 64);
  int lane = tid & 63, wv = tid >> 6;
  if (lane == 0) {
#pragma unroll
    for (int d = 0; d < 6; d++) redl[wv * 6 + d] = part[d];
  }
  __syncthreads();
  float a[6], sv[6];
  float m = -1e30f;
#pragma unroll
  for (int d = 0; d < 6; d++)
    if (d < nv) {
      float s = (redl[d] + redl[6 + d] + redl[12 + d] + redl[18 + d]) * scale;
      sv[d] = s;
      m = fmaxf(m, s);
    }
  float denom = 0.f;
#pragma unroll
  for (int d = 0; d < 6; d++)
    if (d < nv) { a[d] = __expf(sv[d] - m); denom += a[d]; }
  float inv = 1.f / denom;
  size_t vbase = ((size_t)(h * BB + b) * CVv) * TT * OF;
  for (int i = tid; i < CVv * OF; i += 256) {
    int cv = i / OF, f = i % OF;
    float o = 0.f;
#pragma unroll
    for (int d = 0; d < 6; d++)
      if (d < nv) o += a[d] * b2f(V[vbase + ((size_t)cv * TT + (t - d)) * OF + f]);
    O[(((size_t)b * CH + h * CVv + cv) * TT + t) * OF + f] = f2b(o * inv);
  }
}

// ---------------- K10: proj + prelu + ln_cf_proj + residual + re-pad ----------------
__global__ __launch_bounds__(256) void proj_k(const bf16* __restrict__ ob,
                                              const float* __restrict__ pw,
                                              const float* __restrict__ pb,
                                              const float* __restrict__ pa,
                                              const float* __restrict__ pg,
                                              const float* __restrict__ pbeta,
                                              const bf16* __restrict__ interc,
                                              bf16* __restrict__ act) {
  __shared__ float sm[CH * OF];
  __shared__ float wsm[CH * CH];
  __shared__ float yb[CH * OF];
  __shared__ float red[8];
  int bt = blockIdx.x;
  int b = bt / TT, t = bt % TT;
  int tid = threadIdx.x;
  const bf16* src = ob + ((size_t)b * CH * TT + t) * OF;
  for (int idx = tid; idx < CH * OF; idx += 256) {
    int c = idx / OF, f = idx % OF;
    sm[idx] = b2f(src[(size_t)c * TT * OF + f]);
  }
  for (int idx = tid; idx < CH * CH; idx += 256) wsm[idx] = pw[idx];
  __syncthreads();
  float aP = pa[0];
  for (int idx = tid; idx < CH * OF; idx += 256) {
    int d = idx / OF, f = idx % OF;
    float accv = pb[d];
#pragma unroll
    for (int c = 0; c < 32; c++) accv += sm[c * OF + f] * wsm[d * 32 + c];
    yb[idx] = accv >= 0.f ? accv : aP * accv;
  }
  __syncthreads();
  float s1 = 0.f, s2 = 0.f;
  for (int i = tid; i < CH * OF; i += 256) { float v = yb[i]; s1 += v; s2 += v * v; }
  block_reduce2(s1, s2, red);
  const float Mn = (float)(CH * OF);
  float mu = s1 / Mn;
  float var = s2 / Mn - mu * mu;
  float rs = 1.f / (sqrtf(var + EPSf) + EPSf);
  for (int idx = tid; idx < CH * FFp; idx += 256) {
    int d = idx / FFp, f = idx % FFp;
    float v = 0.f;
    if (f < OF) {
      float y = (yb[d * OF + f] - mu) * rs * pg[d * OF + f] + pbeta[d * OF + f];
      v = y + b2f(interc[((size_t)(b * CH + d) * TT + t) * OF + f]);
    }
    act[((size_t)(b * CH + d) * TT + t) * FFp + f] = f2b(v);
  }
}

// ---------------- K11: output deconv (LDS-tiled 3x3 conv over 32ch) -------------------
// block per (b,t): stage 32ci x 3 rows of act in LDS (fp32, 63KB), thread owns f,
// 9-tap register neighborhood per ci reused for both output channels; uniform s_loads for w.
// NOTE: grid MUST be exactly B*TT = 4032 (block-per-(b,t)); larger grids write OOB.
__global__ __launch_bounds__(256) void deconv_k(const bf16* __restrict__ act,
                                                const float* __restrict__ w,
                                                const float* __restrict__ bias,
                                                float* __restrict__ out) {
  __shared__ float ash[CH * 3 * FFp];   // 64512 B
  int bt = blockIdx.x;
  int b = bt / TT, t = bt % TT;
  int tid = threadIdx.x;
  const short* acts = (const short*)act;
  for (int ch = tid; ch < CH * 3 * (FFp / 8); ch += 256) {   // 2016 chunks of 8
    int ci = ch / 63, rem = ch % 63;
    int rr = rem / 21, fc = rem % 21;
    int ts = t + rr - 1;
    float* dst = &ash[(ci * 3 + rr) * FFp + fc * 8];
    if (ts < 0 || ts >= TT) {
#pragma unroll
      for (int k2 = 0; k2 < 8; k2++) dst[k2] = 0.f;
    } else {
      s16x8 v = *(const s16x8*)(acts + ((size_t)(b * CH + ci) * TT + ts) * FFp + fc * 8);
#pragma unroll
      for (int k2 = 0; k2 < 8; k2++) dst[k2] = us2f((unsigned short)v[k2]);
    }
  }
  __syncthreads();
  int f = tid;
  if (f < OF) {
    float acc0 = bias[0], acc1 = bias[1];
#pragma unroll 4
    for (int ci = 0; ci < CH; ci++) {
      const float* row = &ash[ci * 3 * FFp];
      float xv[3][3];
#pragma unroll
      for (int kh = 0; kh < 3; kh++)
#pragma unroll
        for (int kw = 0; kw < 3; kw++) {
          int ff = f + kw - 1;
          xv[kh][kw] = (ff < 0) ? 0.f : row[kh * FFp + ff];   // ff==161 reads zero pad
        }
#pragma unroll
      for (int kh = 0; kh < 3; kh++)
#pragma unroll
        for (int kw = 0; kw < 3; kw++) {
          acc0 += xv[kh][kw] * w[((ci * 2 + 0) * 3 + (2 - kh)) * 3 + (2 - kw)];
          acc1 += xv[kh][kw] * w[((ci * 2 + 1) * 3 + (2 - kh)) * 3 + (2 - kw)];
        }
    }
    out[((size_t)(b * 2 + 0) * TT + t) * OF + f] = acc0;
    out[((size_t)(b * 2 + 1) * TT + t) * OF + f] = acc1;
  }
}

// ---------------- host launch ----------------
extern "C" void kernel_launch(void* const* d_in, const int* in_sizes, int n_in,
                              void* d_out, int out_size, void* d_ws, size_t ws_size,
                              hipStream_t stream) {
  const float* x            = (const float*)d_in[0];
  const float* conv_w       = (const float*)d_in[1];
  const float* conv_b       = (const float*)d_in[2];
  const float* gn_g         = (const float*)d_in[3];
  const float* gn_b         = (const float*)d_in[4];
  const float* intra_norm_g = (const float*)d_in[5];
  const float* intra_norm_b = (const float*)d_in[6];
  const float* intra_wih    = (const float*)d_in[7];
  const float* intra_whh    = (const float*)d_in[8];
  const float* intra_bih    = (const float*)d_in[9];
  const float* intra_bhh    = (const float*)d_in[10];
  const float* intra_lin_w  = (const float*)d_in[11];
  const float* intra_lin_b  = (const float*)d_in[12];
  const float* inter_norm_g = (const float*)d_in[13];
  const float* inter_norm_b = (const float*)d_in[14];
  const float* inter_wih    = (const float*)d_in[15];
  const float* inter_whh    = (const float*)d_in[16];
  const float* inter_bih    = (const float*)d_in[17];
  const float* inter_bhh    = (const float*)d_in[18];
  const float* inter_lin_w  = (const float*)d_in[19];
  const float* inter_lin_b  = (const float*)d_in[20];
  const float* q_w    = (const float*)d_in[21];
  const float* q_b    = (const float*)d_in[22];
  const float* q_a    = (const float*)d_in[23];
  const float* q_g    = (const float*)d_in[24];
  const float* q_beta = (const float*)d_in[25];
  const float* k_w    = (const float*)d_in[26];
  const float* k_b    = (const float*)d_in[27];
  const float* k_a    = (const float*)d_in[28];
  const float* k_g    = (const float*)d_in[29];
  const float* k_beta = (const float*)d_in[30];
  const float* v_w    = (const float*)d_in[31];
  const float* v_b    = (const float*)d_in[32];
  const float* v_a    = (const float*)d_in[33];
  const float* v_g    = (const float*)d_in[34];
  const float* v_beta = (const float*)d_in[35];
  const float* proj_w    = (const float*)d_in[36];
  const float* proj_b    = (const float*)d_in[37];
  const float* proj_a    = (const float*)d_in[38];
  const float* proj_g    = (const float*)d_in[39];
  const float* proj_beta = (const float*)d_in[40];
  const float* deconv_w  = (const float*)d_in[41];
  const float* deconv_b  = (const float*)d_in[42];

  // workspace: 256 B fp32 stats + bf16 arena of 129,153,024 elems = 246.3 MiB total.
  // Liveness-based aliasing:
  //   A act(21.676M)  B tmp(21.676M)  C hbuf(43.352M)  D res(21.676M)  E interc(20.773M)
  //   conv-out->E, qbuf->A, kbuf->B, vbuf->D, obuf->C (all dead at point of reuse)
  //   LSTM weight blobs overlay dead regions: intra blob -> D (dead until fold0),
  //   inter blob -> E (dead until fold1). Zero extra workspace.
  float* stats = (float*)d_ws;
  bf16* arena  = (bf16*)((char*)d_ws + 256);
  bf16* act    = arena;                  // A
  bf16* tmp    = arena + 21676032;       // B
  bf16* hbuf   = arena + 43352064;       // C
  bf16* res    = arena + 86704128;       // D
  bf16* interc = arena + 108380160;      // E  (end: 129,153,024)
  bf16* convout = interc;
  bf16* qbuf = act;
  bf16* kbuf = tmp;
  bf16* vbuf = res;
  bf16* obuf = hbuf;
  bf16* blob_intra = res;                // 2 x 524,288 bf16 = 2 MiB, dead until fold0
  bf16* blob_inter = interc;             // 524,288 bf16 = 1 MiB, dead until fold1

  hipMemsetAsync(stats, 0, 64 * sizeof(float), stream);
  conv_in_k<<<4032, 192, 0, stream>>>(x, conv_w, conv_b, convout);
  gn_reduce_k<<<512, 256, 0, stream>>>(convout, stats);
  gn_apply_k<<<84672, 256, 0, stream>>>(convout, stats, gn_g, gn_b, act);

  for (int l = 0; l < 4; l++) {
    lstm_prep_k<<<dim3(256, 2), 256, 0, stream>>>(
        intra_wih + (size_t)l * 524288, intra_whh + (size_t)l * 524288, blob_intra);
    ln_unfold_k<<<4032, 256, 0, stream>>>(act, intra_norm_g + l * 32, intra_norm_b + l * 32, tmp, 0);
    lstm_mfma_k<<<dim3(252, 2), 512, 0, stream>>>(
        tmp, blob_intra, intra_bih + l * 2048, intra_bhh + l * 2048, hbuf, N1, LFi, 512, 1);
    fold_gemm_k<<<dim3(4, 1323), 256, 0, stream>>>(
        hbuf, intra_lin_w + (size_t)l * 131072, intra_lin_b + l * 32, act, res, 512, 0);
    lstm_prep_k<<<dim3(256, 1), 256, 0, stream>>>(
        inter_wih + (size_t)l * 262144, inter_whh + (size_t)l * 262144, blob_inter);
    ln_unfold_k<<<4032, 256, 0, stream>>>(res, inter_norm_g + l * 32, inter_norm_b + l * 32, tmp, 1);
    lstm_mfma_k<<<dim3(84, 1), 512, 0, stream>>>(
        tmp, blob_inter, inter_bih + l * 1024, inter_bhh + l * 1024, hbuf, N2, LTi, 256, 0);
    fold_gemm_k<<<dim3(4, 1323), 256, 0, stream>>>(
        hbuf, inter_lin_w + (size_t)l * 65536, inter_lin_b + l * 32, res, interc, 256, 1);
    qkv_k<<<dim3(4032, 4), 256, 0, stream>>>(interc,
        q_w + l * 512, q_b + l * 16, q_a + l * 4, q_g + l * 2576, q_beta + l * 2576,
        k_w + l * 512, k_b + l * 16, k_a + l * 4, k_g + l * 2576, k_beta + l * 2576,
        v_w + l * 1024, v_b + l * 32, v_a + l * 4, v_g + l * 5152, v_beta + l * 5152,
        qbuf, kbuf, vbuf);
    attn_k<<<dim3(504, 32), 256, 0, stream>>>(qbuf, kbuf, vbuf, obuf);
    proj_k<<<4032, 256, 0, stream>>>(obuf, proj_w + l * 1024, proj_b + l * 32, proj_a + l,
                                     proj_g + l * 5152, proj_beta + l * 5152, interc, act);
  }
  deconv_k<<<4032, 256, 0, stream>>>(act, deconv_w, deconv_b, (float*)d_out);
}

// Round 6
// 19892.590 us; speedup vs baseline: 2.9599x; 1.0491x over previous
//
#include <hip/hip_runtime.h>
#include <hip/hip_bf16.h>
#include <math.h>

// ---------------- problem constants ----------------
#define BB   8
#define CH   32
#define TT   504
#define FFp  168      // padded F
#define OF   161      // original F
#define KSZ  8
#define HID  256
#define NG   1024     // 4*H
#define NHh  4
#define EE   4
#define CVv  8
#define N1   4032     // B*T  (intra seqs)
#define N2   1344     // B*Fp (inter seqs)
#define LFi  21       // F/KS
#define LTi  63       // T/KS
#define EPSf 1e-5f

typedef __hip_bfloat16 bf16;
typedef __attribute__((ext_vector_type(8))) short s16x8;
typedef __attribute__((ext_vector_type(4))) float f32x4;

__device__ __forceinline__ float b2f(bf16 v) { return __bfloat162float(v); }
__device__ __forceinline__ bf16 f2b(float v) { return __float2bfloat16(v); }
__device__ __forceinline__ float us2f(unsigned short u) {
  return __uint_as_float(((unsigned)u) << 16);
}
__device__ __forceinline__ unsigned short f2bu(float v) {   // RNE bf16 bits
  unsigned u = __float_as_uint(v);
  unsigned r = u + 0x7fffu + ((u >> 16) & 1u);
  return (unsigned short)(r >> 16);
}

__device__ __forceinline__ float sigm(float x) { return 1.f / (1.f + __expf(-x)); }
__device__ __forceinline__ float tanh_f(float x) {
  x = fminf(15.f, fmaxf(-15.f, x));
  float e = __expf(2.f * x);
  return (e - 1.f) / (e + 1.f);
}

// block = 256 threads (4 waves). red must be float[8] shared.
__device__ __forceinline__ void block_reduce2(float& s1, float& s2, float* red) {
#pragma unroll
  for (int off = 32; off > 0; off >>= 1) {
    s1 += __shfl_down(s1, off, 64);
    s2 += __shfl_down(s2, off, 64);
  }
  int lane = threadIdx.x & 63, wv = threadIdx.x >> 6;
  __syncthreads();
  if (lane == 0) { red[wv * 2] = s1; red[wv * 2 + 1] = s2; }
  __syncthreads();
  s1 = red[0] + red[2] + red[4] + red[6];
  s2 = red[1] + red[3] + red[5] + red[7];
}

// ---------------- K1: input conv 2->32, 3x3, pad 1 (LDS-tiled) ----------------
// block per (b,t); stage 2ci x 3 rows in LDS; thread owns f, reuses 18-val
// neighborhood in registers across all 32 output channels; weights via uniform s_loads.
__global__ __launch_bounds__(192) void conv_in_k(const float* __restrict__ x,
                                                 const float* __restrict__ w,
                                                 const float* __restrict__ bias,
                                                 bf16* __restrict__ out) {
  __shared__ float xs[2 * 3 * (OF + 3)];
  int bt = blockIdx.x;
  int b = bt / TT, t = bt % TT;
  int tid = threadIdx.x;
  for (int i = tid; i < 2 * 3 * (OF + 3); i += 192) {
    int ci = i / (3 * (OF + 3));
    int rem = i % (3 * (OF + 3));
    int rr = rem / (OF + 3);
    int f = rem % (OF + 3);
    int ts = t + rr - 1;
    float v = 0.f;
    if (ts >= 0 && ts < TT && f < OF) v = x[((size_t)(b * 2 + ci) * TT + ts) * OF + f];
    xs[i] = v;
  }
  __syncthreads();
  int f = tid;
  if (f < OF) {
    float xv[2][3][3];
#pragma unroll
    for (int ci = 0; ci < 2; ci++)
#pragma unroll
      for (int kh = 0; kh < 3; kh++)
#pragma unroll
        for (int kw = 0; kw < 3; kw++) {
          int ff = f + kw - 1;
          xv[ci][kh][kw] = (ff < 0) ? 0.f : xs[(ci * 3 + kh) * (OF + 3) + ff];
        }
    for (int co = 0; co < CH; co++) {
      float acc = bias[co];
#pragma unroll
      for (int ci = 0; ci < 2; ci++)
#pragma unroll
        for (int kh = 0; kh < 3; kh++)
#pragma unroll
          for (int kw = 0; kw < 3; kw++)
            acc += xv[ci][kh][kw] * w[((co * 2 + ci) * 3 + kh) * 3 + kw];
      out[((size_t)(b * CH + co) * TT + t) * OF + f] = f2b(acc);
    }
  }
}

// ---------------- K2/K3: global per-batch norm ----------------
__global__ __launch_bounds__(256) void gn_reduce_k(const bf16* __restrict__ xin,
                                                   float* __restrict__ stats) {
  const int M = CH * TT * OF;   // 2,596,608
  int b = blockIdx.x >> 6;
  int part = blockIdx.x & 63;
  const bf16* p = xin + (size_t)b * M;
  float s1 = 0.f, s2 = 0.f;
  for (int i = part * 256 + threadIdx.x; i < M; i += 64 * 256) {
    float v = b2f(p[i]);
    s1 += v; s2 += v * v;
  }
  __shared__ float red[8];
  block_reduce2(s1, s2, red);
  if (threadIdx.x == 0) {
    atomicAdd(&stats[b * 2], s1);
    atomicAdd(&stats[b * 2 + 1], s2);
  }
}

__global__ __launch_bounds__(256) void gn_apply_k(const bf16* __restrict__ xin,
                                                  const float* __restrict__ stats,
                                                  const float* __restrict__ g,
                                                  const float* __restrict__ bb,
                                                  bf16* __restrict__ act) {
  int gid = blockIdx.x * 256 + threadIdx.x;       // B*CH*TT*FFp = 21,676,032 exact
  int f = gid % FFp;
  int t = (gid / FFp) % TT;
  int c = (gid / (FFp * TT)) % CH;
  int b = gid / (FFp * TT * CH);
  float v = 0.f;
  if (f < OF) {
    const float M = (float)(CH * TT * OF);
    float mu = stats[b * 2] / M;
    float var = stats[b * 2 + 1] / M - mu * mu;
    float xv = b2f(xin[((size_t)(b * CH + c) * TT + t) * OF + f]);
    v = (xv - mu) * rsqrtf(var + EPSf) * g[c] + bb[c];   // NOTE: no outer +eps here
  }
  act[gid] = f2b(v);
}

// ---------------- K4: ln over channels + unfold to time-major LSTM input ----------------
// mode 0 (intra): out[(f/8)*N1 + b*TT+t][c*8 + f%8]
// mode 1 (inter): out[(t/8)*N2 + b*FFp+f][c*8 + t%8]
__global__ __launch_bounds__(256) void ln_unfold_k(const bf16* __restrict__ xin,
                                                   const float* __restrict__ g,
                                                   const float* __restrict__ bb,
                                                   bf16* __restrict__ out, int mode) {
  __shared__ float sm[CH * FFp];
  __shared__ float mu_s[FFp], rs_s[FFp];
  int bt = blockIdx.x;
  int b = bt / TT, t = bt % TT;
  const bf16* base = xin + ((size_t)b * CH * TT + t) * FFp;
  for (int idx = threadIdx.x; idx < CH * FFp; idx += 256) {
    int c = idx / FFp, f = idx % FFp;
    sm[idx] = b2f(base[(size_t)c * TT * FFp + f]);
  }
  __syncthreads();
  if (threadIdx.x < FFp) {
    int f = threadIdx.x;
    float s1 = 0.f, s2 = 0.f;
#pragma unroll
    for (int c = 0; c < CH; c++) { float v = sm[c * FFp + f]; s1 += v; s2 += v * v; }
    float mu = s1 / CH;
    float var = s2 / CH - mu * mu;
    mu_s[f] = mu;
    rs_s[f] = 1.f / (sqrtf(var + EPSf) + EPSf);
  }
  __syncthreads();
  for (int idx = threadIdx.x; idx < CH * FFp; idx += 256) {
    int c = idx / FFp, f = idx % FFp;
    float v = (sm[idx] - mu_s[f]) * rs_s[f] * g[c] + bb[c];
    size_t o;
    if (mode == 0) {
      o = ((size_t)(f >> 3) * N1 + bt) * 256 + c * 8 + (f & 7);
    } else {
      int n = b * FFp + f;
      o = ((size_t)(t >> 3) * N2 + n) * 256 + c * 8 + (t & 7);
    }
    out[o] = f2b(v);
  }
}

// ---------------- K5a: weight prep — reorder W=[wih|whh] into B-fragment blob ---------
// blob[nt(64)][ks(16)][lane(64)][j(8)], value = Wcat[n][k]:
//   n = nt*16 + (lane&15), k = ks*32 + (lane>>4)*8 + j
//   Wcat[n][k] = k<256 ? wih[n][k] : whh[n][k-256]
__global__ __launch_bounds__(256) void lstm_prep_k(const float* __restrict__ wih0,
                                                   const float* __restrict__ whh0,
                                                   bf16* __restrict__ blob0) {
  int dir = blockIdx.y;
  const float* wih = wih0 + (size_t)dir * 262144;
  const float* whh = whh0 + (size_t)dir * 262144;
  unsigned short* blob = (unsigned short*)(blob0 + (size_t)dir * 524288);
  int gid = blockIdx.x * 256 + threadIdx.x;     // 0..65535
  int lane = gid & 63;
  int ks = (gid >> 6) & 15;
  int nt = gid >> 10;
  int n = nt * 16 + (lane & 15);
  int kb = ks * 32 + (lane >> 4) * 8;
  unsigned short o8[8];
#pragma unroll
  for (int j = 0; j < 8; j++) {
    int k = kb + j;
    float v = (k < 256) ? wih[n * 256 + k] : whh[n * 256 + (k - 256)];
    o8[j] = f2bu(v);
  }
  *(uint4*)(blob + (size_t)gid * 8) = *(uint4*)o8;
}

// ---------------- K5b: MFMA LSTM, 512 threads (8 waves), double-buffered B stream -----
// Wave w owns n-tiles nt = q*16 + 2w + j (q=0..3 gate, j=0..1). acc[q][j]:
// row m=(lane>>4)*4+reg, d=(2w+j)*16+(lane&15). All 4 gates of (m,d) in one lane.
// A=[x_t;h] staged in LDS in frag order; B streamed from pre-reordered blob with
// 2-deep 8-frag prefetch.
// __launch_bounds__(512, 2): live set ~200 VGPR (af 64 + bq 64 + acc 32 + state/addr
// ~40). The default cap of 128 VGPR spilled ~70 regs to scratch -> 2 GB of TCC spill
// traffic per dispatch and serialized prefetch (round-5 counters). 2 waves/SIMD min
// -> 256-VGPR cap -> zero spill; 1 block/CU is fine.
__global__ __launch_bounds__(512, 2) void lstm_mfma_k(const bf16* __restrict__ xz,
                                                      const bf16* __restrict__ blob0,
                                                      const float* __restrict__ bih0,
                                                      const float* __restrict__ bhh0,
                                                      bf16* __restrict__ hout,
                                                      int N, int Ls, int hstride, int bidir) {
  __shared__ short afr[16 * 64 * 8];     // 16 KB; slot = ks*64 + kg*16 + m (ks0-7 x, 8-15 h)
  int tid = threadIdx.x;
  int w = tid >> 6, lane = tid & 63;
  int l15 = lane & 15, lq = lane >> 4;
  int dir = blockIdx.y;
  const short* blob = (const short*)(blob0 + (size_t)dir * 524288);
  const float* bih = bih0 + dir * NG;
  const float* bhh = bhh0 + dir * NG;
  int hoff = dir * 256;
  int n0 = blockIdx.x * 16;
  unsigned short* houtu = (unsigned short*)hout;
  const short* xzs = (const short*)xz;

  float bias[4][2];
#pragma unroll
  for (int q = 0; q < 4; q++)
#pragma unroll
    for (int j = 0; j < 2; j++) {
      int n = q * 256 + (2 * w + j) * 16 + l15;
      bias[q][j] = bih[n] + bhh[n];
    }
  for (int i = tid; i < 8 * 64 * 8; i += 512) afr[8 * 64 * 8 + i] = 0;   // h frags = 0
  float cst[8];
#pragma unroll
  for (int i = 0; i < 8; i++) cst[i] = 0.f;

  int sm_ = tid & 15, sk8 = tid >> 4;                 // x-staging assignment (512 thr exact)
  int sslot = (sk8 >> 2) * 64 + (sk8 & 3) * 16 + sm_;

  for (int st = 0; st < Ls; st++) {
    int t = (bidir && dir) ? (Ls - 1 - st) : st;
    // stage x_t fragments (8 KB)
    {
      s16x8 v = *(const s16x8*)(xzs + ((size_t)t * N + n0 + sm_) * 256 + sk8 * 8);
      *(s16x8*)(&afr[sslot * 8]) = v;
    }
    // preload segment 0 of B (nt for q=0,j=0; ks 0..7) while barrier settles
    s16x8 bq[2][8];
    {
      const short* bp = blob + ((size_t)(2 * w) * 8192) + lane * 8;
#pragma unroll
      for (int k = 0; k < 8; k++) bq[0][k] = *(const s16x8*)(bp + k * 512);
    }
    __syncthreads();                       // x staged + prev h-writes visible
    s16x8 af[16];
#pragma unroll
    for (int ks = 0; ks < 16; ks++) af[ks] = *(const s16x8*)(&afr[(ks * 64 + lane) * 8]);
    __syncthreads();                       // all A-frag reads done before h overwrite

    f32x4 acc[4][2];
#pragma unroll
    for (int q = 0; q < 4; q++)
#pragma unroll
      for (int j = 0; j < 2; j++)
        acc[q][j] = (f32x4){bias[q][j], bias[q][j], bias[q][j], bias[q][j]};

    // 16 segments: seg s -> nt-idx = s>>1 (q=idx>>1, j=idx&1), ks half = s&1
#pragma unroll
    for (int s = 0; s < 16; s++) {
      int buf = s & 1;
      if (s < 15) {                        // prefetch next segment
        int i2 = (s + 1) >> 1;
        int q2 = i2 >> 1, j2 = i2 & 1;
        int nt2 = q2 * 16 + 2 * w + j2;
        const short* bp = blob + ((size_t)nt2 * 8192) + ((size_t)((s + 1) & 1) * 8) * 512 + lane * 8;
#pragma unroll
        for (int k = 0; k < 8; k++) bq[buf ^ 1][k] = *(const s16x8*)(bp + k * 512);
      }
      int idx = s >> 1;
      int q = idx >> 1, j = idx & 1;
      int kbase = (s & 1) * 8;
#pragma unroll
      for (int k = 0; k < 8; k++)
        acc[q][j] = __builtin_amdgcn_mfma_f32_16x16x32_bf16(af[kbase + k], bq[buf][k], acc[q][j], 0, 0, 0);
    }

    // epilogue: gates -> (h, c); h to global + h-frag LDS
#pragma unroll
    for (int j = 0; j < 2; j++) {
      int d = (2 * w + j) * 16 + l15;
      int slot = (8 + (d >> 5)) * 64 + ((d >> 3) & 3) * 16;
#pragma unroll
      for (int r = 0; r < 4; r++) {
        int m = lq * 4 + r;
        float iv = sigm(acc[0][j][r]);
        float fv = sigm(acc[1][j][r]);
        float gv = tanh_f(acc[2][j][r]);
        float ov = sigm(acc[3][j][r]);
        float c = fv * cst[j * 4 + r] + iv * gv;
        cst[j * 4 + r] = c;
        float h = ov * tanh_f(c);
        unsigned short hb = f2bu(h);
        houtu[((size_t)t * N + n0 + m) * hstride + hoff + d] = hb;
        afr[(slot + m) * 8 + (d & 7)] = (short)hb;
      }
    }
  }
}

// ---------------- K6: fold GEMM (M=84672, N=256) + bias + residual, scatter epilogue ---
// mode 0 (intra): res[b,c,t,l*8+k] = val + linb[c] + act[...]
// mode 1 (inter): if f<161: interc[b,c,l*8+k,f] = val + linb[c] + res[...]
__global__ __launch_bounds__(256) void fold_gemm_k(const bf16* __restrict__ A,
                                                   const float* __restrict__ Bw,
                                                   const float* __restrict__ linb,
                                                   const bf16* __restrict__ resid,
                                                   bf16* __restrict__ outp,
                                                   int K, int mode) {
  __shared__ float As[16 * 64];
  __shared__ float Bs[16 * 64];
  int tid = threadIdx.x;
  int n0 = blockIdx.x * 64;
  int m0 = blockIdx.y * 64;
  int tr = tid >> 4, tc = tid & 15;
  float acc[4][4] = {};
  int arow = tid >> 2, akg = (tid & 3) * 4;
  int bkk = tid >> 4, bc4 = (tid & 15) * 4;
  for (int k0 = 0; k0 < K; k0 += 16) {
    ushort4 avu = *(const ushort4*)((const unsigned short*)A + (size_t)(m0 + arow) * K + k0 + akg);
    float4 bv = *(const float4*)(Bw + (size_t)(k0 + bkk) * 256 + n0 + bc4);
    __syncthreads();
    As[(akg + 0) * 64 + arow] = us2f(avu.x);
    As[(akg + 1) * 64 + arow] = us2f(avu.y);
    As[(akg + 2) * 64 + arow] = us2f(avu.z);
    As[(akg + 3) * 64 + arow] = us2f(avu.w);
    *(float4*)(&Bs[bkk * 64 + bc4]) = bv;
    __syncthreads();
#pragma unroll
    for (int kk = 0; kk < 16; kk++) {
      float4 a4 = *(const float4*)(&As[kk * 64 + tr * 4]);
      float4 b4 = *(const float4*)(&Bs[kk * 64 + tc * 4]);
      float aa[4] = {a4.x, a4.y, a4.z, a4.w};
      float bb_[4] = {b4.x, b4.y, b4.z, b4.w};
#pragma unroll
      for (int i = 0; i < 4; i++)
#pragma unroll
        for (int j = 0; j < 4; j++) acc[i][j] += aa[i] * bb_[j];
    }
  }
#pragma unroll
  for (int i = 0; i < 4; i++) {
    int r = m0 + tr * 4 + i;
#pragma unroll
    for (int j = 0; j < 4; j++) {
      int col = n0 + tc * 4 + j;
      int c = col >> 3, kp = col & 7;
      float v = acc[i][j] + linb[c];
      if (mode == 0) {
        int l = r / N1, n = r % N1;
        int b = n / TT, t = n % TT;
        size_t o = ((size_t)(b * CH + c) * TT + t) * FFp + (l * 8 + kp);
        outp[o] = f2b(v + b2f(resid[o]));
      } else {
        int l = r / N2, n = r % N2;
        int b = n / FFp, fq = n % FFp;
        int t = l * 8 + kp;
        if (fq < OF) {
          size_t o = ((size_t)(b * CH + c) * TT + t) * OF + fq;
          size_t ri = ((size_t)(b * CH + c) * TT + t) * FFp + fq;
          outp[o] = f2b(v + b2f(resid[ri]));
        }
      }
    }
  }
}

// ---------------- K8: fused QKV projection + prelu + ln_cf_head ----------------
__global__ __launch_bounds__(256) void qkv_k(const bf16* __restrict__ interc,
    const float* __restrict__ qw, const float* __restrict__ qb, const float* __restrict__ qa,
    const float* __restrict__ qg, const float* __restrict__ qbeta,
    const float* __restrict__ kw, const float* __restrict__ kb, const float* __restrict__ ka,
    const float* __restrict__ kg, const float* __restrict__ kbeta,
    const float* __restrict__ vw, const float* __restrict__ vb, const float* __restrict__ va,
    const float* __restrict__ vg, const float* __restrict__ vbeta,
    bf16* __restrict__ qo, bf16* __restrict__ ko, bf16* __restrict__ vo) {
  __shared__ float sm[CH * OF];     // 5152
  __shared__ float wb[16 * 32];
  __shared__ float wbias[16];
  __shared__ float yb[16 * OF];     // 2576: [0:4) Q-e, [4:8) K-e, [8:16) V-cv
  __shared__ float red[8];
  int bt = blockIdx.x, h = blockIdx.y;
  int b = bt / TT, t = bt % TT;
  int tid = threadIdx.x;
  const bf16* src = interc + ((size_t)b * CH * TT + t) * OF;
  for (int idx = tid; idx < CH * OF; idx += 256) {
    int c = idx / OF, f = idx % OF;
    sm[idx] = b2f(src[(size_t)c * TT * OF + f]);
  }
  for (int idx = tid; idx < 512; idx += 256) {
    int e = idx >> 5, c = idx & 31;
    float w;
    if (e < 4) w = qw[(h * 4 + e) * 32 + c];
    else if (e < 8) w = kw[(h * 4 + e - 4) * 32 + c];
    else w = vw[(h * 8 + e - 8) * 32 + c];
    wb[idx] = w;
  }
  if (tid < 16) {
    float bv;
    if (tid < 4) bv = qb[h * 4 + tid];
    else if (tid < 8) bv = kb[h * 4 + tid - 4];
    else bv = vb[h * 8 + tid - 8];
    wbias[tid] = bv;
  }
  __syncthreads();
  float aQ = qa[h], aK = ka[h], aV = va[h];
  for (int idx = tid; idx < 16 * OF; idx += 256) {
    int e = idx / OF, f = idx % OF;
    float accv = wbias[e];
#pragma unroll
    for (int c = 0; c < 32; c++) accv += sm[c * OF + f] * wb[e * 32 + c];
    float a = e < 4 ? aQ : (e < 8 ? aK : aV);
    yb[idx] = accv >= 0.f ? accv : a * accv;
  }
  __syncthreads();
  for (int seg = 0; seg < 3; seg++) {
    int s0 = (seg == 0) ? 0 : ((seg == 1) ? 644 : 1288);
    int len = (seg == 2) ? 1288 : 644;
    float s1 = 0.f, s2 = 0.f;
    for (int i = tid; i < len; i += 256) { float v = yb[s0 + i]; s1 += v; s2 += v * v; }
    block_reduce2(s1, s2, red);
    float mu = s1 / len;
    float var = s2 / len - mu * mu;
    float rs = 1.f / (sqrtf(var + EPSf) + EPSf);
    const float* gp; const float* bp; bf16* op; int nch;
    if (seg == 0) { gp = qg; bp = qbeta; op = qo; nch = 4; }
    else if (seg == 1) { gp = kg; bp = kbeta; op = ko; nch = 4; }
    else { gp = vg; bp = vbeta; op = vo; nch = 8; }
    for (int i = tid; i < len; i += 256) {
      int e = i / OF, f = i % OF;
      float v = (yb[s0 + i] - mu) * rs * gp[(h * nch + e) * OF + f] + bp[(h * nch + e) * OF + f];
      op[(((size_t)(h * BB + b) * nch + e) * TT + t) * OF + f] = f2b(v);
    }
  }
}

// ---------------- K9: banded causal attention (lookback 5) ----------------
__global__ __launch_bounds__(256) void attn_k(const bf16* __restrict__ Q,
                                              const bf16* __restrict__ Kt,
                                              const bf16* __restrict__ V,
                                              bf16* __restrict__ O) {
  int t = blockIdx.x;
  int hb = blockIdx.y;            // h*8 + b
  int h = hb >> 3, b = hb & 7;
  int tid = threadIdx.x;
  int nv = min(t, 5) + 1;
  const float scale = 0.0394055201f;   // 1/sqrt(644)
  __shared__ float redl[24];
  float part[6] = {0, 0, 0, 0, 0, 0};
  size_t qkbase = ((size_t)(h * BB + b) * EE) * TT * OF;
  for (int i = tid; i < EE * OF; i += 256) {
    int e = i / OF, f = i % OF;
    float qv = b2f(Q[qkbase + ((size_t)e * TT + t) * OF + f]);
#pragma unroll
    for (int d = 0; d < 6; d++)
      if (d < nv) part[d] += qv * b2f(Kt[qkbase + ((size_t)e * TT + (t - d)) * OF + f]);
  }
#pragma unroll
  for (int d = 0; d < 6; d++)
#pragma unroll
    for (int off = 32; off > 0; off >>= 1) part[d] += __shfl_down(part[d], off, 64);
  int lane = tid & 63, wv = tid >> 6;
  if (lane == 0) {
#pragma unroll
    for (int d = 0; d < 6; d++) redl[wv * 6 + d] = part[d];
  }
  __syncthreads();
  float a[6], sv[6];
  float m = -1e30f;
#pragma unroll
  for (int d = 0; d < 6; d++)
    if (d < nv) {
      float s = (redl[d] + redl[6 + d] + redl[12 + d] + redl[18 + d]) * scale;
      sv[d] = s;
      m = fmaxf(m, s);
    }
  float denom = 0.f;
#pragma unroll
  for (int d = 0; d < 6; d++)
    if (d < nv) { a[d] = __expf(sv[d] - m); denom += a[d]; }
  float inv = 1.f / denom;
  size_t vbase = ((size_t)(h * BB + b) * CVv) * TT * OF;
  for (int i = tid; i < CVv * OF; i += 256) {
    int cv = i / OF, f = i % OF;
    float o = 0.f;
#pragma unroll
    for (int d = 0; d < 6; d++)
      if (d < nv) o += a[d] * b2f(V[vbase + ((size_t)cv * TT + (t - d)) * OF + f]);
    O[(((size_t)b * CH + h * CVv + cv) * TT + t) * OF + f] = f2b(o * inv);
  }
}

// ---------------- K10: proj + prelu + ln_cf_proj + residual + re-pad ----------------
__global__ __launch_bounds__(256) void proj_k(const bf16* __restrict__ ob,
                                              const float* __restrict__ pw,
                                              const float* __restrict__ pb,
                                              const float* __restrict__ pa,
                                              const float* __restrict__ pg,
                                              const float* __restrict__ pbeta,
                                              const bf16* __restrict__ interc,
                                              bf16* __restrict__ act) {
  __shared__ float sm[CH * OF];
  __shared__ float wsm[CH * CH];
  __shared__ float yb[CH * OF];
  __shared__ float red[8];
  int bt = blockIdx.x;
  int b = bt / TT, t = bt % TT;
  int tid = threadIdx.x;
  const bf16* src = ob + ((size_t)b * CH * TT + t) * OF;
  for (int idx = tid; idx < CH * OF; idx += 256) {
    int c = idx / OF, f = idx % OF;
    sm[idx] = b2f(src[(size_t)c * TT * OF + f]);
  }
  for (int idx = tid; idx < CH * CH; idx += 256) wsm[idx] = pw[idx];
  __syncthreads();
  float aP = pa[0];
  for (int idx = tid; idx < CH * OF; idx += 256) {
    int d = idx / OF, f = idx % OF;
    float accv = pb[d];
#pragma unroll
    for (int c = 0; c < 32; c++) accv += sm[c * OF + f] * wsm[d * 32 + c];
    yb[idx] = accv >= 0.f ? accv : aP * accv;
  }
  __syncthreads();
  float s1 = 0.f, s2 = 0.f;
  for (int i = tid; i < CH * OF; i += 256) { float v = yb[i]; s1 += v; s2 += v * v; }
  block_reduce2(s1, s2, red);
  const float Mn = (float)(CH * OF);
  float mu = s1 / Mn;
  float var = s2 / Mn - mu * mu;
  float rs = 1.f / (sqrtf(var + EPSf) + EPSf);
  for (int idx = tid; idx < CH * FFp; idx += 256) {
    int d = idx / FFp, f = idx % FFp;
    float v = 0.f;
    if (f < OF) {
      float y = (yb[d * OF + f] - mu) * rs * pg[d * OF + f] + pbeta[d * OF + f];
      v = y + b2f(interc[((size_t)(b * CH + d) * TT + t) * OF + f]);
    }
    act[((size_t)(b * CH + d) * TT + t) * FFp + f] = f2b(v);
  }
}

// ---------------- K11: output deconv (LDS-tiled 3x3 conv over 32ch) -------------------
// block per (b,t): stage 32ci x 3 rows of act in LDS (fp32, 63KB), thread owns f,
// 9-tap register neighborhood per ci reused for both output channels; uniform s_loads for w.
// NOTE: grid MUST be exactly B*TT = 4032 (block-per-(b,t)); larger grids write OOB.
__global__ __launch_bounds__(256) void deconv_k(const bf16* __restrict__ act,
                                                const float* __restrict__ w,
                                                const float* __restrict__ bias,
                                                float* __restrict__ out) {
  __shared__ float ash[CH * 3 * FFp];   // 64512 B
  int bt = blockIdx.x;
  int b = bt / TT, t = bt % TT;
  int tid = threadIdx.x;
  const short* acts = (const short*)act;
  for (int ch = tid; ch < CH * 3 * (FFp / 8); ch += 256) {   // 2016 chunks of 8
    int ci = ch / 63, rem = ch % 63;
    int rr = rem / 21, fc = rem % 21;
    int ts = t + rr - 1;
    float* dst = &ash[(ci * 3 + rr) * FFp + fc * 8];
    if (ts < 0 || ts >= TT) {
#pragma unroll
      for (int k2 = 0; k2 < 8; k2++) dst[k2] = 0.f;
    } else {
      s16x8 v = *(const s16x8*)(acts + ((size_t)(b * CH + ci) * TT + ts) * FFp + fc * 8);
#pragma unroll
      for (int k2 = 0; k2 < 8; k2++) dst[k2] = us2f((unsigned short)v[k2]);
    }
  }
  __syncthreads();
  int f = tid;
  if (f < OF) {
    float acc0 = bias[0], acc1 = bias[1];
#pragma unroll 4
    for (int ci = 0; ci < CH; ci++) {
      const float* row = &ash[ci * 3 * FFp];
      float xv[3][3];
#pragma unroll
      for (int kh = 0; kh < 3; kh++)
#pragma unroll
        for (int kw = 0; kw < 3; kw++) {
          int ff = f + kw - 1;
          xv[kh][kw] = (ff < 0) ? 0.f : row[kh * FFp + ff];   // ff==161 reads zero pad
        }
#pragma unroll
      for (int kh = 0; kh < 3; kh++)
#pragma unroll
        for (int kw = 0; kw < 3; kw++) {
          acc0 += xv[kh][kw] * w[((ci * 2 + 0) * 3 + (2 - kh)) * 3 + (2 - kw)];
          acc1 += xv[kh][kw] * w[((ci * 2 + 1) * 3 + (2 - kh)) * 3 + (2 - kw)];
        }
    }
    out[((size_t)(b * 2 + 0) * TT + t) * OF + f] = acc0;
    out[((size_t)(b * 2 + 1) * TT + t) * OF + f] = acc1;
  }
}

// ---------------- host launch ----------------
extern "C" void kernel_launch(void* const* d_in, const int* in_sizes, int n_in,
                              void* d_out, int out_size, void* d_ws, size_t ws_size,
                              hipStream_t stream) {
  const float* x            = (const float*)d_in[0];
  const float* conv_w       = (const float*)d_in[1];
  const float* conv_b       = (const float*)d_in[2];
  const float* gn_g         = (const float*)d_in[3];
  const float* gn_b         = (const float*)d_in[4];
  const float* intra_norm_g = (const float*)d_in[5];
  const float* intra_norm_b = (const float*)d_in[6];
  const float* intra_wih    = (const float*)d_in[7];
  const float* intra_whh    = (const float*)d_in[8];
  const float* intra_bih    = (const float*)d_in[9];
  const float* intra_bhh    = (const float*)d_in[10];
  const float* intra_lin_w  = (const float*)d_in[11];
  const float* intra_lin_b  = (const float*)d_in[12];
  const float* inter_norm_g = (const float*)d_in[13];
  const float* inter_norm_b = (const float*)d_in[14];
  const float* inter_wih    = (const float*)d_in[15];
  const float* inter_whh    = (const float*)d_in[16];
  const float* inter_bih    = (const float*)d_in[17];
  const float* inter_bhh    = (const float*)d_in[18];
  const float* inter_lin_w  = (const float*)d_in[19];
  const float* inter_lin_b  = (const float*)d_in[20];
  const float* q_w    = (const float*)d_in[21];
  const float* q_b    = (const float*)d_in[22];
  const float* q_a    = (const float*)d_in[23];
  const float* q_g    = (const float*)d_in[24];
  const float* q_beta = (const float*)d_in[25];
  const float* k_w    = (const float*)d_in[26];
  const float* k_b    = (const float*)d_in[27];
  const float* k_a    = (const float*)d_in[28];
  const float* k_g    = (const float*)d_in[29];
  const float* k_beta = (const float*)d_in[30];
  const float* v_w    = (const float*)d_in[31];
  const float* v_b    = (const float*)d_in[32];
  const float* v_a    = (const float*)d_in[33];
  const float* v_g    = (const float*)d_in[34];
  const float* v_beta = (const float*)d_in[35];
  const float* proj_w    = (const float*)d_in[36];
  const float* proj_b    = (const float*)d_in[37];
  const float* proj_a    = (const float*)d_in[38];
  const float* proj_g    = (const float*)d_in[39];
  const float* proj_beta = (const float*)d_in[40];
  const float* deconv_w  = (const float*)d_in[41];
  const float* deconv_b  = (const float*)d_in[42];

  // workspace: 256 B fp32 stats + bf16 arena of 129,153,024 elems = 246.3 MiB total.
  // Liveness-based aliasing:
  //   A act(21.676M)  B tmp(21.676M)  C hbuf(43.352M)  D res(21.676M)  E interc(20.773M)
  //   conv-out->E, qbuf->A, kbuf->B, vbuf->D, obuf->C (all dead at point of reuse)
  //   LSTM weight blobs overlay dead regions: intra blob -> D (dead until fold0),
  //   inter blob -> E (dead until fold1). Zero extra workspace.
  float* stats = (float*)d_ws;
  bf16* arena  = (bf16*)((char*)d_ws + 256);
  bf16* act    = arena;                  // A
  bf16* tmp    = arena + 21676032;       // B
  bf16* hbuf   = arena + 43352064;       // C
  bf16* res    = arena + 86704128;       // D
  bf16* interc = arena + 108380160;      // E  (end: 129,153,024)
  bf16* convout = interc;
  bf16* qbuf = act;
  bf16* kbuf = tmp;
  bf16* vbuf = res;
  bf16* obuf = hbuf;
  bf16* blob_intra = res;                // 2 x 524,288 bf16 = 2 MiB, dead until fold0
  bf16* blob_inter = interc;             // 524,288 bf16 = 1 MiB, dead until fold1

  hipMemsetAsync(stats, 0, 64 * sizeof(float), stream);
  conv_in_k<<<4032, 192, 0, stream>>>(x, conv_w, conv_b, convout);
  gn_reduce_k<<<512, 256, 0, stream>>>(convout, stats);
  gn_apply_k<<<84672, 256, 0, stream>>>(convout, stats, gn_g, gn_b, act);

  for (int l = 0; l < 4; l++) {
    lstm_prep_k<<<dim3(256, 2), 256, 0, stream>>>(
        intra_wih + (size_t)l * 524288, intra_whh + (size_t)l * 524288, blob_intra);
    ln_unfold_k<<<4032, 256, 0, stream>>>(act, intra_norm_g + l * 32, intra_norm_b + l * 32, tmp, 0);
    lstm_mfma_k<<<dim3(252, 2), 512, 0, stream>>>(
        tmp, blob_intra, intra_bih + l * 2048, intra_bhh + l * 2048, hbuf, N1, LFi, 512, 1);
    fold_gemm_k<<<dim3(4, 1323), 256, 0, stream>>>(
        hbuf, intra_lin_w + (size_t)l * 131072, intra_lin_b + l * 32, act, res, 512, 0);
    lstm_prep_k<<<dim3(256, 1), 256, 0, stream>>>(
        inter_wih + (size_t)l * 262144, inter_whh + (size_t)l * 262144, blob_inter);
    ln_unfold_k<<<4032, 256, 0, stream>>>(res, inter_norm_g + l * 32, inter_norm_b + l * 32, tmp, 1);
    lstm_mfma_k<<<dim3(84, 1), 512, 0, stream>>>(
        tmp, blob_inter, inter_bih + l * 1024, inter_bhh + l * 1024, hbuf, N2, LTi, 256, 0);
    fold_gemm_k<<<dim3(4, 1323), 256, 0, stream>>>(
        hbuf, inter_lin_w + (size_t)l * 65536, inter_lin_b + l * 32, res, interc, 256, 1);
    qkv_k<<<dim3(4032, 4), 256, 0, stream>>>(interc,
        q_w + l * 512, q_b + l * 16, q_a + l * 4, q_g + l * 2576, q_beta + l * 2576,
        k_w + l * 512, k_b + l * 16, k_a + l * 4, k_g + l * 2576, k_beta + l * 2576,
        v_w + l * 1024, v_b + l * 32, v_a + l * 4, v_g + l * 5152, v_beta + l * 5152,
        qbuf, kbuf, vbuf);
    attn_k<<<dim3(504, 32), 256, 0, stream>>>(qbuf, kbuf, vbuf, obuf);
    proj_k<<<4032, 256, 0, stream>>>(obuf, proj_w + l * 1024, proj_b + l * 32, proj_a + l,
                                     proj_g + l * 5152, proj_beta + l * 5152, interc, act);
  }
  deconv_k<<<4032, 256, 0, stream>>>(act, deconv_w, deconv_b, (float*)d_out);
}

// Round 7
// 19589.040 us; speedup vs baseline: 3.0058x; 1.0155x over previous
//
#include <hip/hip_runtime.h>
#include <hip/hip_bf16.h>
#include <math.h>

// ---------------- problem constants ----------------
#define BB   8
#define CH   32
#define TT   504
#define FFp  168      // padded F
#define OF   161      // original F
#define KSZ  8
#define HID  256
#define NG   1024     // 4*H
#define NHh  4
#define EE   4
#define CVv  8
#define N1   4032     // B*T  (intra seqs)
#define N2   1344     // B*Fp (inter seqs)
#define LFi  21       // F/KS
#define LTi  63       // T/KS
#define EPSf 1e-5f

typedef __hip_bfloat16 bf16;
typedef __attribute__((ext_vector_type(8))) short s16x8;
typedef __attribute__((ext_vector_type(4))) float f32x4;

__device__ __forceinline__ float b2f(bf16 v) { return __bfloat162float(v); }
__device__ __forceinline__ bf16 f2b(float v) { return __float2bfloat16(v); }
__device__ __forceinline__ float us2f(unsigned short u) {
  return __uint_as_float(((unsigned)u) << 16);
}
__device__ __forceinline__ unsigned short f2bu(float v) {   // RNE bf16 bits
  unsigned u = __float_as_uint(v);
  unsigned r = u + 0x7fffu + ((u >> 16) & 1u);
  return (unsigned short)(r >> 16);
}

__device__ __forceinline__ float sigm(float x) { return 1.f / (1.f + __expf(-x)); }
__device__ __forceinline__ float tanh_f(float x) {
  x = fminf(15.f, fmaxf(-15.f, x));
  float e = __expf(2.f * x);
  return (e - 1.f) / (e + 1.f);
}

// block = 256 threads (4 waves). red must be float[8] shared.
__device__ __forceinline__ void block_reduce2(float& s1, float& s2, float* red) {
#pragma unroll
  for (int off = 32; off > 0; off >>= 1) {
    s1 += __shfl_down(s1, off, 64);
    s2 += __shfl_down(s2, off, 64);
  }
  int lane = threadIdx.x & 63, wv = threadIdx.x >> 6;
  __syncthreads();
  if (lane == 0) { red[wv * 2] = s1; red[wv * 2 + 1] = s2; }
  __syncthreads();
  s1 = red[0] + red[2] + red[4] + red[6];
  s2 = red[1] + red[3] + red[5] + red[7];
}

// ---------------- K1: input conv 2->32, 3x3, pad 1 (LDS-tiled) ----------------
__global__ __launch_bounds__(192) void conv_in_k(const float* __restrict__ x,
                                                 const float* __restrict__ w,
                                                 const float* __restrict__ bias,
                                                 bf16* __restrict__ out) {
  __shared__ float xs[2 * 3 * (OF + 3)];
  int bt = blockIdx.x;
  int b = bt / TT, t = bt % TT;
  int tid = threadIdx.x;
  for (int i = tid; i < 2 * 3 * (OF + 3); i += 192) {
    int ci = i / (3 * (OF + 3));
    int rem = i % (3 * (OF + 3));
    int rr = rem / (OF + 3);
    int f = rem % (OF + 3);
    int ts = t + rr - 1;
    float v = 0.f;
    if (ts >= 0 && ts < TT && f < OF) v = x[((size_t)(b * 2 + ci) * TT + ts) * OF + f];
    xs[i] = v;
  }
  __syncthreads();
  int f = tid;
  if (f < OF) {
    float xv[2][3][3];
#pragma unroll
    for (int ci = 0; ci < 2; ci++)
#pragma unroll
      for (int kh = 0; kh < 3; kh++)
#pragma unroll
        for (int kw = 0; kw < 3; kw++) {
          int ff = f + kw - 1;
          xv[ci][kh][kw] = (ff < 0) ? 0.f : xs[(ci * 3 + kh) * (OF + 3) + ff];
        }
    for (int co = 0; co < CH; co++) {
      float acc = bias[co];
#pragma unroll
      for (int ci = 0; ci < 2; ci++)
#pragma unroll
        for (int kh = 0; kh < 3; kh++)
#pragma unroll
          for (int kw = 0; kw < 3; kw++)
            acc += xv[ci][kh][kw] * w[((co * 2 + ci) * 3 + kh) * 3 + kw];
      out[((size_t)(b * CH + co) * TT + t) * OF + f] = f2b(acc);
    }
  }
}

// ---------------- K2/K3: global per-batch norm ----------------
__global__ __launch_bounds__(256) void gn_reduce_k(const bf16* __restrict__ xin,
                                                   float* __restrict__ stats) {
  const int M = CH * TT * OF;   // 2,596,608
  int b = blockIdx.x >> 6;
  int part = blockIdx.x & 63;
  const bf16* p = xin + (size_t)b * M;
  float s1 = 0.f, s2 = 0.f;
  for (int i = part * 256 + threadIdx.x; i < M; i += 64 * 256) {
    float v = b2f(p[i]);
    s1 += v; s2 += v * v;
  }
  __shared__ float red[8];
  block_reduce2(s1, s2, red);
  if (threadIdx.x == 0) {
    atomicAdd(&stats[b * 2], s1);
    atomicAdd(&stats[b * 2 + 1], s2);
  }
}

__global__ __launch_bounds__(256) void gn_apply_k(const bf16* __restrict__ xin,
                                                  const float* __restrict__ stats,
                                                  const float* __restrict__ g,
                                                  const float* __restrict__ bb,
                                                  bf16* __restrict__ act) {
  int gid = blockIdx.x * 256 + threadIdx.x;       // B*CH*TT*FFp = 21,676,032 exact
  int f = gid % FFp;
  int t = (gid / FFp) % TT;
  int c = (gid / (FFp * TT)) % CH;
  int b = gid / (FFp * TT * CH);
  float v = 0.f;
  if (f < OF) {
    const float M = (float)(CH * TT * OF);
    float mu = stats[b * 2] / M;
    float var = stats[b * 2 + 1] / M - mu * mu;
    float xv = b2f(xin[((size_t)(b * CH + c) * TT + t) * OF + f]);
    v = (xv - mu) * rsqrtf(var + EPSf) * g[c] + bb[c];   // NOTE: no outer +eps here
  }
  act[gid] = f2b(v);
}

// ---------------- K4: ln over channels + unfold to time-major LSTM input ----------------
// mode 0 (intra): out[(f/8)*N1 + b*TT+t][c*8 + f%8]
// mode 1 (inter): out[(t/8)*N2 + b*FFp+f][c*8 + t%8]
__global__ __launch_bounds__(256) void ln_unfold_k(const bf16* __restrict__ xin,
                                                   const float* __restrict__ g,
                                                   const float* __restrict__ bb,
                                                   bf16* __restrict__ out, int mode) {
  __shared__ float sm[CH * FFp];
  __shared__ float mu_s[FFp], rs_s[FFp];
  int bt = blockIdx.x;
  int b = bt / TT, t = bt % TT;
  const bf16* base = xin + ((size_t)b * CH * TT + t) * FFp;
  for (int idx = threadIdx.x; idx < CH * FFp; idx += 256) {
    int c = idx / FFp, f = idx % FFp;
    sm[idx] = b2f(base[(size_t)c * TT * FFp + f]);
  }
  __syncthreads();
  if (threadIdx.x < FFp) {
    int f = threadIdx.x;
    float s1 = 0.f, s2 = 0.f;
#pragma unroll
    for (int c = 0; c < CH; c++) { float v = sm[c * FFp + f]; s1 += v; s2 += v * v; }
    float mu = s1 / CH;
    float var = s2 / CH - mu * mu;
    mu_s[f] = mu;
    rs_s[f] = 1.f / (sqrtf(var + EPSf) + EPSf);
  }
  __syncthreads();
  for (int idx = threadIdx.x; idx < CH * FFp; idx += 256) {
    int c = idx / FFp, f = idx % FFp;
    float v = (sm[idx] - mu_s[f]) * rs_s[f] * g[c] + bb[c];
    size_t o;
    if (mode == 0) {
      o = ((size_t)(f >> 3) * N1 + bt) * 256 + c * 8 + (f & 7);
    } else {
      int n = b * FFp + f;
      o = ((size_t)(t >> 3) * N2 + n) * 256 + c * 8 + (t & 7);
    }
    out[o] = f2b(v);
  }
}

// ---------------- K5a: weight prep — reorder W=[wih|whh] into B-fragment blob ---------
// blob[nt(64)][ks(16)][lane(64)][j(8)], value = Wcat[n][k]:
//   n = nt*16 + (lane&15), k = ks*32 + (lane>>4)*8 + j
//   Wcat[n][k] = k<256 ? wih[n][k] : whh[n][k-256]
__global__ __launch_bounds__(256) void lstm_prep_k(const float* __restrict__ wih0,
                                                   const float* __restrict__ whh0,
                                                   bf16* __restrict__ blob0) {
  int dir = blockIdx.y;
  const float* wih = wih0 + (size_t)dir * 262144;
  const float* whh = whh0 + (size_t)dir * 262144;
  unsigned short* blob = (unsigned short*)(blob0 + (size_t)dir * 524288);
  int gid = blockIdx.x * 256 + threadIdx.x;     // 0..65535
  int lane = gid & 63;
  int ks = (gid >> 6) & 15;
  int nt = gid >> 10;
  int n = nt * 16 + (lane & 15);
  int kb = ks * 32 + (lane >> 4) * 8;
  unsigned short o8[8];
#pragma unroll
  for (int j = 0; j < 8; j++) {
    int k = kb + j;
    float v = (k < 256) ? wih[n * 256 + k] : whh[n * 256 + (k - 256)];
    o8[j] = f2bu(v);
  }
  *(uint4*)(blob + (size_t)gid * 8) = *(uint4*)o8;
}

// ---------------- K5b: MFMA LSTM, 512 threads (8 waves) ----------------
// Register-budgeted rewrite (R6 post-mortem: allocator caps at 128 arch VGPRs and the
// old 64+64-reg prefetch scheme spilled ~70 regs -> 2-4 GB scratch traffic/dispatch).
// Live set now ~110: A-frags held 8-at-a-time per ks-phase (32 VGPR), B double-buffered
// in 4-frag batches (32 VGPR), acc in AGPRs. 32 batches/step, 4 MFMAs each.
// Barrier layout per step: [stage x | preload B0] BARRIER-A [phase loop: ds_read af,
// 16 batches] BARRIER-B [epilogue writes h to afr+global]. x-slots (0-7) and h-slots
// (8-15) are disjoint, so staging(t+1) never races epilogue(t).
__global__ __launch_bounds__(512) void lstm_mfma_k(const bf16* __restrict__ xz,
                                                   const bf16* __restrict__ blob0,
                                                   const float* __restrict__ bih0,
                                                   const float* __restrict__ bhh0,
                                                   bf16* __restrict__ hout,
                                                   int N, int Ls, int hstride, int bidir) {
  __shared__ short afr[16 * 64 * 8];     // 16 KB; slot = ks*64 + kg*16 + m (ks0-7 x, 8-15 h)
  int tid = threadIdx.x;
  int w = tid >> 6, lane = tid & 63;
  int l15 = lane & 15, lq = lane >> 4;
  int dir = blockIdx.y;
  const short* blob = (const short*)(blob0 + (size_t)dir * 524288);
  const float* bih = bih0 + dir * NG;
  const float* bhh = bhh0 + dir * NG;
  int hoff = dir * 256;
  int n0 = blockIdx.x * 16;
  unsigned short* houtu = (unsigned short*)hout;
  const short* xzs = (const short*)xz;

  float bias[4][2];
#pragma unroll
  for (int q = 0; q < 4; q++)
#pragma unroll
    for (int j = 0; j < 2; j++) {
      int n = q * 256 + (2 * w + j) * 16 + l15;
      bias[q][j] = bih[n] + bhh[n];
    }
  for (int i = tid; i < 8 * 64 * 8; i += 512) afr[8 * 64 * 8 + i] = 0;   // h frags = 0
  float cst[8];
#pragma unroll
  for (int i = 0; i < 8; i++) cst[i] = 0.f;

  int sm_ = tid & 15, sk8 = tid >> 4;                 // x-staging assignment (512 thr exact)
  int sslot = (sk8 >> 2) * 64 + (sk8 & 3) * 16 + sm_;

  for (int st = 0; st < Ls; st++) {
    int t = (bidir && dir) ? (Ls - 1 - st) : st;
    // stage x_t fragments (8 KB)
    {
      s16x8 v = *(const s16x8*)(xzs + ((size_t)t * N + n0 + sm_) * 256 + sk8 * 8);
      *(s16x8*)(&afr[sslot * 8]) = v;
    }
    // preload batch 0 of B: phase 0, nt=2w, frags 0..3
    s16x8 bq[2][4];
    {
      const short* bp = blob + ((size_t)(2 * w) * 8192) + lane * 8;
#pragma unroll
      for (int k = 0; k < 4; k++) bq[0][k] = *(const s16x8*)(bp + k * 512);
    }
    __syncthreads();                       // BARRIER-A: x staged + prev h visible

    f32x4 acc[4][2];
#pragma unroll
    for (int q = 0; q < 4; q++)
#pragma unroll
      for (int j = 0; j < 2; j++)
        acc[q][j] = (f32x4){bias[q][j], bias[q][j], bias[q][j], bias[q][j]};

#pragma unroll
    for (int p = 0; p < 2; p++) {          // ks halves: p=0 -> x part, p=1 -> h part
      s16x8 af[8];
#pragma unroll
      for (int k = 0; k < 8; k++)
        af[k] = *(const s16x8*)(&afr[((p * 8 + k) * 64 + lane) * 8]);
#pragma unroll
      for (int bi = 0; bi < 16; bi++) {    // idx = bi>>1 (nt within wave), h2 = bi&1
        int buf = bi & 1;
        if (!(p == 1 && bi == 15)) {       // prefetch next batch
          int g = p * 16 + bi + 1;
          int np = g >> 4, nb = g & 15;
          int nidx = nb >> 1, nh2 = nb & 1;
          int nnt = (nidx >> 1) * 16 + 2 * w + (nidx & 1);
          const short* bp = blob + ((size_t)nnt * 8192) +
                            ((size_t)(np * 8 + nh2 * 4)) * 512 + lane * 8;
#pragma unroll
          for (int k = 0; k < 4; k++) bq[buf ^ 1][k] = *(const s16x8*)(bp + k * 512);
        }
        int idx = bi >> 1, h2 = bi & 1;
        int q = idx >> 1, j = idx & 1;
#pragma unroll
        for (int k = 0; k < 4; k++)
          acc[q][j] = __builtin_amdgcn_mfma_f32_16x16x32_bf16(af[h2 * 4 + k], bq[buf][k],
                                                              acc[q][j], 0, 0, 0);
      }
    }
    __syncthreads();                       // BARRIER-B: all afr reads done before h overwrite

    // epilogue: gates -> (h, c); h to global + h-frag LDS
#pragma unroll
    for (int j = 0; j < 2; j++) {
      int d = (2 * w + j) * 16 + l15;
      int slot = (8 + (d >> 5)) * 64 + ((d >> 3) & 3) * 16;
#pragma unroll
      for (int r = 0; r < 4; r++) {
        int m = lq * 4 + r;
        float iv = sigm(acc[0][j][r]);
        float fv = sigm(acc[1][j][r]);
        float gv = tanh_f(acc[2][j][r]);
        float ov = sigm(acc[3][j][r]);
        float c = fv * cst[j * 4 + r] + iv * gv;
        cst[j * 4 + r] = c;
        float h = ov * tanh_f(c);
        unsigned short hb = f2bu(h);
        houtu[((size_t)t * N + n0 + m) * hstride + hoff + d] = hb;
        afr[(slot + m) * 8 + (d & 7)] = (short)hb;
      }
    }
  }
}

// ---------------- K6: fold GEMM (M=84672, N=256) + bias + residual, scatter epilogue ---
// As padded to stride 68 (R6: stride-64 scalar writes hit bank = arow mod 32 -> 4-way
// conflict; 68 -> 2-way max, 16B-aligned rows preserved for b128 reads).
__global__ __launch_bounds__(256) void fold_gemm_k(const bf16* __restrict__ A,
                                                   const float* __restrict__ Bw,
                                                   const float* __restrict__ linb,
                                                   const bf16* __restrict__ resid,
                                                   bf16* __restrict__ outp,
                                                   int K, int mode) {
  __shared__ float As[16 * 68];
  __shared__ float Bs[16 * 64];
  int tid = threadIdx.x;
  int n0 = blockIdx.x * 64;
  int m0 = blockIdx.y * 64;
  int tr = tid >> 4, tc = tid & 15;
  float acc[4][4] = {};
  int arow = tid >> 2, akg = (tid & 3) * 4;
  int bkk = tid >> 4, bc4 = (tid & 15) * 4;
  for (int k0 = 0; k0 < K; k0 += 16) {
    ushort4 avu = *(const ushort4*)((const unsigned short*)A + (size_t)(m0 + arow) * K + k0 + akg);
    float4 bv = *(const float4*)(Bw + (size_t)(k0 + bkk) * 256 + n0 + bc4);
    __syncthreads();
    As[(akg + 0) * 68 + arow] = us2f(avu.x);
    As[(akg + 1) * 68 + arow] = us2f(avu.y);
    As[(akg + 2) * 68 + arow] = us2f(avu.z);
    As[(akg + 3) * 68 + arow] = us2f(avu.w);
    *(float4*)(&Bs[bkk * 64 + bc4]) = bv;
    __syncthreads();
#pragma unroll
    for (int kk = 0; kk < 16; kk++) {
      float4 a4 = *(const float4*)(&As[kk * 68 + tr * 4]);
      float4 b4 = *(const float4*)(&Bs[kk * 64 + tc * 4]);
      float aa[4] = {a4.x, a4.y, a4.z, a4.w};
      float bb_[4] = {b4.x, b4.y, b4.z, b4.w};
#pragma unroll
      for (int i = 0; i < 4; i++)
#pragma unroll
        for (int j = 0; j < 4; j++) acc[i][j] += aa[i] * bb_[j];
    }
  }
#pragma unroll
  for (int i = 0; i < 4; i++) {
    int r = m0 + tr * 4 + i;
#pragma unroll
    for (int j = 0; j < 4; j++) {
      int col = n0 + tc * 4 + j;
      int c = col >> 3, kp = col & 7;
      float v = acc[i][j] + linb[c];
      if (mode == 0) {
        int l = r / N1, n = r % N1;
        int b = n / TT, t = n % TT;
        size_t o = ((size_t)(b * CH + c) * TT + t) * FFp + (l * 8 + kp);
        outp[o] = f2b(v + b2f(resid[o]));
      } else {
        int l = r / N2, n = r % N2;
        int b = n / FFp, fq = n % FFp;
        int t = l * 8 + kp;
        if (fq < OF) {
          size_t o = ((size_t)(b * CH + c) * TT + t) * OF + fq;
          size_t ri = ((size_t)(b * CH + c) * TT + t) * FFp + fq;
          outp[o] = f2b(v + b2f(resid[ri]));
        }
      }
    }
  }
}

// ---------------- K8: fused QKV projection + prelu + ln_cf_head ----------------
__global__ __launch_bounds__(256) void qkv_k(const bf16* __restrict__ interc,
    const float* __restrict__ qw, const float* __restrict__ qb, const float* __restrict__ qa,
    const float* __restrict__ qg, const float* __restrict__ qbeta,
    const float* __restrict__ kw, const float* __restrict__ kb, const float* __restrict__ ka,
    const float* __restrict__ kg, const float* __restrict__ kbeta,
    const float* __restrict__ vw, const float* __restrict__ vb, const float* __restrict__ va,
    const float* __restrict__ vg, const float* __restrict__ vbeta,
    bf16* __restrict__ qo, bf16* __restrict__ ko, bf16* __restrict__ vo) {
  __shared__ float sm[CH * OF];     // 5152
  __shared__ float wb[16 * 32];
  __shared__ float wbias[16];
  __shared__ float yb[16 * OF];     // 2576: [0:4) Q-e, [4:8) K-e, [8:16) V-cv
  __shared__ float red[8];
  int bt = blockIdx.x, h = blockIdx.y;
  int b = bt / TT, t = bt % TT;
  int tid = threadIdx.x;
  const bf16* src = interc + ((size_t)b * CH * TT + t) * OF;
  for (int idx = tid; idx < CH * OF; idx += 256) {
    int c = idx / OF, f = idx % OF;
    sm[idx] = b2f(src[(size_t)c * TT * OF + f]);
  }
  for (int idx = tid; idx < 512; idx += 256) {
    int e = idx >> 5, c = idx & 31;
    float w;
    if (e < 4) w = qw[(h * 4 + e) * 32 + c];
    else if (e < 8) w = kw[(h * 4 + e - 4) * 32 + c];
    else w = vw[(h * 8 + e - 8) * 32 + c];
    wb[idx] = w;
  }
  if (tid < 16) {
    float bv;
    if (tid < 4) bv = qb[h * 4 + tid];
    else if (tid < 8) bv = kb[h * 4 + tid - 4];
    else bv = vb[h * 8 + tid - 8];
    wbias[tid] = bv;
  }
  __syncthreads();
  float aQ = qa[h], aK = ka[h], aV = va[h];
  for (int idx = tid; idx < 16 * OF; idx += 256) {
    int e = idx / OF, f = idx % OF;
    float accv = wbias[e];
#pragma unroll
    for (int c = 0; c < 32; c++) accv += sm[c * OF + f] * wb[e * 32 + c];
    float a = e < 4 ? aQ : (e < 8 ? aK : aV);
    yb[idx] = accv >= 0.f ? accv : a * accv;
  }
  __syncthreads();
  for (int seg = 0; seg < 3; seg++) {
    int s0 = (seg == 0) ? 0 : ((seg == 1) ? 644 : 1288);
    int len = (seg == 2) ? 1288 : 644;
    float s1 = 0.f, s2 = 0.f;
    for (int i = tid; i < len; i += 256) { float v = yb[s0 + i]; s1 += v; s2 += v * v; }
    block_reduce2(s1, s2, red);
    float mu = s1 / len;
    float var = s2 / len - mu * mu;
    float rs = 1.f / (sqrtf(var + EPSf) + EPSf);
    const float* gp; const float* bp; bf16* op; int nch;
    if (seg == 0) { gp = qg; bp = qbeta; op = qo; nch = 4; }
    else if (seg == 1) { gp = kg; bp = kbeta; op = ko; nch = 4; }
    else { gp = vg; bp = vbeta; op = vo; nch = 8; }
    for (int i = tid; i < len; i += 256) {
      int e = i / OF, f = i % OF;
      float v = (yb[s0 + i] - mu) * rs * gp[(h * nch + e) * OF + f] + bp[(h * nch + e) * OF + f];
      op[(((size_t)(h * BB + b) * nch + e) * TT + t) * OF + f] = f2b(v);
    }
  }
}

// ---------------- K9: banded causal attention (lookback 5) ----------------
__global__ __launch_bounds__(256) void attn_k(const bf16* __restrict__ Q,
                                              const bf16* __restrict__ Kt,
                                              const bf16* __restrict__ V,
                                              bf16* __restrict__ O) {
  int t = blockIdx.x;
  int hb = blockIdx.y;            // h*8 + b
  int h = hb >> 3, b = hb & 7;
  int tid = threadIdx.x;
  int nv = min(t, 5) + 1;
  const float scale = 0.0394055201f;   // 1/sqrt(644)
  __shared__ float redl[24];
  float part[6] = {0, 0, 0, 0, 0, 0};
  size_t qkbase = ((size_t)(h * BB + b) * EE) * TT * OF;
  for (int i = tid; i < EE * OF; i += 256) {
    int e = i / OF, f = i % OF;
    float qv = b2f(Q[qkbase + ((size_t)e * TT + t) * OF + f]);
#pragma unroll
    for (int d = 0; d < 6; d++)
      if (d < nv) part[d] += qv * b2f(Kt[qkbase + ((size_t)e * TT + (t - d)) * OF + f]);
  }
#pragma unroll
  for (int d = 0; d < 6; d++)
#pragma unroll
    for (int off = 32; off > 0; off >>= 1) part[d] += __shfl_down(part[d], off, 64);
  int lane = tid & 63, wv = tid >> 6;
  if (lane == 0) {
#pragma unroll
    for (int d = 0; d < 6; d++) redl[wv * 6 + d] = part[d];
  }
  __syncthreads();
  float a[6], sv[6];
  float m = -1e30f;
#pragma unroll
  for (int d = 0; d < 6; d++)
    if (d < nv) {
      float s = (redl[d] + redl[6 + d] + redl[12 + d] + redl[18 + d]) * scale;
      sv[d] = s;
      m = fmaxf(m, s);
    }
  float denom = 0.f;
#pragma unroll
  for (int d = 0; d < 6; d++)
    if (d < nv) { a[d] = __expf(sv[d] - m); denom += a[d]; }
  float inv = 1.f / denom;
  size_t vbase = ((size_t)(h * BB + b) * CVv) * TT * OF;
  for (int i = tid; i < CVv * OF; i += 256) {
    int cv = i / OF, f = i % OF;
    float o = 0.f;
#pragma unroll
    for (int d = 0; d < 6; d++)
      if (d < nv) o += a[d] * b2f(V[vbase + ((size_t)cv * TT + (t - d)) * OF + f]);
    O[(((size_t)b * CH + h * CVv + cv) * TT + t) * OF + f] = f2b(o * inv);
  }
}

// ---------------- K10: proj + prelu + ln_cf_proj + residual + re-pad ----------------
__global__ __launch_bounds__(256) void proj_k(const bf16* __restrict__ ob,
                                              const float* __restrict__ pw,
                                              const float* __restrict__ pb,
                                              const float* __restrict__ pa,
                                              const float* __restrict__ pg,
                                              const float* __restrict__ pbeta,
                                              const bf16* __restrict__ interc,
                                              bf16* __restrict__ act) {
  __shared__ float sm[CH * OF];
  __shared__ float wsm[CH * CH];
  __shared__ float yb[CH * OF];
  __shared__ float red[8];
  int bt = blockIdx.x;
  int b = bt / TT, t = bt % TT;
  int tid = threadIdx.x;
  const bf16* src = ob + ((size_t)b * CH * TT + t) * OF;
  for (int idx = tid; idx < CH * OF; idx += 256) {
    int c = idx / OF, f = idx % OF;
    sm[idx] = b2f(src[(size_t)c * TT * OF + f]);
  }
  for (int idx = tid; idx < CH * CH; idx += 256) wsm[idx] = pw[idx];
  __syncthreads();
  float aP = pa[0];
  for (int idx = tid; idx < CH * OF; idx += 256) {
    int d = idx / OF, f = idx % OF;
    float accv = pb[d];
#pragma unroll
    for (int c = 0; c < 32; c++) accv += sm[c * OF + f] * wsm[d * 32 + c];
    yb[idx] = accv >= 0.f ? accv : aP * accv;
  }
  __syncthreads();
  float s1 = 0.f, s2 = 0.f;
  for (int i = tid; i < CH * OF; i += 256) { float v = yb[i]; s1 += v; s2 += v * v; }
  block_reduce2(s1, s2, red);
  const float Mn = (float)(CH * OF);
  float mu = s1 / Mn;
  float var = s2 / Mn - mu * mu;
  float rs = 1.f / (sqrtf(var + EPSf) + EPSf);
  for (int idx = tid; idx < CH * FFp; idx += 256) {
    int d = idx / FFp, f = idx % FFp;
    float v = 0.f;
    if (f < OF) {
      float y = (yb[d * OF + f] - mu) * rs * pg[d * OF + f] + pbeta[d * OF + f];
      v = y + b2f(interc[((size_t)(b * CH + d) * TT + t) * OF + f]);
    }
    act[((size_t)(b * CH + d) * TT + t) * FFp + f] = f2b(v);
  }
}

// ---------------- K11: output deconv (LDS-tiled 3x3 conv over 32ch) -------------------
// NOTE: grid MUST be exactly B*TT = 4032 (block-per-(b,t)); larger grids write OOB.
__global__ __launch_bounds__(256) void deconv_k(const bf16* __restrict__ act,
                                                const float* __restrict__ w,
                                                const float* __restrict__ bias,
                                                float* __restrict__ out) {
  __shared__ float ash[CH * 3 * FFp];   // 64512 B
  int bt = blockIdx.x;
  int b = bt / TT, t = bt % TT;
  int tid = threadIdx.x;
  const short* acts = (const short*)act;
  for (int ch = tid; ch < CH * 3 * (FFp / 8); ch += 256) {   // 2016 chunks of 8
    int ci = ch / 63, rem = ch % 63;
    int rr = rem / 21, fc = rem % 21;
    int ts = t + rr - 1;
    float* dst = &ash[(ci * 3 + rr) * FFp + fc * 8];
    if (ts < 0 || ts >= TT) {
#pragma unroll
      for (int k2 = 0; k2 < 8; k2++) dst[k2] = 0.f;
    } else {
      s16x8 v = *(const s16x8*)(acts + ((size_t)(b * CH + ci) * TT + ts) * FFp + fc * 8);
#pragma unroll
      for (int k2 = 0; k2 < 8; k2++) dst[k2] = us2f((unsigned short)v[k2]);
    }
  }
  __syncthreads();
  int f = tid;
  if (f < OF) {
    float acc0 = bias[0], acc1 = bias[1];
#pragma unroll 4
    for (int ci = 0; ci < CH; ci++) {
      const float* row = &ash[ci * 3 * FFp];
      float xv[3][3];
#pragma unroll
      for (int kh = 0; kh < 3; kh++)
#pragma unroll
        for (int kw = 0; kw < 3; kw++) {
          int ff = f + kw - 1;
          xv[kh][kw] = (ff < 0) ? 0.f : row[kh * FFp + ff];   // ff==161 reads zero pad
        }
#pragma unroll
      for (int kh = 0; kh < 3; kh++)
#pragma unroll
        for (int kw = 0; kw < 3; kw++) {
          acc0 += xv[kh][kw] * w[((ci * 2 + 0) * 3 + (2 - kh)) * 3 + (2 - kw)];
          acc1 += xv[kh][kw] * w[((ci * 2 + 1) * 3 + (2 - kh)) * 3 + (2 - kw)];
        }
    }
    out[((size_t)(b * 2 + 0) * TT + t) * OF + f] = acc0;
    out[((size_t)(b * 2 + 1) * TT + t) * OF + f] = acc1;
  }
}

// ---------------- host launch ----------------
extern "C" void kernel_launch(void* const* d_in, const int* in_sizes, int n_in,
                              void* d_out, int out_size, void* d_ws, size_t ws_size,
                              hipStream_t stream) {
  const float* x            = (const float*)d_in[0];
  const float* conv_w       = (const float*)d_in[1];
  const float* conv_b       = (const float*)d_in[2];
  const float* gn_g         = (const float*)d_in[3];
  const float* gn_b         = (const float*)d_in[4];
  const float* intra_norm_g = (const float*)d_in[5];
  const float* intra_norm_b = (const float*)d_in[6];
  const float* intra_wih    = (const float*)d_in[7];
  const float* intra_whh    = (const float*)d_in[8];
  const float* intra_bih    = (const float*)d_in[9];
  const float* intra_bhh    = (const float*)d_in[10];
  const float* intra_lin_w  = (const float*)d_in[11];
  const float* intra_lin_b  = (const float*)d_in[12];
  const float* inter_norm_g = (const float*)d_in[13];
  const float* inter_norm_b = (const float*)d_in[14];
  const float* inter_wih    = (const float*)d_in[15];
  const float* inter_whh    = (const float*)d_in[16];
  const float* inter_bih    = (const float*)d_in[17];
  const float* inter_bhh    = (const float*)d_in[18];
  const float* inter_lin_w  = (const float*)d_in[19];
  const float* inter_lin_b  = (const float*)d_in[20];
  const float* q_w    = (const float*)d_in[21];
  const float* q_b    = (const float*)d_in[22];
  const float* q_a    = (const float*)d_in[23];
  const float* q_g    = (const float*)d_in[24];
  const float* q_beta = (const float*)d_in[25];
  const float* k_w    = (const float*)d_in[26];
  const float* k_b    = (const float*)d_in[27];
  const float* k_a    = (const float*)d_in[28];
  const float* k_g    = (const float*)d_in[29];
  const float* k_beta = (const float*)d_in[30];
  const float* v_w    = (const float*)d_in[31];
  const float* v_b    = (const float*)d_in[32];
  const float* v_a    = (const float*)d_in[33];
  const float* v_g    = (const float*)d_in[34];
  const float* v_beta = (const float*)d_in[35];
  const float* proj_w    = (const float*)d_in[36];
  const float* proj_b    = (const float*)d_in[37];
  const float* proj_a    = (const float*)d_in[38];
  const float* proj_g    = (const float*)d_in[39];
  const float* proj_beta = (const float*)d_in[40];
  const float* deconv_w  = (const float*)d_in[41];
  const float* deconv_b  = (const float*)d_in[42];

  // workspace: 256 B fp32 stats + bf16 arena of 129,153,024 elems = 246.3 MiB total.
  // Liveness-based aliasing:
  //   A act(21.676M)  B tmp(21.676M)  C hbuf(43.352M)  D res(21.676M)  E interc(20.773M)
  //   conv-out->E, qbuf->A, kbuf->B, vbuf->D, obuf->C (all dead at point of reuse)
  //   LSTM weight blobs overlay dead regions: intra blob -> D (dead until fold0),
  //   inter blob -> E (dead until fold1). Zero extra workspace.
  float* stats = (float*)d_ws;
  bf16* arena  = (bf16*)((char*)d_ws + 256);
  bf16* act    = arena;                  // A
  bf16* tmp    = arena + 21676032;       // B
  bf16* hbuf   = arena + 43352064;       // C
  bf16* res    = arena + 86704128;       // D
  bf16* interc = arena + 108380160;      // E  (end: 129,153,024)
  bf16* convout = interc;
  bf16* qbuf = act;
  bf16* kbuf = tmp;
  bf16* vbuf = res;
  bf16* obuf = hbuf;
  bf16* blob_intra = res;                // 2 x 524,288 bf16 = 2 MiB, dead until fold0
  bf16* blob_inter = interc;             // 524,288 bf16 = 1 MiB, dead until fold1

  hipMemsetAsync(stats, 0, 64 * sizeof(float), stream);
  conv_in_k<<<4032, 192, 0, stream>>>(x, conv_w, conv_b, convout);
  gn_reduce_k<<<512, 256, 0, stream>>>(convout, stats);
  gn_apply_k<<<84672, 256, 0, stream>>>(convout, stats, gn_g, gn_b, act);

  for (int l = 0; l < 4; l++) {
    lstm_prep_k<<<dim3(256, 2), 256, 0, stream>>>(
        intra_wih + (size_t)l * 524288, intra_whh + (size_t)l * 524288, blob_intra);
    ln_unfold_k<<<4032, 256, 0, stream>>>(act, intra_norm_g + l * 32, intra_norm_b + l * 32, tmp, 0);
    lstm_mfma_k<<<dim3(252, 2), 512, 0, stream>>>(
        tmp, blob_intra, intra_bih + l * 2048, intra_bhh + l * 2048, hbuf, N1, LFi, 512, 1);
    fold_gemm_k<<<dim3(4, 1323), 256, 0, stream>>>(
        hbuf, intra_lin_w + (size_t)l * 131072, intra_lin_b + l * 32, act, res, 512, 0);
    lstm_prep_k<<<dim3(256, 1), 256, 0, stream>>>(
        inter_wih + (size_t)l * 262144, inter_whh + (size_t)l * 262144, blob_inter);
    ln_unfold_k<<<4032, 256, 0, stream>>>(res, inter_norm_g + l * 32, inter_norm_b + l * 32, tmp, 1);
    lstm_mfma_k<<<dim3(84, 1), 512, 0, stream>>>(
        tmp, blob_inter, inter_bih + l * 1024, inter_bhh + l * 1024, hbuf, N2, LTi, 256, 0);
    fold_gemm_k<<<dim3(4, 1323), 256, 0, stream>>>(
        hbuf, inter_lin_w + (size_t)l * 65536, inter_lin_b + l * 32, res, interc, 256, 1);
    qkv_k<<<dim3(4032, 4), 256, 0, stream>>>(interc,
        q_w + l * 512, q_b + l * 16, q_a + l * 4, q_g + l * 2576, q_beta + l * 2576,
        k_w + l * 512, k_b + l * 16, k_a + l * 4, k_g + l * 2576, k_beta + l * 2576,
        v_w + l * 1024, v_b + l * 32, v_a + l * 4, v_g + l * 5152, v_beta + l * 5152,
        qbuf, kbuf, vbuf);
    attn_k<<<dim3(504, 32), 256, 0, stream>>>(qbuf, kbuf, vbuf, obuf);
    proj_k<<<4032, 256, 0, stream>>>(obuf, proj_w + l * 1024, proj_b + l * 32, proj_a + l,
                                     proj_g + l * 5152, proj_beta + l * 5152, interc, act);
  }
  deconv_k<<<4032, 256, 0, stream>>>(act, deconv_w, deconv_b, (float*)d_out);
}

// Round 8
// 19511.497 us; speedup vs baseline: 3.0177x; 1.0040x over previous
//
#include <hip/hip_runtime.h>
#include <hip/hip_bf16.h>
#include <math.h>

// ---------------- problem constants ----------------
#define BB   8
#define CH   32
#define TT   504
#define FFp  168      // padded F
#define OF   161      // original F
#define KSZ  8
#define HID  256
#define NG   1024     // 4*H
#define NHh  4
#define EE   4
#define CVv  8
#define N1   4032     // B*T  (intra seqs)
#define N2   1344     // B*Fp (inter seqs)
#define LFi  21       // F/KS
#define LTi  63       // T/KS
#define EPSf 1e-5f

typedef __hip_bfloat16 bf16;
typedef __attribute__((ext_vector_type(8))) short s16x8;
typedef __attribute__((ext_vector_type(4))) float f32x4;

__device__ __forceinline__ float b2f(bf16 v) { return __bfloat162float(v); }
__device__ __forceinline__ bf16 f2b(float v) { return __float2bfloat16(v); }
__device__ __forceinline__ float us2f(unsigned short u) {
  return __uint_as_float(((unsigned)u) << 16);
}
__device__ __forceinline__ unsigned short f2bu(float v) {   // RNE bf16 bits
  unsigned u = __float_as_uint(v);
  unsigned r = u + 0x7fffu + ((u >> 16) & 1u);
  return (unsigned short)(r >> 16);
}

__device__ __forceinline__ float sigm(float x) { return 1.f / (1.f + __expf(-x)); }
__device__ __forceinline__ float tanh_f(float x) {
  x = fminf(15.f, fmaxf(-15.f, x));
  float e = __expf(2.f * x);
  return (e - 1.f) / (e + 1.f);
}

// block = 256 threads (4 waves). red must be float[8] shared.
__device__ __forceinline__ void block_reduce2(float& s1, float& s2, float* red) {
#pragma unroll
  for (int off = 32; off > 0; off >>= 1) {
    s1 += __shfl_down(s1, off, 64);
    s2 += __shfl_down(s2, off, 64);
  }
  int lane = threadIdx.x & 63, wv = threadIdx.x >> 6;
  __syncthreads();
  if (lane == 0) { red[wv * 2] = s1; red[wv * 2 + 1] = s2; }
  __syncthreads();
  s1 = red[0] + red[2] + red[4] + red[6];
  s2 = red[1] + red[3] + red[5] + red[7];
}

// ---------------- K1: input conv 2->32, 3x3, pad 1 (LDS-tiled) ----------------
__global__ __launch_bounds__(192) void conv_in_k(const float* __restrict__ x,
                                                 const float* __restrict__ w,
                                                 const float* __restrict__ bias,
                                                 bf16* __restrict__ out) {
  __shared__ float xs[2 * 3 * (OF + 3)];
  int bt = blockIdx.x;
  int b = bt / TT, t = bt % TT;
  int tid = threadIdx.x;
  for (int i = tid; i < 2 * 3 * (OF + 3); i += 192) {
    int ci = i / (3 * (OF + 3));
    int rem = i % (3 * (OF + 3));
    int rr = rem / (OF + 3);
    int f = rem % (OF + 3);
    int ts = t + rr - 1;
    float v = 0.f;
    if (ts >= 0 && ts < TT && f < OF) v = x[((size_t)(b * 2 + ci) * TT + ts) * OF + f];
    xs[i] = v;
  }
  __syncthreads();
  int f = tid;
  if (f < OF) {
    float xv[2][3][3];
#pragma unroll
    for (int ci = 0; ci < 2; ci++)
#pragma unroll
      for (int kh = 0; kh < 3; kh++)
#pragma unroll
        for (int kw = 0; kw < 3; kw++) {
          int ff = f + kw - 1;
          xv[ci][kh][kw] = (ff < 0) ? 0.f : xs[(ci * 3 + kh) * (OF + 3) + ff];
        }
    for (int co = 0; co < CH; co++) {
      float acc = bias[co];
#pragma unroll
      for (int ci = 0; ci < 2; ci++)
#pragma unroll
        for (int kh = 0; kh < 3; kh++)
#pragma unroll
          for (int kw = 0; kw < 3; kw++)
            acc += xv[ci][kh][kw] * w[((co * 2 + ci) * 3 + kh) * 3 + kw];
      out[((size_t)(b * CH + co) * TT + t) * OF + f] = f2b(acc);
    }
  }
}

// ---------------- K2/K3: global per-batch norm ----------------
__global__ __launch_bounds__(256) void gn_reduce_k(const bf16* __restrict__ xin,
                                                   float* __restrict__ stats) {
  const int M = CH * TT * OF;   // 2,596,608
  int b = blockIdx.x >> 6;
  int part = blockIdx.x & 63;
  const bf16* p = xin + (size_t)b * M;
  float s1 = 0.f, s2 = 0.f;
  for (int i = part * 256 + threadIdx.x; i < M; i += 64 * 256) {
    float v = b2f(p[i]);
    s1 += v; s2 += v * v;
  }
  __shared__ float red[8];
  block_reduce2(s1, s2, red);
  if (threadIdx.x == 0) {
    atomicAdd(&stats[b * 2], s1);
    atomicAdd(&stats[b * 2 + 1], s2);
  }
}

__global__ __launch_bounds__(256) void gn_apply_k(const bf16* __restrict__ xin,
                                                  const float* __restrict__ stats,
                                                  const float* __restrict__ g,
                                                  const float* __restrict__ bb,
                                                  bf16* __restrict__ act) {
  int gid = blockIdx.x * 256 + threadIdx.x;       // B*CH*TT*FFp = 21,676,032 exact
  int f = gid % FFp;
  int t = (gid / FFp) % TT;
  int c = (gid / (FFp * TT)) % CH;
  int b = gid / (FFp * TT * CH);
  float v = 0.f;
  if (f < OF) {
    const float M = (float)(CH * TT * OF);
    float mu = stats[b * 2] / M;
    float var = stats[b * 2 + 1] / M - mu * mu;
    float xv = b2f(xin[((size_t)(b * CH + c) * TT + t) * OF + f]);
    v = (xv - mu) * rsqrtf(var + EPSf) * g[c] + bb[c];   // NOTE: no outer +eps here
  }
  act[gid] = f2b(v);
}

// ---------------- K4: ln over channels + unfold to time-major LSTM input ----------------
// mode 0 (intra): out[(f/8)*N1 + b*TT+t][c*8 + f%8]
// mode 1 (inter): out[(t/8)*N2 + b*FFp+f][c*8 + t%8]
__global__ __launch_bounds__(256) void ln_unfold_k(const bf16* __restrict__ xin,
                                                   const float* __restrict__ g,
                                                   const float* __restrict__ bb,
                                                   bf16* __restrict__ out, int mode) {
  __shared__ float sm[CH * FFp];
  __shared__ float mu_s[FFp], rs_s[FFp];
  int bt = blockIdx.x;
  int b = bt / TT, t = bt % TT;
  const bf16* base = xin + ((size_t)b * CH * TT + t) * FFp;
  for (int idx = threadIdx.x; idx < CH * FFp; idx += 256) {
    int c = idx / FFp, f = idx % FFp;
    sm[idx] = b2f(base[(size_t)c * TT * FFp + f]);
  }
  __syncthreads();
  if (threadIdx.x < FFp) {
    int f = threadIdx.x;
    float s1 = 0.f, s2 = 0.f;
#pragma unroll
    for (int c = 0; c < CH; c++) { float v = sm[c * FFp + f]; s1 += v; s2 += v * v; }
    float mu = s1 / CH;
    float var = s2 / CH - mu * mu;
    mu_s[f] = mu;
    rs_s[f] = 1.f / (sqrtf(var + EPSf) + EPSf);
  }
  __syncthreads();
  for (int idx = threadIdx.x; idx < CH * FFp; idx += 256) {
    int c = idx / FFp, f = idx % FFp;
    float v = (sm[idx] - mu_s[f]) * rs_s[f] * g[c] + bb[c];
    size_t o;
    if (mode == 0) {
      o = ((size_t)(f >> 3) * N1 + bt) * 256 + c * 8 + (f & 7);
    } else {
      int n = b * FFp + f;
      o = ((size_t)(t >> 3) * N2 + n) * 256 + c * 8 + (t & 7);
    }
    out[o] = f2b(v);
  }
}

// ---------------- K5a: weight prep — reorder W=[wih|whh] into B-fragment blob ---------
// blob[nt(64)][ks(16)][lane(64)][j(8)], value = Wcat[n][k]:
//   n = nt*16 + (lane&15), k = ks*32 + (lane>>4)*8 + j
//   Wcat[n][k] = k<256 ? wih[n][k] : whh[n][k-256]
__global__ __launch_bounds__(256) void lstm_prep_k(const float* __restrict__ wih0,
                                                   const float* __restrict__ whh0,
                                                   bf16* __restrict__ blob0) {
  int dir = blockIdx.y;
  const float* wih = wih0 + (size_t)dir * 262144;
  const float* whh = whh0 + (size_t)dir * 262144;
  unsigned short* blob = (unsigned short*)(blob0 + (size_t)dir * 524288);
  int gid = blockIdx.x * 256 + threadIdx.x;     // 0..65535
  int lane = gid & 63;
  int ks = (gid >> 6) & 15;
  int nt = gid >> 10;
  int n = nt * 16 + (lane & 15);
  int kb = ks * 32 + (lane >> 4) * 8;
  unsigned short o8[8];
#pragma unroll
  for (int j = 0; j < 8; j++) {
    int k = kb + j;
    float v = (k < 256) ? wih[n * 256 + k] : whh[n * 256 + (k - 256)];
    o8[j] = f2bu(v);
  }
  *(uint4*)(blob + (size_t)gid * 8) = *(uint4*)o8;
}

// ---------------- K5b: MFMA LSTM, 512 threads (8 waves), 3-deep rotating B pipeline ---
// R7 post-mortem: inter dispatch is per-CU load-LATENCY-bound (1 batch of 4 loads in
// flight -> ~1us stall per batch x 32 batches = 32us/step). Fix: af held 4-at-a-time
// (16 VGPR), bq[3][4] rotating (48 VGPR) so batch g+2's loads are in flight while
// batch g MFMAs -> depth 2-3. Batches 0,1 (blob is step-invariant) are issued during
// the previous step's epilogue, hiding refill under the barrier. Worst-case live
// ~126-135 arch VGPRs -> no R5-style spill.
// Batch order: g in [0,32): a = g>>3 (ks quad: ks = a*4..a*4+3), r = g&7 ->
// q = r>>1 (gate), j = r&1; nt = q*16 + 2w + j. Consume slot g%3, prefetch (g+2)%3.
__global__ __launch_bounds__(512) void lstm_mfma_k(const bf16* __restrict__ xz,
                                                   const bf16* __restrict__ blob0,
                                                   const float* __restrict__ bih0,
                                                   const float* __restrict__ bhh0,
                                                   bf16* __restrict__ hout,
                                                   int N, int Ls, int hstride, int bidir) {
  __shared__ short afr[16 * 64 * 8];     // 16 KB; slot = ks*64 + kg*16 + m (ks0-7 x, 8-15 h)
  int tid = threadIdx.x;
  int w = tid >> 6, lane = tid & 63;
  int l15 = lane & 15, lq = lane >> 4;
  int dir = blockIdx.y;
  const short* blob = (const short*)(blob0 + (size_t)dir * 524288);
  const float* bih = bih0 + dir * NG;
  const float* bhh = bhh0 + dir * NG;
  int hoff = dir * 256;
  int n0 = blockIdx.x * 16;
  unsigned short* houtu = (unsigned short*)hout;
  const short* xzs = (const short*)xz;

  float bias[4][2];
#pragma unroll
  for (int q = 0; q < 4; q++)
#pragma unroll
    for (int j = 0; j < 2; j++) {
      int n = q * 256 + (2 * w + j) * 16 + l15;
      bias[q][j] = bih[n] + bhh[n];
    }
  for (int i = tid; i < 8 * 64 * 8; i += 512) afr[8 * 64 * 8 + i] = 0;   // h frags = 0
  float cst[8];
#pragma unroll
  for (int i = 0; i < 8; i++) cst[i] = 0.f;

  int sm_ = tid & 15, sk8 = tid >> 4;                 // x-staging assignment (512 thr exact)
  int sslot = (sk8 >> 2) * 64 + (sk8 & 3) * 16 + sm_;

  s16x8 bq[3][4];
#define LSTM_PRELOAD(G, S)                                                     \
  {                                                                            \
    int a2 = (G) >> 3, r2 = (G) & 7;                                           \
    int nt2 = (r2 >> 1) * 16 + 2 * w + (r2 & 1);                               \
    const short* bp = blob + ((size_t)nt2 * 8192) + (a2 * 4) * 512 + lane * 8; \
    _Pragma("unroll")                                                          \
    for (int k = 0; k < 4; k++) bq[S][k] = *(const s16x8*)(bp + k * 512);      \
  }

  LSTM_PRELOAD(0, 0);
  LSTM_PRELOAD(1, 1);

  for (int st = 0; st < Ls; st++) {
    int t = (bidir && dir) ? (Ls - 1 - st) : st;
    // stage x_t fragments (8 KB)
    {
      s16x8 v = *(const s16x8*)(xzs + ((size_t)t * N + n0 + sm_) * 256 + sk8 * 8);
      *(s16x8*)(&afr[sslot * 8]) = v;
    }
    __syncthreads();                       // BARRIER-A: x staged + prev h visible

    f32x4 acc[4][2];
#pragma unroll
    for (int q = 0; q < 4; q++)
#pragma unroll
      for (int j = 0; j < 2; j++)
        acc[q][j] = (f32x4){bias[q][j], bias[q][j], bias[q][j], bias[q][j]};

#pragma unroll
    for (int a = 0; a < 4; a++) {          // ks quads
      s16x8 af[4];
#pragma unroll
      for (int k = 0; k < 4; k++)
        af[k] = *(const s16x8*)(&afr[((a * 4 + k) * 64 + lane) * 8]);
#pragma unroll
      for (int r = 0; r < 8; r++) {
        int g = a * 8 + r;
        if (g < 30) LSTM_PRELOAD(g + 2, (g + 2) % 3);
        int q = r >> 1, j = r & 1;
#pragma unroll
        for (int k = 0; k < 4; k++)
          acc[q][j] = __builtin_amdgcn_mfma_f32_16x16x32_bf16(af[k], bq[g % 3][k],
                                                              acc[q][j], 0, 0, 0);
      }
    }
    __syncthreads();                       // BARRIER-B: all afr reads done before h overwrite

    // epilogue: gates -> (h, c); h to global + h-frag LDS
#pragma unroll
    for (int j = 0; j < 2; j++) {
      int d = (2 * w + j) * 16 + l15;
      int slot = (8 + (d >> 5)) * 64 + ((d >> 3) & 3) * 16;
#pragma unroll
      for (int r = 0; r < 4; r++) {
        int m = lq * 4 + r;
        float iv = sigm(acc[0][j][r]);
        float fv = sigm(acc[1][j][r]);
        float gv = tanh_f(acc[2][j][r]);
        float ov = sigm(acc[3][j][r]);
        float c = fv * cst[j * 4 + r] + iv * gv;
        cst[j * 4 + r] = c;
        float h = ov * tanh_f(c);
        unsigned short hb = f2bu(h);
        houtu[((size_t)t * N + n0 + m) * hstride + hoff + d] = hb;
        afr[(slot + m) * 8 + (d & 7)] = (short)hb;
      }
    }
    if (st + 1 < Ls) {                     // refill batches 0,1 for next step (step-invariant)
      LSTM_PRELOAD(0, 0);
      LSTM_PRELOAD(1, 1);
    }
  }
#undef LSTM_PRELOAD
}

// ---------------- K6: fold GEMM (M=84672, N=256) + bias + residual, scatter epilogue ---
// As padded to stride 68 (R6: stride-64 scalar writes hit bank = arow mod 32 -> 4-way
// conflict; 68 -> 2-way max, 16B-aligned rows preserved for b128 reads).
__global__ __launch_bounds__(256) void fold_gemm_k(const bf16* __restrict__ A,
                                                   const float* __restrict__ Bw,
                                                   const float* __restrict__ linb,
                                                   const bf16* __restrict__ resid,
                                                   bf16* __restrict__ outp,
                                                   int K, int mode) {
  __shared__ float As[16 * 68];
  __shared__ float Bs[16 * 64];
  int tid = threadIdx.x;
  int n0 = blockIdx.x * 64;
  int m0 = blockIdx.y * 64;
  int tr = tid >> 4, tc = tid & 15;
  float acc[4][4] = {};
  int arow = tid >> 2, akg = (tid & 3) * 4;
  int bkk = tid >> 4, bc4 = (tid & 15) * 4;
  for (int k0 = 0; k0 < K; k0 += 16) {
    ushort4 avu = *(const ushort4*)((const unsigned short*)A + (size_t)(m0 + arow) * K + k0 + akg);
    float4 bv = *(const float4*)(Bw + (size_t)(k0 + bkk) * 256 + n0 + bc4);
    __syncthreads();
    As[(akg + 0) * 68 + arow] = us2f(avu.x);
    As[(akg + 1) * 68 + arow] = us2f(avu.y);
    As[(akg + 2) * 68 + arow] = us2f(avu.z);
    As[(akg + 3) * 68 + arow] = us2f(avu.w);
    *(float4*)(&Bs[bkk * 64 + bc4]) = bv;
    __syncthreads();
#pragma unroll
    for (int kk = 0; kk < 16; kk++) {
      float4 a4 = *(const float4*)(&As[kk * 68 + tr * 4]);
      float4 b4 = *(const float4*)(&Bs[kk * 64 + tc * 4]);
      float aa[4] = {a4.x, a4.y, a4.z, a4.w};
      float bb_[4] = {b4.x, b4.y, b4.z, b4.w};
#pragma unroll
      for (int i = 0; i < 4; i++)
#pragma unroll
        for (int j = 0; j < 4; j++) acc[i][j] += aa[i] * bb_[j];
    }
  }
#pragma unroll
  for (int i = 0; i < 4; i++) {
    int r = m0 + tr * 4 + i;
#pragma unroll
    for (int j = 0; j < 4; j++) {
      int col = n0 + tc * 4 + j;
      int c = col >> 3, kp = col & 7;
      float v = acc[i][j] + linb[c];
      if (mode == 0) {
        int l = r / N1, n = r % N1;
        int b = n / TT, t = n % TT;
        size_t o = ((size_t)(b * CH + c) * TT + t) * FFp + (l * 8 + kp);
        outp[o] = f2b(v + b2f(resid[o]));
      } else {
        int l = r / N2, n = r % N2;
        int b = n / FFp, fq = n % FFp;
        int t = l * 8 + kp;
        if (fq < OF) {
          size_t o = ((size_t)(b * CH + c) * TT + t) * OF + fq;
          size_t ri = ((size_t)(b * CH + c) * TT + t) * FFp + fq;
          outp[o] = f2b(v + b2f(resid[ri]));
        }
      }
    }
  }
}

// ---------------- K8: fused QKV projection + prelu + ln_cf_head ----------------
__global__ __launch_bounds__(256) void qkv_k(const bf16* __restrict__ interc,
    const float* __restrict__ qw, const float* __restrict__ qb, const float* __restrict__ qa,
    const float* __restrict__ qg, const float* __restrict__ qbeta,
    const float* __restrict__ kw, const float* __restrict__ kb, const float* __restrict__ ka,
    const float* __restrict__ kg, const float* __restrict__ kbeta,
    const float* __restrict__ vw, const float* __restrict__ vb, const float* __restrict__ va,
    const float* __restrict__ vg, const float* __restrict__ vbeta,
    bf16* __restrict__ qo, bf16* __restrict__ ko, bf16* __restrict__ vo) {
  __shared__ float sm[CH * OF];     // 5152
  __shared__ float wb[16 * 32];
  __shared__ float wbias[16];
  __shared__ float yb[16 * OF];     // 2576: [0:4) Q-e, [4:8) K-e, [8:16) V-cv
  __shared__ float red[8];
  int bt = blockIdx.x, h = blockIdx.y;
  int b = bt / TT, t = bt % TT;
  int tid = threadIdx.x;
  const bf16* src = interc + ((size_t)b * CH * TT + t) * OF;
  for (int idx = tid; idx < CH * OF; idx += 256) {
    int c = idx / OF, f = idx % OF;
    sm[idx] = b2f(src[(size_t)c * TT * OF + f]);
  }
  for (int idx = tid; idx < 512; idx += 256) {
    int e = idx >> 5, c = idx & 31;
    float w;
    if (e < 4) w = qw[(h * 4 + e) * 32 + c];
    else if (e < 8) w = kw[(h * 4 + e - 4) * 32 + c];
    else w = vw[(h * 8 + e - 8) * 32 + c];
    wb[idx] = w;
  }
  if (tid < 16) {
    float bv;
    if (tid < 4) bv = qb[h * 4 + tid];
    else if (tid < 8) bv = kb[h * 4 + tid - 4];
    else bv = vb[h * 8 + tid - 8];
    wbias[tid] = bv;
  }
  __syncthreads();
  float aQ = qa[h], aK = ka[h], aV = va[h];
  for (int idx = tid; idx < 16 * OF; idx += 256) {
    int e = idx / OF, f = idx % OF;
    float accv = wbias[e];
#pragma unroll
    for (int c = 0; c < 32; c++) accv += sm[c * OF + f] * wb[e * 32 + c];
    float a = e < 4 ? aQ : (e < 8 ? aK : aV);
    yb[idx] = accv >= 0.f ? accv : a * accv;
  }
  __syncthreads();
  for (int seg = 0; seg < 3; seg++) {
    int s0 = (seg == 0) ? 0 : ((seg == 1) ? 644 : 1288);
    int len = (seg == 2) ? 1288 : 644;
    float s1 = 0.f, s2 = 0.f;
    for (int i = tid; i < len; i += 256) { float v = yb[s0 + i]; s1 += v; s2 += v * v; }
    block_reduce2(s1, s2, red);
    float mu = s1 / len;
    float var = s2 / len - mu * mu;
    float rs = 1.f / (sqrtf(var + EPSf) + EPSf);
    const float* gp; const float* bp; bf16* op; int nch;
    if (seg == 0) { gp = qg; bp = qbeta; op = qo; nch = 4; }
    else if (seg == 1) { gp = kg; bp = kbeta; op = ko; nch = 4; }
    else { gp = vg; bp = vbeta; op = vo; nch = 8; }
    for (int i = tid; i < len; i += 256) {
      int e = i / OF, f = i % OF;
      float v = (yb[s0 + i] - mu) * rs * gp[(h * nch + e) * OF + f] + bp[(h * nch + e) * OF + f];
      op[(((size_t)(h * BB + b) * nch + e) * TT + t) * OF + f] = f2b(v);
    }
  }
}

// ---------------- K9: banded causal attention (lookback 5) ----------------
__global__ __launch_bounds__(256) void attn_k(const bf16* __restrict__ Q,
                                              const bf16* __restrict__ Kt,
                                              const bf16* __restrict__ V,
                                              bf16* __restrict__ O) {
  int t = blockIdx.x;
  int hb = blockIdx.y;            // h*8 + b
  int h = hb >> 3, b = hb & 7;
  int tid = threadIdx.x;
  int nv = min(t, 5) + 1;
  const float scale = 0.0394055201f;   // 1/sqrt(644)
  __shared__ float redl[24];
  float part[6] = {0, 0, 0, 0, 0, 0};
  size_t qkbase = ((size_t)(h * BB + b) * EE) * TT * OF;
  for (int i = tid; i < EE * OF; i += 256) {
    int e = i / OF, f = i % OF;
    float qv = b2f(Q[qkbase + ((size_t)e * TT + t) * OF + f]);
#pragma unroll
    for (int d = 0; d < 6; d++)
      if (d < nv) part[d] += qv * b2f(Kt[qkbase + ((size_t)e * TT + (t - d)) * OF + f]);
  }
#pragma unroll
  for (int d = 0; d < 6; d++)
#pragma unroll
    for (int off = 32; off > 0; off >>= 1) part[d] += __shfl_down(part[d], off, 64);
  int lane = tid & 63, wv = tid >> 6;
  if (lane == 0) {
#pragma unroll
    for (int d = 0; d < 6; d++) redl[wv * 6 + d] = part[d];
  }
  __syncthreads();
  float a[6], sv[6];
  float m = -1e30f;
#pragma unroll
  for (int d = 0; d < 6; d++)
    if (d < nv) {
      float s = (redl[d] + redl[6 + d] + redl[12 + d] + redl[18 + d]) * scale;
      sv[d] = s;
      m = fmaxf(m, s);
    }
  float denom = 0.f;
#pragma unroll
  for (int d = 0; d < 6; d++)
    if (d < nv) { a[d] = __expf(sv[d] - m); denom += a[d]; }
  float inv = 1.f / denom;
  size_t vbase = ((size_t)(h * BB + b) * CVv) * TT * OF;
  for (int i = tid; i < CVv * OF; i += 256) {
    int cv = i / OF, f = i % OF;
    float o = 0.f;
#pragma unroll
    for (int d = 0; d < 6; d++)
      if (d < nv) o += a[d] * b2f(V[vbase + ((size_t)cv * TT + (t - d)) * OF + f]);
    O[(((size_t)b * CH + h * CVv + cv) * TT + t) * OF + f] = f2b(o * inv);
  }
}

// ---------------- K10: proj + prelu + ln_cf_proj + residual + re-pad ----------------
__global__ __launch_bounds__(256) void proj_k(const bf16* __restrict__ ob,
                                              const float* __restrict__ pw,
                                              const float* __restrict__ pb,
                                              const float* __restrict__ pa,
                                              const float* __restrict__ pg,
                                              const float* __restrict__ pbeta,
                                              const bf16* __restrict__ interc,
                                              bf16* __restrict__ act) {
  __shared__ float sm[CH * OF];
  __shared__ float wsm[CH * CH];
  __shared__ float yb[CH * OF];
  __shared__ float red[8];
  int bt = blockIdx.x;
  int b = bt / TT, t = bt % TT;
  int tid = threadIdx.x;
  const bf16* src = ob + ((size_t)b * CH * TT + t) * OF;
  for (int idx = tid; idx < CH * OF; idx += 256) {
    int c = idx / OF, f = idx % OF;
    sm[idx] = b2f(src[(size_t)c * TT * OF + f]);
  }
  for (int idx = tid; idx < CH * CH; idx += 256) wsm[idx] = pw[idx];
  __syncthreads();
  float aP = pa[0];
  for (int idx = tid; idx < CH * OF; idx += 256) {
    int d = idx / OF, f = idx % OF;
    float accv = pb[d];
#pragma unroll
    for (int c = 0; c < 32; c++) accv += sm[c * OF + f] * wsm[d * 32 + c];
    yb[idx] = accv >= 0.f ? accv : aP * accv;
  }
  __syncthreads();
  float s1 = 0.f, s2 = 0.f;
  for (int i = tid; i < CH * OF; i += 256) { float v = yb[i]; s1 += v; s2 += v * v; }
  block_reduce2(s1, s2, red);
  const float Mn = (float)(CH * OF);
  float mu = s1 / Mn;
  float var = s2 / Mn - mu * mu;
  float rs = 1.f / (sqrtf(var + EPSf) + EPSf);
  for (int idx = tid; idx < CH * FFp; idx += 256) {
    int d = idx / FFp, f = idx % FFp;
    float v = 0.f;
    if (f < OF) {
      float y = (yb[d * OF + f] - mu) * rs * pg[d * OF + f] + pbeta[d * OF + f];
      v = y + b2f(interc[((size_t)(b * CH + d) * TT + t) * OF + f]);
    }
    act[((size_t)(b * CH + d) * TT + t) * FFp + f] = f2b(v);
  }
}

// ---------------- K11: output deconv (LDS-tiled 3x3 conv over 32ch) -------------------
// NOTE: grid MUST be exactly B*TT = 4032 (block-per-(b,t)); larger grids write OOB.
__global__ __launch_bounds__(256) void deconv_k(const bf16* __restrict__ act,
                                                const float* __restrict__ w,
                                                const float* __restrict__ bias,
                                                float* __restrict__ out) {
  __shared__ float ash[CH * 3 * FFp];   // 64512 B
  int bt = blockIdx.x;
  int b = bt / TT, t = bt % TT;
  int tid = threadIdx.x;
  const short* acts = (const short*)act;
  for (int ch = tid; ch < CH * 3 * (FFp / 8); ch += 256) {   // 2016 chunks of 8
    int ci = ch / 63, rem = ch % 63;
    int rr = rem / 21, fc = rem % 21;
    int ts = t + rr - 1;
    float* dst = &ash[(ci * 3 + rr) * FFp + fc * 8];
    if (ts < 0 || ts >= TT) {
#pragma unroll
      for (int k2 = 0; k2 < 8; k2++) dst[k2] = 0.f;
    } else {
      s16x8 v = *(const s16x8*)(acts + ((size_t)(b * CH + ci) * TT + ts) * FFp + fc * 8);
#pragma unroll
      for (int k2 = 0; k2 < 8; k2++) dst[k2] = us2f((unsigned short)v[k2]);
    }
  }
  __syncthreads();
  int f = tid;
  if (f < OF) {
    float acc0 = bias[0], acc1 = bias[1];
#pragma unroll 4
    for (int ci = 0; ci < CH; ci++) {
      const float* row = &ash[ci * 3 * FFp];
      float xv[3][3];
#pragma unroll
      for (int kh = 0; kh < 3; kh++)
#pragma unroll
        for (int kw = 0; kw < 3; kw++) {
          int ff = f + kw - 1;
          xv[kh][kw] = (ff < 0) ? 0.f : row[kh * FFp + ff];   // ff==161 reads zero pad
        }
#pragma unroll
      for (int kh = 0; kh < 3; kh++)
#pragma unroll
        for (int kw = 0; kw < 3; kw++) {
          acc0 += xv[kh][kw] * w[((ci * 2 + 0) * 3 + (2 - kh)) * 3 + (2 - kw)];
          acc1 += xv[kh][kw] * w[((ci * 2 + 1) * 3 + (2 - kh)) * 3 + (2 - kw)];
        }
    }
    out[((size_t)(b * 2 + 0) * TT + t) * OF + f] = acc0;
    out[((size_t)(b * 2 + 1) * TT + t) * OF + f] = acc1;
  }
}

// ---------------- host launch ----------------
extern "C" void kernel_launch(void* const* d_in, const int* in_sizes, int n_in,
                              void* d_out, int out_size, void* d_ws, size_t ws_size,
                              hipStream_t stream) {
  const float* x            = (const float*)d_in[0];
  const float* conv_w       = (const float*)d_in[1];
  const float* conv_b       = (const float*)d_in[2];
  const float* gn_g         = (const float*)d_in[3];
  const float* gn_b         = (const float*)d_in[4];
  const float* intra_norm_g = (const float*)d_in[5];
  const float* intra_norm_b = (const float*)d_in[6];
  const float* intra_wih    = (const float*)d_in[7];
  const float* intra_whh    = (const float*)d_in[8];
  const float* intra_bih    = (const float*)d_in[9];
  const float* intra_bhh    = (const float*)d_in[10];
  const float* intra_lin_w  = (const float*)d_in[11];
  const float* intra_lin_b  = (const float*)d_in[12];
  const float* inter_norm_g = (const float*)d_in[13];
  const float* inter_norm_b = (const float*)d_in[14];
  const float* inter_wih    = (const float*)d_in[15];
  const float* inter_whh    = (const float*)d_in[16];
  const float* inter_bih    = (const float*)d_in[17];
  const float* inter_bhh    = (const float*)d_in[18];
  const float* inter_lin_w  = (const float*)d_in[19];
  const float* inter_lin_b  = (const float*)d_in[20];
  const float* q_w    = (const float*)d_in[21];
  const float* q_b    = (const float*)d_in[22];
  const float* q_a    = (const float*)d_in[23];
  const float* q_g    = (const float*)d_in[24];
  const float* q_beta = (const float*)d_in[25];
  const float* k_w    = (const float*)d_in[26];
  const float* k_b    = (const float*)d_in[27];
  const float* k_a    = (const float*)d_in[28];
  const float* k_g    = (const float*)d_in[29];
  const float* k_beta = (const float*)d_in[30];
  const float* v_w    = (const float*)d_in[31];
  const float* v_b    = (const float*)d_in[32];
  const float* v_a    = (const float*)d_in[33];
  const float* v_g    = (const float*)d_in[34];
  const float* v_beta = (const float*)d_in[35];
  const float* proj_w    = (const float*)d_in[36];
  const float* proj_b    = (const float*)d_in[37];
  const float* proj_a    = (const float*)d_in[38];
  const float* proj_g    = (const float*)d_in[39];
  const float* proj_beta = (const float*)d_in[40];
  const float* deconv_w  = (const float*)d_in[41];
  const float* deconv_b  = (const float*)d_in[42];

  // workspace: 256 B fp32 stats + bf16 arena of 129,153,024 elems = 246.3 MiB total.
  // Liveness-based aliasing:
  //   A act(21.676M)  B tmp(21.676M)  C hbuf(43.352M)  D res(21.676M)  E interc(20.773M)
  //   conv-out->E, qbuf->A, kbuf->B, vbuf->D, obuf->C (all dead at point of reuse)
  //   LSTM weight blobs overlay dead regions: intra blob -> D (dead until fold0),
  //   inter blob -> E (dead until fold1). Zero extra workspace.
  float* stats = (float*)d_ws;
  bf16* arena  = (bf16*)((char*)d_ws + 256);
  bf16* act    = arena;                  // A
  bf16* tmp    = arena + 21676032;       // B
  bf16* hbuf   = arena + 43352064;       // C
  bf16* res    = arena + 86704128;       // D
  bf16* interc = arena + 108380160;      // E  (end: 129,153,024)
  bf16* convout = interc;
  bf16* qbuf = act;
  bf16* kbuf = tmp;
  bf16* vbuf = res;
  bf16* obuf = hbuf;
  bf16* blob_intra = res;                // 2 x 524,288 bf16 = 2 MiB, dead until fold0
  bf16* blob_inter = interc;             // 524,288 bf16 = 1 MiB, dead until fold1

  hipMemsetAsync(stats, 0, 64 * sizeof(float), stream);
  conv_in_k<<<4032, 192, 0, stream>>>(x, conv_w, conv_b, convout);
  gn_reduce_k<<<512, 256, 0, stream>>>(convout, stats);
  gn_apply_k<<<84672, 256, 0, stream>>>(convout, stats, gn_g, gn_b, act);

  for (int l = 0; l < 4; l++) {
    lstm_prep_k<<<dim3(256, 2), 256, 0, stream>>>(
        intra_wih + (size_t)l * 524288, intra_whh + (size_t)l * 524288, blob_intra);
    ln_unfold_k<<<4032, 256, 0, stream>>>(act, intra_norm_g + l * 32, intra_norm_b + l * 32, tmp, 0);
    lstm_mfma_k<<<dim3(252, 2), 512, 0, stream>>>(
        tmp, blob_intra, intra_bih + l * 2048, intra_bhh + l * 2048, hbuf, N1, LFi, 512, 1);
    fold_gemm_k<<<dim3(4, 1323), 256, 0, stream>>>(
        hbuf, intra_lin_w + (size_t)l * 131072, intra_lin_b + l * 32, act, res, 512, 0);
    lstm_prep_k<<<dim3(256, 1), 256, 0, stream>>>(
        inter_wih + (size_t)l * 262144, inter_whh + (size_t)l * 262144, blob_inter);
    ln_unfold_k<<<4032, 256, 0, stream>>>(res, inter_norm_g + l * 32, inter_norm_b + l * 32, tmp, 1);
    lstm_mfma_k<<<dim3(84, 1), 512, 0, stream>>>(
        tmp, blob_inter, inter_bih + l * 1024, inter_bhh + l * 1024, hbuf, N2, LTi, 256, 0);
    fold_gemm_k<<<dim3(4, 1323), 256, 0, stream>>>(
        hbuf, inter_lin_w + (size_t)l * 65536, inter_lin_b + l * 32, res, interc, 256, 1);
    qkv_k<<<dim3(4032, 4), 256, 0, stream>>>(interc,
        q_w + l * 512, q_b + l * 16, q_a + l * 4, q_g + l * 2576, q_beta + l * 2576,
        k_w + l * 512, k_b + l * 16, k_a + l * 4, k_g + l * 2576, k_beta + l * 2576,
        v_w + l * 1024, v_b + l * 32, v_a + l * 4, v_g + l * 5152, v_beta + l * 5152,
        qbuf, kbuf, vbuf);
    attn_k<<<dim3(504, 32), 256, 0, stream>>>(qbuf, kbuf, vbuf, obuf);
    proj_k<<<4032, 256, 0, stream>>>(obuf, proj_w + l * 1024, proj_b + l * 32, proj_a + l,
                                     proj_g + l * 5152, proj_beta + l * 5152, interc, act);
  }
  deconv_k<<<4032, 256, 0, stream>>>(act, deconv_w, deconv_b, (float*)d_out);
}

// Round 9
// 16508.769 us; speedup vs baseline: 3.5666x; 1.1819x over previous
//
#include <hip/hip_runtime.h>
#include <hip/hip_bf16.h>
#include <math.h>

// ---------------- problem constants ----------------
#define BB   8
#define CH   32
#define TT   504
#define FFp  168      // padded F
#define OF   161      // original F
#define KSZ  8
#define HID  256
#define NG   1024     // 4*H
#define NHh  4
#define EE   4
#define CVv  8
#define N1   4032     // B*T  (intra seqs)
#define N2   1344     // B*Fp (inter seqs)
#define LFi  21       // F/KS
#define LTi  63       // T/KS
#define EPSf 1e-5f

#define AS1 __attribute__((address_space(1)))
#define AS3 __attribute__((address_space(3)))

typedef __hip_bfloat16 bf16;
typedef __attribute__((ext_vector_type(8))) short s16x8;
typedef __attribute__((ext_vector_type(4))) float f32x4;

__device__ __forceinline__ float b2f(bf16 v) { return __bfloat162float(v); }
__device__ __forceinline__ bf16 f2b(float v) { return __float2bfloat16(v); }
__device__ __forceinline__ float us2f(unsigned short u) {
  return __uint_as_float(((unsigned)u) << 16);
}
__device__ __forceinline__ unsigned short f2bu(float v) {   // RNE bf16 bits
  unsigned u = __float_as_uint(v);
  unsigned r = u + 0x7fffu + ((u >> 16) & 1u);
  return (unsigned short)(r >> 16);
}

__device__ __forceinline__ float sigm(float x) { return 1.f / (1.f + __expf(-x)); }
__device__ __forceinline__ float tanh_f(float x) {
  x = fminf(15.f, fmaxf(-15.f, x));
  float e = __expf(2.f * x);
  return (e - 1.f) / (e + 1.f);
}

// block = 256 threads (4 waves). red must be float[8] shared.
__device__ __forceinline__ void block_reduce2(float& s1, float& s2, float* red) {
#pragma unroll
  for (int off = 32; off > 0; off >>= 1) {
    s1 += __shfl_down(s1, off, 64);
    s2 += __shfl_down(s2, off, 64);
  }
  int lane = threadIdx.x & 63, wv = threadIdx.x >> 6;
  __syncthreads();
  if (lane == 0) { red[wv * 2] = s1; red[wv * 2 + 1] = s2; }
  __syncthreads();
  s1 = red[0] + red[2] + red[4] + red[6];
  s2 = red[1] + red[3] + red[5] + red[7];
}

// ---------------- K1: input conv 2->32, 3x3, pad 1 (LDS-tiled) ----------------
__global__ __launch_bounds__(192) void conv_in_k(const float* __restrict__ x,
                                                 const float* __restrict__ w,
                                                 const float* __restrict__ bias,
                                                 bf16* __restrict__ out) {
  __shared__ float xs[2 * 3 * (OF + 3)];
  int bt = blockIdx.x;
  int b = bt / TT, t = bt % TT;
  int tid = threadIdx.x;
  for (int i = tid; i < 2 * 3 * (OF + 3); i += 192) {
    int ci = i / (3 * (OF + 3));
    int rem = i % (3 * (OF + 3));
    int rr = rem / (OF + 3);
    int f = rem % (OF + 3);
    int ts = t + rr - 1;
    float v = 0.f;
    if (ts >= 0 && ts < TT && f < OF) v = x[((size_t)(b * 2 + ci) * TT + ts) * OF + f];
    xs[i] = v;
  }
  __syncthreads();
  int f = tid;
  if (f < OF) {
    float xv[2][3][3];
#pragma unroll
    for (int ci = 0; ci < 2; ci++)
#pragma unroll
      for (int kh = 0; kh < 3; kh++)
#pragma unroll
        for (int kw = 0; kw < 3; kw++) {
          int ff = f + kw - 1;
          xv[ci][kh][kw] = (ff < 0) ? 0.f : xs[(ci * 3 + kh) * (OF + 3) + ff];
        }
    for (int co = 0; co < CH; co++) {
      float acc = bias[co];
#pragma unroll
      for (int ci = 0; ci < 2; ci++)
#pragma unroll
        for (int kh = 0; kh < 3; kh++)
#pragma unroll
          for (int kw = 0; kw < 3; kw++)
            acc += xv[ci][kh][kw] * w[((co * 2 + ci) * 3 + kh) * 3 + kw];
      out[((size_t)(b * CH + co) * TT + t) * OF + f] = f2b(acc);
    }
  }
}

// ---------------- K2/K3: global per-batch norm ----------------
__global__ __launch_bounds__(256) void gn_reduce_k(const bf16* __restrict__ xin,
                                                   float* __restrict__ stats) {
  const int M = CH * TT * OF;   // 2,596,608
  int b = blockIdx.x >> 6;
  int part = blockIdx.x & 63;
  const bf16* p = xin + (size_t)b * M;
  float s1 = 0.f, s2 = 0.f;
  for (int i = part * 256 + threadIdx.x; i < M; i += 64 * 256) {
    float v = b2f(p[i]);
    s1 += v; s2 += v * v;
  }
  __shared__ float red[8];
  block_reduce2(s1, s2, red);
  if (threadIdx.x == 0) {
    atomicAdd(&stats[b * 2], s1);
    atomicAdd(&stats[b * 2 + 1], s2);
  }
}

__global__ __launch_bounds__(256) void gn_apply_k(const bf16* __restrict__ xin,
                                                  const float* __restrict__ stats,
                                                  const float* __restrict__ g,
                                                  const float* __restrict__ bb,
                                                  bf16* __restrict__ act) {
  int gid = blockIdx.x * 256 + threadIdx.x;       // B*CH*TT*FFp = 21,676,032 exact
  int f = gid % FFp;
  int t = (gid / FFp) % TT;
  int c = (gid / (FFp * TT)) % CH;
  int b = gid / (FFp * TT * CH);
  float v = 0.f;
  if (f < OF) {
    const float M = (float)(CH * TT * OF);
    float mu = stats[b * 2] / M;
    float var = stats[b * 2 + 1] / M - mu * mu;
    float xv = b2f(xin[((size_t)(b * CH + c) * TT + t) * OF + f]);
    v = (xv - mu) * rsqrtf(var + EPSf) * g[c] + bb[c];   // NOTE: no outer +eps here
  }
  act[gid] = f2b(v);
}

// ---------------- K4: ln over channels + unfold to time-major LSTM input ----------------
// mode 0 (intra): out[(f/8)*N1 + b*TT+t][c*8 + f%8]
// mode 1 (inter): out[(t/8)*N2 + b*FFp+f][c*8 + t%8]
__global__ __launch_bounds__(256) void ln_unfold_k(const bf16* __restrict__ xin,
                                                   const float* __restrict__ g,
                                                   const float* __restrict__ bb,
                                                   bf16* __restrict__ out, int mode) {
  __shared__ float sm[CH * FFp];
  __shared__ float mu_s[FFp], rs_s[FFp];
  int bt = blockIdx.x;
  int b = bt / TT, t = bt % TT;
  const bf16* base = xin + ((size_t)b * CH * TT + t) * FFp;
  for (int idx = threadIdx.x; idx < CH * FFp; idx += 256) {
    int c = idx / FFp, f = idx % FFp;
    sm[idx] = b2f(base[(size_t)c * TT * FFp + f]);
  }
  __syncthreads();
  if (threadIdx.x < FFp) {
    int f = threadIdx.x;
    float s1 = 0.f, s2 = 0.f;
#pragma unroll
    for (int c = 0; c < CH; c++) { float v = sm[c * FFp + f]; s1 += v; s2 += v * v; }
    float mu = s1 / CH;
    float var = s2 / CH - mu * mu;
    mu_s[f] = mu;
    rs_s[f] = 1.f / (sqrtf(var + EPSf) + EPSf);
  }
  __syncthreads();
  for (int idx = threadIdx.x; idx < CH * FFp; idx += 256) {
    int c = idx / FFp, f = idx % FFp;
    float v = (sm[idx] - mu_s[f]) * rs_s[f] * g[c] + bb[c];
    size_t o;
    if (mode == 0) {
      o = ((size_t)(f >> 3) * N1 + bt) * 256 + c * 8 + (f & 7);
    } else {
      int n = b * FFp + f;
      o = ((size_t)(t >> 3) * N2 + n) * 256 + c * 8 + (t & 7);
    }
    out[o] = f2b(v);
  }
}

// ---------------- K5a: weight prep — reorder W=[wih|whh] into B-fragment blob ---------
// blob[nt(64)][ks(16)][lane(64)][j(8)], value = Wcat[n][k]:
//   n = nt*16 + (lane&15), k = ks*32 + (lane>>4)*8 + j
//   Wcat[n][k] = k<256 ? wih[n][k] : whh[n][k-256]
__global__ __launch_bounds__(256) void lstm_prep_k(const float* __restrict__ wih0,
                                                   const float* __restrict__ whh0,
                                                   bf16* __restrict__ blob0) {
  int dir = blockIdx.y;
  const float* wih = wih0 + (size_t)dir * 262144;
  const float* whh = whh0 + (size_t)dir * 262144;
  unsigned short* blob = (unsigned short*)(blob0 + (size_t)dir * 524288);
  int gid = blockIdx.x * 256 + threadIdx.x;     // 0..65535
  int lane = gid & 63;
  int ks = (gid >> 6) & 15;
  int nt = gid >> 10;
  int n = nt * 16 + (lane & 15);
  int kb = ks * 32 + (lane >> 4) * 8;
  unsigned short o8[8];
#pragma unroll
  for (int j = 0; j < 8; j++) {
    int k = kb + j;
    float v = (k < 256) ? wih[n * 256 + k] : whh[n * 256 + (k - 256)];
    o8[j] = f2bu(v);
  }
  *(uint4*)(blob + (size_t)gid * 8) = *(uint4*)o8;
}

// ---------------- K5b: MFMA LSTM, 512 threads, async global_load_lds B-stream ---------
// R8 post-mortem: all VGPR-prefetch structures serialize at full load latency
// (compiler vmcnt placement; 128 loads x ~600cyc = observed 32us/step). Fix: stream
// the blob via __builtin_amdgcn_global_load_lds (async DMA, vmcnt-tracked, zero VGPR
// cost). Blob layout [lane][16B] is exactly the wave-uniform-base + lane*16 DMA shape.
// Per wave: 32 chunks/step of 4 frags (4 KiB), double-buffered in its private LDS
// slice; explicit s_waitcnt vmcnt(4) per chunk -> >=8 loads in flight. Chunk order
// identical to R8 batches -> bit-identical accumulation.
// LDS: afr 16 KiB static + bstage 64 KiB dynamic = 80 KiB -> 2 blocks/CU.
__global__ __launch_bounds__(512) void lstm_mfma_k(const bf16* __restrict__ xz,
                                                   const bf16* __restrict__ blob0,
                                                   const float* __restrict__ bih0,
                                                   const float* __restrict__ bhh0,
                                                   bf16* __restrict__ hout,
                                                   int N, int Ls, int hstride, int bidir) {
  __shared__ __attribute__((aligned(16))) short afr[16 * 64 * 8];  // 16 KiB; slot=ks*64+kg*16+m
  extern __shared__ __attribute__((aligned(16))) short bstage[];   // 64 KiB: [w][buf][frag4][lane][8]
  int tid = threadIdx.x;
  int w = tid >> 6, lane = tid & 63;
  int l15 = lane & 15, lq = lane >> 4;
  int dir = blockIdx.y;
  const short* blob = (const short*)(blob0 + (size_t)dir * 524288);
  const float* bih = bih0 + dir * NG;
  const float* bhh = bhh0 + dir * NG;
  int hoff = dir * 256;
  int n0 = blockIdx.x * 16;
  unsigned short* houtu = (unsigned short*)hout;
  const short* xzs = (const short*)xz;
  short* bst_w = bstage + w * 4096;      // per-wave 8 KiB: 2 bufs x 4 frags x 512 shorts

  float bias[4][2];
#pragma unroll
  for (int q = 0; q < 4; q++)
#pragma unroll
    for (int j = 0; j < 2; j++) {
      int n = q * 256 + (2 * w + j) * 16 + l15;
      bias[q][j] = bih[n] + bhh[n];
    }
  for (int i = tid; i < 8 * 64 * 8; i += 512) afr[8 * 64 * 8 + i] = 0;   // h frags = 0
  float cst[8];
#pragma unroll
  for (int i = 0; i < 8; i++) cst[i] = 0.f;

// chunk C in [0,32): a=C>>3 (ks quad), r=C&7 -> q=r>>1, j=r&1, nt=q*16+2w+j; buf=C&1.
#define BQ_ISSUE(C)                                                              \
  {                                                                              \
    int a_ = (C) >> 3, r_ = (C) & 7;                                             \
    int nt_ = (r_ >> 1) * 16 + 2 * w + (r_ & 1);                                 \
    const short* gb_ = blob + (size_t)nt_ * 8192 + a_ * 2048 + lane * 8;         \
    short* lb_ = bst_w + ((C) & 1) * 2048;                                       \
    _Pragma("unroll")                                                            \
    for (int k_ = 0; k_ < 4; k_++)                                               \
      __builtin_amdgcn_global_load_lds((const AS1 void*)(gb_ + k_ * 512),        \
                                       (AS3 void*)(lb_ + k_ * 512), 16, 0, 0);   \
  }

  for (int st = 0; st < Ls; st++) {
    int t = (bidir && dir) ? (Ls - 1 - st) : st;
    // stage x_t via DMA: wave w fills afr slots w*64+lane (lane-contiguous, 16 B each)
    {
      const short* gx = xzs + ((size_t)t * N + n0 + (lane & 15)) * 256 + (w * 4 + (lane >> 4)) * 8;
      __builtin_amdgcn_global_load_lds((const AS1 void*)gx, (AS3 void*)(afr + w * 512), 16, 0, 0);
    }
    BQ_ISSUE(0);
    BQ_ISSUE(1);
    __syncthreads();   // BARRIER-A: drains all DMA (x + chunks 0,1 resident), h visible

    f32x4 acc[4][2];
#pragma unroll
    for (int q = 0; q < 4; q++)
#pragma unroll
      for (int j = 0; j < 2; j++)
        acc[q][j] = (f32x4){bias[q][j], bias[q][j], bias[q][j], bias[q][j]};

    s16x8 af[4];
#pragma unroll
    for (int c = 0; c < 32; c++) {
      int a = c >> 3, r = c & 7;
      int q = r >> 1, j = r & 1;
      if (r == 0) {
#pragma unroll
        for (int k = 0; k < 4; k++)
          af[k] = *(const s16x8*)(&afr[((a * 4 + k) * 64 + lane) * 8]);
      }
      __builtin_amdgcn_s_waitcnt(0x0F74);   // vmcnt(4): chunk c resident, c+1 in flight
      const short* lb = bst_w + (c & 1) * 2048;
#pragma unroll
      for (int k = 0; k < 4; k++) {
        s16x8 bf = *(const s16x8*)(lb + k * 512 + lane * 8);
        acc[q][j] = __builtin_amdgcn_mfma_f32_16x16x32_bf16(af[k], bf, acc[q][j], 0, 0, 0);
      }
      if (c < 30) BQ_ISSUE(c + 2);
    }
    __syncthreads();   // BARRIER-B: all afr reads done before h overwrite

    // epilogue: gates -> (h, c); h to global + h-frag LDS
#pragma unroll
    for (int j = 0; j < 2; j++) {
      int d = (2 * w + j) * 16 + l15;
      int slot = (8 + (d >> 5)) * 64 + ((d >> 3) & 3) * 16;
#pragma unroll
      for (int r = 0; r < 4; r++) {
        int m = lq * 4 + r;
        float iv = sigm(acc[0][j][r]);
        float fv = sigm(acc[1][j][r]);
        float gv = tanh_f(acc[2][j][r]);
        float ov = sigm(acc[3][j][r]);
        float c = fv * cst[j * 4 + r] + iv * gv;
        cst[j * 4 + r] = c;
        float h = ov * tanh_f(c);
        unsigned short hb = f2bu(h);
        houtu[((size_t)t * N + n0 + m) * hstride + hoff + d] = hb;
        afr[(slot + m) * 8 + (d & 7)] = (short)hb;
      }
    }
  }
#undef BQ_ISSUE
}

// ---------------- K6: fold GEMM (M=84672, N=256) + bias + residual, scatter epilogue ---
// As padded to stride 68 (R6: stride-64 scalar writes hit bank = arow mod 32 -> 4-way
// conflict; 68 -> 2-way max, 16B-aligned rows preserved for b128 reads).
__global__ __launch_bounds__(256) void fold_gemm_k(const bf16* __restrict__ A,
                                                   const float* __restrict__ Bw,
                                                   const float* __restrict__ linb,
                                                   const bf16* __restrict__ resid,
                                                   bf16* __restrict__ outp,
                                                   int K, int mode) {
  __shared__ float As[16 * 68];
  __shared__ float Bs[16 * 64];
  int tid = threadIdx.x;
  int n0 = blockIdx.x * 64;
  int m0 = blockIdx.y * 64;
  int tr = tid >> 4, tc = tid & 15;
  float acc[4][4] = {};
  int arow = tid >> 2, akg = (tid & 3) * 4;
  int bkk = tid >> 4, bc4 = (tid & 15) * 4;
  for (int k0 = 0; k0 < K; k0 += 16) {
    ushort4 avu = *(const ushort4*)((const unsigned short*)A + (size_t)(m0 + arow) * K + k0 + akg);
    float4 bv = *(const float4*)(Bw + (size_t)(k0 + bkk) * 256 + n0 + bc4);
    __syncthreads();
    As[(akg + 0) * 68 + arow] = us2f(avu.x);
    As[(akg + 1) * 68 + arow] = us2f(avu.y);
    As[(akg + 2) * 68 + arow] = us2f(avu.z);
    As[(akg + 3) * 68 + arow] = us2f(avu.w);
    *(float4*)(&Bs[bkk * 64 + bc4]) = bv;
    __syncthreads();
#pragma unroll
    for (int kk = 0; kk < 16; kk++) {
      float4 a4 = *(const float4*)(&As[kk * 68 + tr * 4]);
      float4 b4 = *(const float4*)(&Bs[kk * 64 + tc * 4]);
      float aa[4] = {a4.x, a4.y, a4.z, a4.w};
      float bb_[4] = {b4.x, b4.y, b4.z, b4.w};
#pragma unroll
      for (int i = 0; i < 4; i++)
#pragma unroll
        for (int j = 0; j < 4; j++) acc[i][j] += aa[i] * bb_[j];
    }
  }
#pragma unroll
  for (int i = 0; i < 4; i++) {
    int r = m0 + tr * 4 + i;
#pragma unroll
    for (int j = 0; j < 4; j++) {
      int col = n0 + tc * 4 + j;
      int c = col >> 3, kp = col & 7;
      float v = acc[i][j] + linb[c];
      if (mode == 0) {
        int l = r / N1, n = r % N1;
        int b = n / TT, t = n % TT;
        size_t o = ((size_t)(b * CH + c) * TT + t) * FFp + (l * 8 + kp);
        outp[o] = f2b(v + b2f(resid[o]));
      } else {
        int l = r / N2, n = r % N2;
        int b = n / FFp, fq = n % FFp;
        int t = l * 8 + kp;
        if (fq < OF) {
          size_t o = ((size_t)(b * CH + c) * TT + t) * OF + fq;
          size_t ri = ((size_t)(b * CH + c) * TT + t) * FFp + fq;
          outp[o] = f2b(v + b2f(resid[ri]));
        }
      }
    }
  }
}

// ---------------- K8: fused QKV projection + prelu + ln_cf_head ----------------
__global__ __launch_bounds__(256) void qkv_k(const bf16* __restrict__ interc,
    const float* __restrict__ qw, const float* __restrict__ qb, const float* __restrict__ qa,
    const float* __restrict__ qg, const float* __restrict__ qbeta,
    const float* __restrict__ kw, const float* __restrict__ kb, const float* __restrict__ ka,
    const float* __restrict__ kg, const float* __restrict__ kbeta,
    const float* __restrict__ vw, const float* __restrict__ vb, const float* __restrict__ va,
    const float* __restrict__ vg, const float* __restrict__ vbeta,
    bf16* __restrict__ qo, bf16* __restrict__ ko, bf16* __restrict__ vo) {
  __shared__ float sm[CH * OF];     // 5152
  __shared__ float wb[16 * 32];
  __shared__ float wbias[16];
  __shared__ float yb[16 * OF];     // 2576: [0:4) Q-e, [4:8) K-e, [8:16) V-cv
  __shared__ float red[8];
  int bt = blockIdx.x, h = blockIdx.y;
  int b = bt / TT, t = bt % TT;
  int tid = threadIdx.x;
  const bf16* src = interc + ((size_t)b * CH * TT + t) * OF;
  for (int idx = tid; idx < CH * OF; idx += 256) {
    int c = idx / OF, f = idx % OF;
    sm[idx] = b2f(src[(size_t)c * TT * OF + f]);
  }
  for (int idx = tid; idx < 512; idx += 256) {
    int e = idx >> 5, c = idx & 31;
    float w;
    if (e < 4) w = qw[(h * 4 + e) * 32 + c];
    else if (e < 8) w = kw[(h * 4 + e - 4) * 32 + c];
    else w = vw[(h * 8 + e - 8) * 32 + c];
    wb[idx] = w;
  }
  if (tid < 16) {
    float bv;
    if (tid < 4) bv = qb[h * 4 + tid];
    else if (tid < 8) bv = kb[h * 4 + tid - 4];
    else bv = vb[h * 8 + tid - 8];
    wbias[tid] = bv;
  }
  __syncthreads();
  float aQ = qa[h], aK = ka[h], aV = va[h];
  for (int idx = tid; idx < 16 * OF; idx += 256) {
    int e = idx / OF, f = idx % OF;
    float accv = wbias[e];
#pragma unroll
    for (int c = 0; c < 32; c++) accv += sm[c * OF + f] * wb[e * 32 + c];
    float a = e < 4 ? aQ : (e < 8 ? aK : aV);
    yb[idx] = accv >= 0.f ? accv : a * accv;
  }
  __syncthreads();
  for (int seg = 0; seg < 3; seg++) {
    int s0 = (seg == 0) ? 0 : ((seg == 1) ? 644 : 1288);
    int len = (seg == 2) ? 1288 : 644;
    float s1 = 0.f, s2 = 0.f;
    for (int i = tid; i < len; i += 256) { float v = yb[s0 + i]; s1 += v; s2 += v * v; }
    block_reduce2(s1, s2, red);
    float mu = s1 / len;
    float var = s2 / len - mu * mu;
    float rs = 1.f / (sqrtf(var + EPSf) + EPSf);
    const float* gp; const float* bp; bf16* op; int nch;
    if (seg == 0) { gp = qg; bp = qbeta; op = qo; nch = 4; }
    else if (seg == 1) { gp = kg; bp = kbeta; op = ko; nch = 4; }
    else { gp = vg; bp = vbeta; op = vo; nch = 8; }
    for (int i = tid; i < len; i += 256) {
      int e = i / OF, f = i % OF;
      float v = (yb[s0 + i] - mu) * rs * gp[(h * nch + e) * OF + f] + bp[(h * nch + e) * OF + f];
      op[(((size_t)(h * BB + b) * nch + e) * TT + t) * OF + f] = f2b(v);
    }
  }
}

// ---------------- K9: banded causal attention (lookback 5) ----------------
__global__ __launch_bounds__(256) void attn_k(const bf16* __restrict__ Q,
                                              const bf16* __restrict__ Kt,
                                              const bf16* __restrict__ V,
                                              bf16* __restrict__ O) {
  int t = blockIdx.x;
  int hb = blockIdx.y;            // h*8 + b
  int h = hb >> 3, b = hb & 7;
  int tid = threadIdx.x;
  int nv = min(t, 5) + 1;
  const float scale = 0.0394055201f;   // 1/sqrt(644)
  __shared__ float redl[24];
  float part[6] = {0, 0, 0, 0, 0, 0};
  size_t qkbase = ((size_t)(h * BB + b) * EE) * TT * OF;
  for (int i = tid; i < EE * OF; i += 256) {
    int e = i / OF, f = i % OF;
    float qv = b2f(Q[qkbase + ((size_t)e * TT + t) * OF + f]);
#pragma unroll
    for (int d = 0; d < 6; d++)
      if (d < nv) part[d] += qv * b2f(Kt[qkbase + ((size_t)e * TT + (t - d)) * OF + f]);
  }
#pragma unroll
  for (int d = 0; d < 6; d++)
#pragma unroll
    for (int off = 32; off > 0; off >>= 1) part[d] += __shfl_down(part[d], off, 64);
  int lane = tid & 63, wv = tid >> 6;
  if (lane == 0) {
#pragma unroll
    for (int d = 0; d < 6; d++) redl[wv * 6 + d] = part[d];
  }
  __syncthreads();
  float a[6], sv[6];
  float m = -1e30f;
#pragma unroll
  for (int d = 0; d < 6; d++)
    if (d < nv) {
      float s = (redl[d] + redl[6 + d] + redl[12 + d] + redl[18 + d]) * scale;
      sv[d] = s;
      m = fmaxf(m, s);
    }
  float denom = 0.f;
#pragma unroll
  for (int d = 0; d < 6; d++)
    if (d < nv) { a[d] = __expf(sv[d] - m); denom += a[d]; }
  float inv = 1.f / denom;
  size_t vbase = ((size_t)(h * BB + b) * CVv) * TT * OF;
  for (int i = tid; i < CVv * OF; i += 256) {
    int cv = i / OF, f = i % OF;
    float o = 0.f;
#pragma unroll
    for (int d = 0; d < 6; d++)
      if (d < nv) o += a[d] * b2f(V[vbase + ((size_t)cv * TT + (t - d)) * OF + f]);
    O[(((size_t)b * CH + h * CVv + cv) * TT + t) * OF + f] = f2b(o * inv);
  }
}

// ---------------- K10: proj + prelu + ln_cf_proj + residual + re-pad ----------------
__global__ __launch_bounds__(256) void proj_k(const bf16* __restrict__ ob,
                                              const float* __restrict__ pw,
                                              const float* __restrict__ pb,
                                              const float* __restrict__ pa,
                                              const float* __restrict__ pg,
                                              const float* __restrict__ pbeta,
                                              const bf16* __restrict__ interc,
                                              bf16* __restrict__ act) {
  __shared__ float sm[CH * OF];
  __shared__ float wsm[CH * CH];
  __shared__ float yb[CH * OF];
  __shared__ float red[8];
  int bt = blockIdx.x;
  int b = bt / TT, t = bt % TT;
  int tid = threadIdx.x;
  const bf16* src = ob + ((size_t)b * CH * TT + t) * OF;
  for (int idx = tid; idx < CH * OF; idx += 256) {
    int c = idx / OF, f = idx % OF;
    sm[idx] = b2f(src[(size_t)c * TT * OF + f]);
  }
  for (int idx = tid; idx < CH * CH; idx += 256) wsm[idx] = pw[idx];
  __syncthreads();
  float aP = pa[0];
  for (int idx = tid; idx < CH * OF; idx += 256) {
    int d = idx / OF, f = idx % OF;
    float accv = pb[d];
#pragma unroll
    for (int c = 0; c < 32; c++) accv += sm[c * OF + f] * wsm[d * 32 + c];
    yb[idx] = accv >= 0.f ? accv : aP * accv;
  }
  __syncthreads();
  float s1 = 0.f, s2 = 0.f;
  for (int i = tid; i < CH * OF; i += 256) { float v = yb[i]; s1 += v; s2 += v * v; }
  block_reduce2(s1, s2, red);
  const float Mn = (float)(CH * OF);
  float mu = s1 / Mn;
  float var = s2 / Mn - mu * mu;
  float rs = 1.f / (sqrtf(var + EPSf) + EPSf);
  for (int idx = tid; idx < CH * FFp; idx += 256) {
    int d = idx / FFp, f = idx % FFp;
    float v = 0.f;
    if (f < OF) {
      float y = (yb[d * OF + f] - mu) * rs * pg[d * OF + f] + pbeta[d * OF + f];
      v = y + b2f(interc[((size_t)(b * CH + d) * TT + t) * OF + f]);
    }
    act[((size_t)(b * CH + d) * TT + t) * FFp + f] = f2b(v);
  }
}

// ---------------- K11: output deconv (LDS-tiled 3x3 conv over 32ch) -------------------
// NOTE: grid MUST be exactly B*TT = 4032 (block-per-(b,t)); larger grids write OOB.
__global__ __launch_bounds__(256) void deconv_k(const bf16* __restrict__ act,
                                                const float* __restrict__ w,
                                                const float* __restrict__ bias,
                                                float* __restrict__ out) {
  __shared__ float ash[CH * 3 * FFp];   // 64512 B
  int bt = blockIdx.x;
  int b = bt / TT, t = bt % TT;
  int tid = threadIdx.x;
  const short* acts = (const short*)act;
  for (int ch = tid; ch < CH * 3 * (FFp / 8); ch += 256) {   // 2016 chunks of 8
    int ci = ch / 63, rem = ch % 63;
    int rr = rem / 21, fc = rem % 21;
    int ts = t + rr - 1;
    float* dst = &ash[(ci * 3 + rr) * FFp + fc * 8];
    if (ts < 0 || ts >= TT) {
#pragma unroll
      for (int k2 = 0; k2 < 8; k2++) dst[k2] = 0.f;
    } else {
      s16x8 v = *(const s16x8*)(acts + ((size_t)(b * CH + ci) * TT + ts) * FFp + fc * 8);
#pragma unroll
      for (int k2 = 0; k2 < 8; k2++) dst[k2] = us2f((unsigned short)v[k2]);
    }
  }
  __syncthreads();
  int f = tid;
  if (f < OF) {
    float acc0 = bias[0], acc1 = bias[1];
#pragma unroll 4
    for (int ci = 0; ci < CH; ci++) {
      const float* row = &ash[ci * 3 * FFp];
      float xv[3][3];
#pragma unroll
      for (int kh = 0; kh < 3; kh++)
#pragma unroll
        for (int kw = 0; kw < 3; kw++) {
          int ff = f + kw - 1;
          xv[kh][kw] = (ff < 0) ? 0.f : row[kh * FFp + ff];   // ff==161 reads zero pad
        }
#pragma unroll
      for (int kh = 0; kh < 3; kh++)
#pragma unroll
        for (int kw = 0; kw < 3; kw++) {
          acc0 += xv[kh][kw] * w[((ci * 2 + 0) * 3 + (2 - kh)) * 3 + (2 - kw)];
          acc1 += xv[kh][kw] * w[((ci * 2 + 1) * 3 + (2 - kh)) * 3 + (2 - kw)];
        }
    }
    out[((size_t)(b * 2 + 0) * TT + t) * OF + f] = acc0;
    out[((size_t)(b * 2 + 1) * TT + t) * OF + f] = acc1;
  }
}

// ---------------- host launch ----------------
extern "C" void kernel_launch(void* const* d_in, const int* in_sizes, int n_in,
                              void* d_out, int out_size, void* d_ws, size_t ws_size,
                              hipStream_t stream) {
  const float* x            = (const float*)d_in[0];
  const float* conv_w       = (const float*)d_in[1];
  const float* conv_b       = (const float*)d_in[2];
  const float* gn_g         = (const float*)d_in[3];
  const float* gn_b         = (const float*)d_in[4];
  const float* intra_norm_g = (const float*)d_in[5];
  const float* intra_norm_b = (const float*)d_in[6];
  const float* intra_wih    = (const float*)d_in[7];
  const float* intra_whh    = (const float*)d_in[8];
  const float* intra_bih    = (const float*)d_in[9];
  const float* intra_bhh    = (const float*)d_in[10];
  const float* intra_lin_w  = (const float*)d_in[11];
  const float* intra_lin_b  = (const float*)d_in[12];
  const float* inter_norm_g = (const float*)d_in[13];
  const float* inter_norm_b = (const float*)d_in[14];
  const float* inter_wih    = (const float*)d_in[15];
  const float* inter_whh    = (const float*)d_in[16];
  const float* inter_bih    = (const float*)d_in[17];
  const float* inter_bhh    = (const float*)d_in[18];
  const float* inter_lin_w  = (const float*)d_in[19];
  const float* inter_lin_b  = (const float*)d_in[20];
  const float* q_w    = (const float*)d_in[21];
  const float* q_b    = (const float*)d_in[22];
  const float* q_a    = (const float*)d_in[23];
  const float* q_g    = (const float*)d_in[24];
  const float* q_beta = (const float*)d_in[25];
  const float* k_w    = (const float*)d_in[26];
  const float* k_b    = (const float*)d_in[27];
  const float* k_a    = (const float*)d_in[28];
  const float* k_g    = (const float*)d_in[29];
  const float* k_beta = (const float*)d_in[30];
  const float* v_w    = (const float*)d_in[31];
  const float* v_b    = (const float*)d_in[32];
  const float* v_a    = (const float*)d_in[33];
  const float* v_g    = (const float*)d_in[34];
  const float* v_beta = (const float*)d_in[35];
  const float* proj_w    = (const float*)d_in[36];
  const float* proj_b    = (const float*)d_in[37];
  const float* proj_a    = (const float*)d_in[38];
  const float* proj_g    = (const float*)d_in[39];
  const float* proj_beta = (const float*)d_in[40];
  const float* deconv_w  = (const float*)d_in[41];
  const float* deconv_b  = (const float*)d_in[42];

  // workspace: 256 B fp32 stats + bf16 arena of 129,153,024 elems = 246.3 MiB total.
  // Liveness-based aliasing:
  //   A act(21.676M)  B tmp(21.676M)  C hbuf(43.352M)  D res(21.676M)  E interc(20.773M)
  //   conv-out->E, qbuf->A, kbuf->B, vbuf->D, obuf->C (all dead at point of reuse)
  //   LSTM weight blobs overlay dead regions: intra blob -> D (dead until fold0),
  //   inter blob -> E (dead until fold1). Zero extra workspace.
  float* stats = (float*)d_ws;
  bf16* arena  = (bf16*)((char*)d_ws + 256);
  bf16* act    = arena;                  // A
  bf16* tmp    = arena + 21676032;       // B
  bf16* hbuf   = arena + 43352064;       // C
  bf16* res    = arena + 86704128;       // D
  bf16* interc = arena + 108380160;      // E  (end: 129,153,024)
  bf16* convout = interc;
  bf16* qbuf = act;
  bf16* kbuf = tmp;
  bf16* vbuf = res;
  bf16* obuf = hbuf;
  bf16* blob_intra = res;                // 2 x 524,288 bf16 = 2 MiB, dead until fold0
  bf16* blob_inter = interc;             // 524,288 bf16 = 1 MiB, dead until fold1

  hipMemsetAsync(stats, 0, 64 * sizeof(float), stream);
  conv_in_k<<<4032, 192, 0, stream>>>(x, conv_w, conv_b, convout);
  gn_reduce_k<<<512, 256, 0, stream>>>(convout, stats);
  gn_apply_k<<<84672, 256, 0, stream>>>(convout, stats, gn_g, gn_b, act);

  for (int l = 0; l < 4; l++) {
    lstm_prep_k<<<dim3(256, 2), 256, 0, stream>>>(
        intra_wih + (size_t)l * 524288, intra_whh + (size_t)l * 524288, blob_intra);
    ln_unfold_k<<<4032, 256, 0, stream>>>(act, intra_norm_g + l * 32, intra_norm_b + l * 32, tmp, 0);
    lstm_mfma_k<<<dim3(252, 2), 512, 65536, stream>>>(
        tmp, blob_intra, intra_bih + l * 2048, intra_bhh + l * 2048, hbuf, N1, LFi, 512, 1);
    fold_gemm_k<<<dim3(4, 1323), 256, 0, stream>>>(
        hbuf, intra_lin_w + (size_t)l * 131072, intra_lin_b + l * 32, act, res, 512, 0);
    lstm_prep_k<<<dim3(256, 1), 256, 0, stream>>>(
        inter_wih + (size_t)l * 262144, inter_whh + (size_t)l * 262144, blob_inter);
    ln_unfold_k<<<4032, 256, 0, stream>>>(res, inter_norm_g + l * 32, inter_norm_b + l * 32, tmp, 1);
    lstm_mfma_k<<<dim3(84, 1), 512, 65536, stream>>>(
        tmp, blob_inter, inter_bih + l * 1024, inter_bhh + l * 1024, hbuf, N2, LTi, 256, 0);
    fold_gemm_k<<<dim3(4, 1323), 256, 0, stream>>>(
        hbuf, inter_lin_w + (size_t)l * 65536, inter_lin_b + l * 32, res, interc, 256, 1);
    qkv_k<<<dim3(4032, 4), 256, 0, stream>>>(interc,
        q_w + l * 512, q_b + l * 16, q_a + l * 4, q_g + l * 2576, q_beta + l * 2576,
        k_w + l * 512, k_b + l * 16, k_a + l * 4, k_g + l * 2576, k_beta + l * 2576,
        v_w + l * 1024, v_b + l * 32, v_a + l * 4, v_g + l * 5152, v_beta + l * 5152,
        qbuf, kbuf, vbuf);
    attn_k<<<dim3(504, 32), 256, 0, stream>>>(qbuf, kbuf, vbuf, obuf);
    proj_k<<<4032, 256, 0, stream>>>(obuf, proj_w + l * 1024, proj_b + l * 32, proj_a + l,
                                     proj_g + l * 5152, proj_beta + l * 5152, interc, act);
  }
  deconv_k<<<4032, 256, 0, stream>>>(act, deconv_w, deconv_b, (float*)d_out);
}

// Round 10
// 16474.785 us; speedup vs baseline: 3.5740x; 1.0021x over previous
//
#include <hip/hip_runtime.h>
#include <hip/hip_bf16.h>
#include <math.h>

// ---------------- problem constants ----------------
#define BB   8
#define CH   32
#define TT   504
#define FFp  168      // padded F
#define OF   161      // original F
#define KSZ  8
#define HID  256
#define NG   1024     // 4*H
#define NHh  4
#define EE   4
#define CVv  8
#define N1   4032     // B*T  (intra seqs)
#define N2   1344     // B*Fp (inter seqs)
#define LFi  21       // F/KS
#define LTi  63       // T/KS
#define EPSf 1e-5f

#define AS1 __attribute__((address_space(1)))
#define AS3 __attribute__((address_space(3)))

typedef __hip_bfloat16 bf16;
typedef __attribute__((ext_vector_type(8))) short s16x8;
typedef __attribute__((ext_vector_type(4))) float f32x4;

__device__ __forceinline__ float b2f(bf16 v) { return __bfloat162float(v); }
__device__ __forceinline__ bf16 f2b(float v) { return __float2bfloat16(v); }
__device__ __forceinline__ float us2f(unsigned short u) {
  return __uint_as_float(((unsigned)u) << 16);
}
__device__ __forceinline__ unsigned short f2bu(float v) {   // RNE bf16 bits
  unsigned u = __float_as_uint(v);
  unsigned r = u + 0x7fffu + ((u >> 16) & 1u);
  return (unsigned short)(r >> 16);
}

__device__ __forceinline__ float sigm(float x) { return 1.f / (1.f + __expf(-x)); }
__device__ __forceinline__ float tanh_f(float x) {
  x = fminf(15.f, fmaxf(-15.f, x));
  float e = __expf(2.f * x);
  return (e - 1.f) / (e + 1.f);
}

// block = 256 threads (4 waves). red must be float[8] shared.
__device__ __forceinline__ void block_reduce2(float& s1, float& s2, float* red) {
#pragma unroll
  for (int off = 32; off > 0; off >>= 1) {
    s1 += __shfl_down(s1, off, 64);
    s2 += __shfl_down(s2, off, 64);
  }
  int lane = threadIdx.x & 63, wv = threadIdx.x >> 6;
  __syncthreads();
  if (lane == 0) { red[wv * 2] = s1; red[wv * 2 + 1] = s2; }
  __syncthreads();
  s1 = red[0] + red[2] + red[4] + red[6];
  s2 = red[1] + red[3] + red[5] + red[7];
}

// ---------------- K1: input conv 2->32, 3x3, pad 1 (LDS-tiled) ----------------
__global__ __launch_bounds__(192) void conv_in_k(const float* __restrict__ x,
                                                 const float* __restrict__ w,
                                                 const float* __restrict__ bias,
                                                 bf16* __restrict__ out) {
  __shared__ float xs[2 * 3 * (OF + 3)];
  int bt = blockIdx.x;
  int b = bt / TT, t = bt % TT;
  int tid = threadIdx.x;
  for (int i = tid; i < 2 * 3 * (OF + 3); i += 192) {
    int ci = i / (3 * (OF + 3));
    int rem = i % (3 * (OF + 3));
    int rr = rem / (OF + 3);
    int f = rem % (OF + 3);
    int ts = t + rr - 1;
    float v = 0.f;
    if (ts >= 0 && ts < TT && f < OF) v = x[((size_t)(b * 2 + ci) * TT + ts) * OF + f];
    xs[i] = v;
  }
  __syncthreads();
  int f = tid;
  if (f < OF) {
    float xv[2][3][3];
#pragma unroll
    for (int ci = 0; ci < 2; ci++)
#pragma unroll
      for (int kh = 0; kh < 3; kh++)
#pragma unroll
        for (int kw = 0; kw < 3; kw++) {
          int ff = f + kw - 1;
          xv[ci][kh][kw] = (ff < 0) ? 0.f : xs[(ci * 3 + kh) * (OF + 3) + ff];
        }
    for (int co = 0; co < CH; co++) {
      float acc = bias[co];
#pragma unroll
      for (int ci = 0; ci < 2; ci++)
#pragma unroll
        for (int kh = 0; kh < 3; kh++)
#pragma unroll
          for (int kw = 0; kw < 3; kw++)
            acc += xv[ci][kh][kw] * w[((co * 2 + ci) * 3 + kh) * 3 + kw];
      out[((size_t)(b * CH + co) * TT + t) * OF + f] = f2b(acc);
    }
  }
}

// ---------------- K2/K3: global per-batch norm ----------------
__global__ __launch_bounds__(256) void gn_reduce_k(const bf16* __restrict__ xin,
                                                   float* __restrict__ stats) {
  const int M = CH * TT * OF;   // 2,596,608
  int b = blockIdx.x >> 6;
  int part = blockIdx.x & 63;
  const bf16* p = xin + (size_t)b * M;
  float s1 = 0.f, s2 = 0.f;
  for (int i = part * 256 + threadIdx.x; i < M; i += 64 * 256) {
    float v = b2f(p[i]);
    s1 += v; s2 += v * v;
  }
  __shared__ float red[8];
  block_reduce2(s1, s2, red);
  if (threadIdx.x == 0) {
    atomicAdd(&stats[b * 2], s1);
    atomicAdd(&stats[b * 2 + 1], s2);
  }
}

__global__ __launch_bounds__(256) void gn_apply_k(const bf16* __restrict__ xin,
                                                  const float* __restrict__ stats,
                                                  const float* __restrict__ g,
                                                  const float* __restrict__ bb,
                                                  bf16* __restrict__ act) {
  int gid = blockIdx.x * 256 + threadIdx.x;       // B*CH*TT*FFp = 21,676,032 exact
  int f = gid % FFp;
  int t = (gid / FFp) % TT;
  int c = (gid / (FFp * TT)) % CH;
  int b = gid / (FFp * TT * CH);
  float v = 0.f;
  if (f < OF) {
    const float M = (float)(CH * TT * OF);
    float mu = stats[b * 2] / M;
    float var = stats[b * 2 + 1] / M - mu * mu;
    float xv = b2f(xin[((size_t)(b * CH + c) * TT + t) * OF + f]);
    v = (xv - mu) * rsqrtf(var + EPSf) * g[c] + bb[c];   // NOTE: no outer +eps here
  }
  act[gid] = f2b(v);
}

// ---------------- K4a: intra ln + unfold, coalesced 16-B record writes ----------------
// out[(f/8)*N1 + bt][c*8 + f%8]; per (group g, channel c) the 8 values (k=f%8) form one
// 16-B record -> one uint4 store; consecutive c -> contiguous 512 B per group.
__global__ __launch_bounds__(256) void ln_unfold_k(const bf16* __restrict__ xin,
                                                   const float* __restrict__ g,
                                                   const float* __restrict__ bb,
                                                   bf16* __restrict__ out) {
  __shared__ float sm[CH * FFp];
  __shared__ float mu_s[FFp], rs_s[FFp];
  __shared__ float gg[CH], bv[CH];
  int bt = blockIdx.x;
  int b = bt / TT, t = bt % TT;
  int tid = threadIdx.x;
  if (tid < CH) { gg[tid] = g[tid]; bv[tid] = bb[tid]; }
  const bf16* base = xin + ((size_t)b * CH * TT + t) * FFp;
  for (int idx = tid; idx < CH * FFp; idx += 256) {
    int c = idx / FFp, f = idx % FFp;
    sm[idx] = b2f(base[(size_t)c * TT * FFp + f]);
  }
  __syncthreads();
  if (tid < FFp) {
    int f = tid;
    float s1 = 0.f, s2 = 0.f;
#pragma unroll
    for (int c = 0; c < CH; c++) { float v = sm[c * FFp + f]; s1 += v; s2 += v * v; }
    float mu = s1 / CH;
    float var = s2 / CH - mu * mu;
    mu_s[f] = mu;
    rs_s[f] = 1.f / (sqrtf(var + EPSf) + EPSf);
  }
  __syncthreads();
  unsigned short* outu = (unsigned short*)out;
  for (int ch = tid; ch < LFi * CH; ch += 256) {     // 672 records
    int gI = ch >> 5, c = ch & 31;
    float gc = gg[c], bc = bv[c];
    unsigned short o8[8];
#pragma unroll
    for (int k = 0; k < 8; k++) {
      int f = gI * 8 + k;
      float v = (sm[c * FFp + f] - mu_s[f]) * rs_s[f] * gc + bc;
      o8[k] = f2bu(v);
    }
    *(uint4*)(outu + ((size_t)gI * N1 + bt) * 256 + c * 8) = *(uint4*)o8;
  }
}

// ---------------- K4b: inter ln + unfold, 8-t blocks, coalesced writes ----------------
// out[(t/8)*N2 + b*FFp+f][c*8 + t%8]; block owns (b, tg) covering t = tg*8..tg*8+7 so
// each (f, c) record [c*8 + 0..7] is complete -> one 16-B store; per f: 512 B contiguous.
__global__ __launch_bounds__(256) void ln_unfold8_k(const bf16* __restrict__ xin,
                                                    const float* __restrict__ g,
                                                    const float* __restrict__ bb,
                                                    bf16* __restrict__ out) {
  __shared__ short smb[8 * CH * FFp];              // 86016 B, [t8*32+c][f]
  __shared__ float mu_s[8 * FFp], rs_s[8 * FFp];   // 10752 B
  __shared__ float gg[CH], bv[CH];
  int tg = blockIdx.x, b = blockIdx.y;
  int tid = threadIdx.x;
  if (tid < CH) { gg[tid] = g[tid]; bv[tid] = bb[tid]; }
  const short* src = (const short*)xin;
  for (int idx = tid; idx < 8 * CH * (FFp / 8); idx += 256) {   // 5376 chunks of 8
    int t8 = idx / (CH * 21);
    int rem = idx % (CH * 21);
    int c = rem / 21, fc = rem % 21;
    s16x8 v = *(const s16x8*)(src + ((size_t)(b * CH + c) * TT + tg * 8 + t8) * FFp + fc * 8);
    *(s16x8*)(&smb[(t8 * CH + c) * FFp + fc * 8]) = v;
  }
  __syncthreads();
  for (int p = tid; p < 8 * FFp; p += 256) {       // 1344 (t8,f) pairs
    int t8 = p / FFp, f = p % FFp;
    float s1 = 0.f, s2 = 0.f;
#pragma unroll
    for (int c = 0; c < CH; c++) {
      float v = us2f((unsigned short)smb[(t8 * CH + c) * FFp + f]);
      s1 += v; s2 += v * v;
    }
    float mu = s1 / CH;
    float var = s2 / CH - mu * mu;
    mu_s[p] = mu;
    rs_s[p] = 1.f / (sqrtf(var + EPSf) + EPSf);
  }
  __syncthreads();
  unsigned short* outu = (unsigned short*)out;
  for (int ch = tid; ch < FFp * CH; ch += 256) {   // 5376 records
    int f = ch >> 5, c = ch & 31;
    float gc = gg[c], bc = bv[c];
    unsigned short o8[8];
#pragma unroll
    for (int k = 0; k < 8; k++) {
      float v = us2f((unsigned short)smb[(k * CH + c) * FFp + f]);
      v = (v - mu_s[k * FFp + f]) * rs_s[k * FFp + f] * gc + bc;
      o8[k] = f2bu(v);
    }
    *(uint4*)(outu + ((size_t)tg * N2 + b * FFp + f) * 256 + c * 8) = *(uint4*)o8;
  }
}

// ---------------- K5a: weight prep — reorder W=[wih|whh] into B-fragment blob ---------
// blob[nt(64)][ks(16)][lane(64)][j(8)], value = Wcat[n][k]:
//   n = nt*16 + (lane&15), k = ks*32 + (lane>>4)*8 + j
//   Wcat[n][k] = k<256 ? wih[n][k] : whh[n][k-256]
__global__ __launch_bounds__(256) void lstm_prep_k(const float* __restrict__ wih0,
                                                   const float* __restrict__ whh0,
                                                   bf16* __restrict__ blob0) {
  int dir = blockIdx.y;
  const float* wih = wih0 + (size_t)dir * 262144;
  const float* whh = whh0 + (size_t)dir * 262144;
  unsigned short* blob = (unsigned short*)(blob0 + (size_t)dir * 524288);
  int gid = blockIdx.x * 256 + threadIdx.x;     // 0..65535
  int lane = gid & 63;
  int ks = (gid >> 6) & 15;
  int nt = gid >> 10;
  int n = nt * 16 + (lane & 15);
  int kb = ks * 32 + (lane >> 4) * 8;
  unsigned short o8[8];
#pragma unroll
  for (int j = 0; j < 8; j++) {
    int k = kb + j;
    float v = (k < 256) ? wih[n * 256 + k] : whh[n * 256 + (k - 256)];
    o8[j] = f2bu(v);
  }
  *(uint4*)(blob + (size_t)gid * 8) = *(uint4*)o8;
}

// ---------------- K5b: MFMA LSTM, 512 threads, async DMA B-stream, race-free bufs -----
// R9 post-mortem: absmax drift traced to 2-buffer rotation — chunk c+2's DMA targets
// the buffer being read at chunk c ((c+2)&1 == c&1). Fix: 4 rotating buffers with
// 2-frag chunks (64 chunks/step) and issue distance 3: (C+3)&3 differs from the read
// buffer AND both in-flight buffers at every iteration -> no write-over-read ordering
// possible regardless of compiler scheduling. Same LDS footprint as R9 (80 KiB total,
// proven launch size), same MFMA order -> bit-identical math.
__global__ __launch_bounds__(512) void lstm_mfma_k(const bf16* __restrict__ xz,
                                                   const bf16* __restrict__ blob0,
                                                   const float* __restrict__ bih0,
                                                   const float* __restrict__ bhh0,
                                                   bf16* __restrict__ hout,
                                                   int N, int Ls, int hstride, int bidir) {
  __shared__ __attribute__((aligned(16))) short afr[16 * 64 * 8];  // 16 KiB; slot=ks*64+kg*16+m
  extern __shared__ __attribute__((aligned(16))) short bstage[];   // 64 KiB: [w][buf4][frag2][lane][8]
  int tid = threadIdx.x;
  int w = tid >> 6, lane = tid & 63;
  int l15 = lane & 15, lq = lane >> 4;
  int dir = blockIdx.y;
  const short* blob = (const short*)(blob0 + (size_t)dir * 524288);
  const float* bih = bih0 + dir * NG;
  const float* bhh = bhh0 + dir * NG;
  int hoff = dir * 256;
  int n0 = blockIdx.x * 16;
  unsigned short* houtu = (unsigned short*)hout;
  const short* xzs = (const short*)xz;
  short* bst_w = bstage + w * 4096;      // per-wave 8 KiB: 4 bufs x 2 frags x 512 shorts

  float bias[4][2];
#pragma unroll
  for (int q = 0; q < 4; q++)
#pragma unroll
    for (int j = 0; j < 2; j++) {
      int n = q * 256 + (2 * w + j) * 16 + l15;
      bias[q][j] = bih[n] + bhh[n];
    }
  for (int i = tid; i < 8 * 64 * 8; i += 512) afr[8 * 64 * 8 + i] = 0;   // h frags = 0
  float cst[8];
#pragma unroll
  for (int i = 0; i < 8; i++) cst[i] = 0.f;

// chunk C in [0,64): c32=C>>1, h2=C&1; a=c32>>3 (ks quad), r=c32&7 -> q=r>>1, j=r&1,
// nt=q*16+2w+j; frags ks = a*4 + h2*2 + {0,1}. Buffer C&3.
#define BQ_ISSUE(C)                                                              \
  {                                                                              \
    int c32_ = (C) >> 1, h2_ = (C) & 1;                                          \
    int a_ = c32_ >> 3, r_ = c32_ & 7;                                           \
    int nt_ = (r_ >> 1) * 16 + 2 * w + (r_ & 1);                                 \
    const short* gb_ = blob + (size_t)nt_ * 8192 + (a_ * 4 + h2_ * 2) * 512 + lane * 8; \
    short* lb_ = bst_w + ((C) & 3) * 1024;                                       \
    _Pragma("unroll")                                                            \
    for (int k_ = 0; k_ < 2; k_++)                                               \
      __builtin_amdgcn_global_load_lds((const AS1 void*)(gb_ + k_ * 512),        \
                                       (AS3 void*)(lb_ + k_ * 512), 16, 0, 0);   \
  }

  for (int st = 0; st < Ls; st++) {
    int t = (bidir && dir) ? (Ls - 1 - st) : st;
    // stage x_t via DMA: wave w fills afr slots w*64+lane (lane-contiguous, 16 B each)
    {
      const short* gx = xzs + ((size_t)t * N + n0 + (lane & 15)) * 256 + (w * 4 + (lane >> 4)) * 8;
      __builtin_amdgcn_global_load_lds((const AS1 void*)gx, (AS3 void*)(afr + w * 512), 16, 0, 0);
    }
    BQ_ISSUE(0);
    BQ_ISSUE(1);
    BQ_ISSUE(2);
    __syncthreads();   // BARRIER-A: drains all DMA (x + chunks 0..2 resident), h visible

    f32x4 acc[4][2];
#pragma unroll
    for (int q = 0; q < 4; q++)
#pragma unroll
      for (int j = 0; j < 2; j++)
        acc[q][j] = (f32x4){bias[q][j], bias[q][j], bias[q][j], bias[q][j]};

    s16x8 af[4];
#pragma unroll
    for (int C = 0; C < 64; C++) {
      int c32 = C >> 1, h2 = C & 1;
      int a = c32 >> 3, r = c32 & 7;
      int q = r >> 1, j = r & 1;
      if (r == 0 && h2 == 0) {
#pragma unroll
        for (int k = 0; k < 4; k++)
          af[k] = *(const s16x8*)(&afr[((a * 4 + k) * 64 + lane) * 8]);
      }
      __builtin_amdgcn_s_waitcnt(0x0F74);   // vmcnt(4): chunk C resident, C+1/C+2 in flight
      const short* lb = bst_w + (C & 3) * 1024;
#pragma unroll
      for (int k = 0; k < 2; k++) {
        s16x8 bf = *(const s16x8*)(lb + k * 512 + lane * 8);
        acc[q][j] = __builtin_amdgcn_mfma_f32_16x16x32_bf16(af[h2 * 2 + k], bf, acc[q][j], 0, 0, 0);
      }
      if (C < 61) BQ_ISSUE(C + 3);
    }
    __syncthreads();   // BARRIER-B: all afr reads done before h overwrite

    // epilogue: gates -> (h, c); h to global + h-frag LDS
#pragma unroll
    for (int j = 0; j < 2; j++) {
      int d = (2 * w + j) * 16 + l15;
      int slot = (8 + (d >> 5)) * 64 + ((d >> 3) & 3) * 16;
#pragma unroll
      for (int r = 0; r < 4; r++) {
        int m = lq * 4 + r;
        float iv = sigm(acc[0][j][r]);
        float fv = sigm(acc[1][j][r]);
        float gv = tanh_f(acc[2][j][r]);
        float ov = sigm(acc[3][j][r]);
        float c = fv * cst[j * 4 + r] + iv * gv;
        cst[j * 4 + r] = c;
        float h = ov * tanh_f(c);
        unsigned short hb = f2bu(h);
        houtu[((size_t)t * N + n0 + m) * hstride + hoff + d] = hb;
        afr[(slot + m) * 8 + (d & 7)] = (short)hb;
      }
    }
  }
#undef BQ_ISSUE
}

// ---------------- K6: fold GEMM (M=84672, N=256) + bias + residual, scatter epilogue ---
__global__ __launch_bounds__(256) void fold_gemm_k(const bf16* __restrict__ A,
                                                   const float* __restrict__ Bw,
                                                   const float* __restrict__ linb,
                                                   const bf16* __restrict__ resid,
                                                   bf16* __restrict__ outp,
                                                   int K, int mode) {
  __shared__ float As[16 * 68];
  __shared__ float Bs[16 * 64];
  int tid = threadIdx.x;
  int n0 = blockIdx.x * 64;
  int m0 = blockIdx.y * 64;
  int tr = tid >> 4, tc = tid & 15;
  float acc[4][4] = {};
  int arow = tid >> 2, akg = (tid & 3) * 4;
  int bkk = tid >> 4, bc4 = (tid & 15) * 4;
  for (int k0 = 0; k0 < K; k0 += 16) {
    ushort4 avu = *(const ushort4*)((const unsigned short*)A + (size_t)(m0 + arow) * K + k0 + akg);
    float4 bv = *(const float4*)(Bw + (size_t)(k0 + bkk) * 256 + n0 + bc4);
    __syncthreads();
    As[(akg + 0) * 68 + arow] = us2f(avu.x);
    As[(akg + 1) * 68 + arow] = us2f(avu.y);
    As[(akg + 2) * 68 + arow] = us2f(avu.z);
    As[(akg + 3) * 68 + arow] = us2f(avu.w);
    *(float4*)(&Bs[bkk * 64 + bc4]) = bv;
    __syncthreads();
#pragma unroll
    for (int kk = 0; kk < 16; kk++) {
      float4 a4 = *(const float4*)(&As[kk * 68 + tr * 4]);
      float4 b4 = *(const float4*)(&Bs[kk * 64 + tc * 4]);
      float aa[4] = {a4.x, a4.y, a4.z, a4.w};
      float bb_[4] = {b4.x, b4.y, b4.z, b4.w};
#pragma unroll
      for (int i = 0; i < 4; i++)
#pragma unroll
        for (int j = 0; j < 4; j++) acc[i][j] += aa[i] * bb_[j];
    }
  }
#pragma unroll
  for (int i = 0; i < 4; i++) {
    int r = m0 + tr * 4 + i;
#pragma unroll
    for (int j = 0; j < 4; j++) {
      int col = n0 + tc * 4 + j;
      int c = col >> 3, kp = col & 7;
      float v = acc[i][j] + linb[c];
      if (mode == 0) {
        int l = r / N1, n = r % N1;
        int b = n / TT, t = n % TT;
        size_t o = ((size_t)(b * CH + c) * TT + t) * FFp + (l * 8 + kp);
        outp[o] = f2b(v + b2f(resid[o]));
      } else {
        int l = r / N2, n = r % N2;
        int b = n / FFp, fq = n % FFp;
        int t = l * 8 + kp;
        if (fq < OF) {
          size_t o = ((size_t)(b * CH + c) * TT + t) * OF + fq;
          size_t ri = ((size_t)(b * CH + c) * TT + t) * FFp + fq;
          outp[o] = f2b(v + b2f(resid[ri]));
        }
      }
    }
  }
}

// ---------------- K8: fused QKV projection + prelu + ln_cf_head ----------------
__global__ __launch_bounds__(256) void qkv_k(const bf16* __restrict__ interc,
    const float* __restrict__ qw, const float* __restrict__ qb, const float* __restrict__ qa,
    const float* __restrict__ qg, const float* __restrict__ qbeta,
    const float* __restrict__ kw, const float* __restrict__ kb, const float* __restrict__ ka,
    const float* __restrict__ kg, const float* __restrict__ kbeta,
    const float* __restrict__ vw, const float* __restrict__ vb, const float* __restrict__ va,
    const float* __restrict__ vg, const float* __restrict__ vbeta,
    bf16* __restrict__ qo, bf16* __restrict__ ko, bf16* __restrict__ vo) {
  __shared__ float sm[CH * OF];     // 5152
  __shared__ float wb[16 * 32];
  __shared__ float wbias[16];
  __shared__ float yb[16 * OF];     // 2576: [0:4) Q-e, [4:8) K-e, [8:16) V-cv
  __shared__ float red[8];
  int bt = blockIdx.x, h = blockIdx.y;
  int b = bt / TT, t = bt % TT;
  int tid = threadIdx.x;
  const bf16* src = interc + ((size_t)b * CH * TT + t) * OF;
  for (int idx = tid; idx < CH * OF; idx += 256) {
    int c = idx / OF, f = idx % OF;
    sm[idx] = b2f(src[(size_t)c * TT * OF + f]);
  }
  for (int idx = tid; idx < 512; idx += 256) {
    int e = idx >> 5, c = idx & 31;
    float w;
    if (e < 4) w = qw[(h * 4 + e) * 32 + c];
    else if (e < 8) w = kw[(h * 4 + e - 4) * 32 + c];
    else w = vw[(h * 8 + e - 8) * 32 + c];
    wb[idx] = w;
  }
  if (tid < 16) {
    float bv;
    if (tid < 4) bv = qb[h * 4 + tid];
    else if (tid < 8) bv = kb[h * 4 + tid - 4];
    else bv = vb[h * 8 + tid - 8];
    wbias[tid] = bv;
  }
  __syncthreads();
  float aQ = qa[h], aK = ka[h], aV = va[h];
  for (int idx = tid; idx < 16 * OF; idx += 256) {
    int e = idx / OF, f = idx % OF;
    float accv = wbias[e];
#pragma unroll
    for (int c = 0; c < 32; c++) accv += sm[c * OF + f] * wb[e * 32 + c];
    float a = e < 4 ? aQ : (e < 8 ? aK : aV);
    yb[idx] = accv >= 0.f ? accv : a * accv;
  }
  __syncthreads();
  for (int seg = 0; seg < 3; seg++) {
    int s0 = (seg == 0) ? 0 : ((seg == 1) ? 644 : 1288);
    int len = (seg == 2) ? 1288 : 644;
    float s1 = 0.f, s2 = 0.f;
    for (int i = tid; i < len; i += 256) { float v = yb[s0 + i]; s1 += v; s2 += v * v; }
    block_reduce2(s1, s2, red);
    float mu = s1 / len;
    float var = s2 / len - mu * mu;
    float rs = 1.f / (sqrtf(var + EPSf) + EPSf);
    const float* gp; const float* bp; bf16* op; int nch;
    if (seg == 0) { gp = qg; bp = qbeta; op = qo; nch = 4; }
    else if (seg == 1) { gp = kg; bp = kbeta; op = ko; nch = 4; }
    else { gp = vg; bp = vbeta; op = vo; nch = 8; }
    for (int i = tid; i < len; i += 256) {
      int e = i / OF, f = i % OF;
      float v = (yb[s0 + i] - mu) * rs * gp[(h * nch + e) * OF + f] + bp[(h * nch + e) * OF + f];
      op[(((size_t)(h * BB + b) * nch + e) * TT + t) * OF + f] = f2b(v);
    }
  }
}

// ---------------- K9: banded causal attention (lookback 5) ----------------
__global__ __launch_bounds__(256) void attn_k(const bf16* __restrict__ Q,
                                              const bf16* __restrict__ Kt,
                                              const bf16* __restrict__ V,
                                              bf16* __restrict__ O) {
  int t = blockIdx.x;
  int hb = blockIdx.y;            // h*8 + b
  int h = hb >> 3, b = hb & 7;
  int tid = threadIdx.x;
  int nv = min(t, 5) + 1;
  const float scale = 0.0394055201f;   // 1/sqrt(644)
  __shared__ float redl[24];
  float part[6] = {0, 0, 0, 0, 0, 0};
  size_t qkbase = ((size_t)(h * BB + b) * EE) * TT * OF;
  for (int i = tid; i < EE * OF; i += 256) {
    int e = i / OF, f = i % OF;
    float qv = b2f(Q[qkbase + ((size_t)e * TT + t) * OF + f]);
#pragma unroll
    for (int d = 0; d < 6; d++)
      if (d < nv) part[d] += qv * b2f(Kt[qkbase + ((size_t)e * TT + (t - d)) * OF + f]);
  }
#pragma unroll
  for (int d = 0; d < 6; d++)
#pragma unroll
    for (int off = 32; off > 0; off >>= 1) part[d] += __shfl_down(part[d], off, 64);
  int lane = tid & 63, wv = tid >> 6;
  if (lane == 0) {
#pragma unroll
    for (int d = 0; d < 6; d++) redl[wv * 6 + d] = part[d];
  }
  __syncthreads();
  float a[6], sv[6];
  float m = -1e30f;
#pragma unroll
  for (int d = 0; d < 6; d++)
    if (d < nv) {
      float s = (redl[d] + redl[6 + d] + redl[12 + d] + redl[18 + d]) * scale;
      sv[d] = s;
      m = fmaxf(m, s);
    }
  float denom = 0.f;
#pragma unroll
  for (int d = 0; d < 6; d++)
    if (d < nv) { a[d] = __expf(sv[d] - m); denom += a[d]; }
  float inv = 1.f / denom;
  size_t vbase = ((size_t)(h * BB + b) * CVv) * TT * OF;
  for (int i = tid; i < CVv * OF; i += 256) {
    int cv = i / OF, f = i % OF;
    float o = 0.f;
#pragma unroll
    for (int d = 0; d < 6; d++)
      if (d < nv) o += a[d] * b2f(V[vbase + ((size_t)cv * TT + (t - d)) * OF + f]);
    O[(((size_t)b * CH + h * CVv + cv) * TT + t) * OF + f] = f2b(o * inv);
  }
}

// ---------------- K10: proj + prelu + ln_cf_proj + residual + re-pad ----------------
__global__ __launch_bounds__(256) void proj_k(const bf16* __restrict__ ob,
                                              const float* __restrict__ pw,
                                              const float* __restrict__ pb,
                                              const float* __restrict__ pa,
                                              const float* __restrict__ pg,
                                              const float* __restrict__ pbeta,
                                              const bf16* __restrict__ interc,
                                              bf16* __restrict__ act) {
  __shared__ float sm[CH * OF];
  __shared__ float wsm[CH * CH];
  __shared__ float yb[CH * OF];
  __shared__ float red[8];
  int bt = blockIdx.x;
  int b = bt / TT, t = bt % TT;
  int tid = threadIdx.x;
  const bf16* src = ob + ((size_t)b * CH * TT + t) * OF;
  for (int idx = tid; idx < CH * OF; idx += 256) {
    int c = idx / OF, f = idx % OF;
    sm[idx] = b2f(src[(size_t)c * TT * OF + f]);
  }
  for (int idx = tid; idx < CH * CH; idx += 256) wsm[idx] = pw[idx];
  __syncthreads();
  float aP = pa[0];
  for (int idx = tid; idx < CH * OF; idx += 256) {
    int d = idx / OF, f = idx % OF;
    float accv = pb[d];
#pragma unroll
    for (int c = 0; c < 32; c++) accv += sm[c * OF + f] * wsm[d * 32 + c];
    yb[idx] = accv >= 0.f ? accv : aP * accv;
  }
  __syncthreads();
  float s1 = 0.f, s2 = 0.f;
  for (int i = tid; i < CH * OF; i += 256) { float v = yb[i]; s1 += v; s2 += v * v; }
  block_reduce2(s1, s2, red);
  const float Mn = (float)(CH * OF);
  float mu = s1 / Mn;
  float var = s2 / Mn - mu * mu;
  float rs = 1.f / (sqrtf(var + EPSf) + EPSf);
  for (int idx = tid; idx < CH * FFp; idx += 256) {
    int d = idx / FFp, f = idx % FFp;
    float v = 0.f;
    if (f < OF) {
      float y = (yb[d * OF + f] - mu) * rs * pg[d * OF + f] + pbeta[d * OF + f];
      v = y + b2f(interc[((size_t)(b * CH + d) * TT + t) * OF + f]);
    }
    act[((size_t)(b * CH + d) * TT + t) * FFp + f] = f2b(v);
  }
}

// ---------------- K11: output deconv (LDS-tiled 3x3 conv over 32ch) -------------------
// NOTE: grid MUST be exactly B*TT = 4032 (block-per-(b,t)); larger grids write OOB.
__global__ __launch_bounds__(256) void deconv_k(const bf16* __restrict__ act,
                                                const float* __restrict__ w,
                                                const float* __restrict__ bias,
                                                float* __restrict__ out) {
  __shared__ float ash[CH * 3 * FFp];   // 64512 B
  int bt = blockIdx.x;
  int b = bt / TT, t = bt % TT;
  int tid = threadIdx.x;
  const short* acts = (const short*)act;
  for (int ch = tid; ch < CH * 3 * (FFp / 8); ch += 256) {   // 2016 chunks of 8
    int ci = ch / 63, rem = ch % 63;
    int rr = rem / 21, fc = rem % 21;
    int ts = t + rr - 1;
    float* dst = &ash[(ci * 3 + rr) * FFp + fc * 8];
    if (ts < 0 || ts >= TT) {
#pragma unroll
      for (int k2 = 0; k2 < 8; k2++) dst[k2] = 0.f;
    } else {
      s16x8 v = *(const s16x8*)(acts + ((size_t)(b * CH + ci) * TT + ts) * FFp + fc * 8);
#pragma unroll
      for (int k2 = 0; k2 < 8; k2++) dst[k2] = us2f((unsigned short)v[k2]);
    }
  }
  __syncthreads();
  int f = tid;
  if (f < OF) {
    float acc0 = bias[0], acc1 = bias[1];
#pragma unroll 4
    for (int ci = 0; ci < CH; ci++) {
      const float* row = &ash[ci * 3 * FFp];
      float xv[3][3];
#pragma unroll
      for (int kh = 0; kh < 3; kh++)
#pragma unroll
        for (int kw = 0; kw < 3; kw++) {
          int ff = f + kw - 1;
          xv[kh][kw] = (ff < 0) ? 0.f : row[kh * FFp + ff];   // ff==161 reads zero pad
        }
#pragma unroll
      for (int kh = 0; kh < 3; kh++)
#pragma unroll
        for (int kw = 0; kw < 3; kw++) {
          acc0 += xv[kh][kw] * w[((ci * 2 + 0) * 3 + (2 - kh)) * 3 + (2 - kw)];
          acc1 += xv[kh][kw] * w[((ci * 2 + 1) * 3 + (2 - kh)) * 3 + (2 - kw)];
        }
    }
    out[((size_t)(b * 2 + 0) * TT + t) * OF + f] = acc0;
    out[((size_t)(b * 2 + 1) * TT + t) * OF + f] = acc1;
  }
}

// ---------------- host launch ----------------
extern "C" void kernel_launch(void* const* d_in, const int* in_sizes, int n_in,
                              void* d_out, int out_size, void* d_ws, size_t ws_size,
                              hipStream_t stream) {
  const float* x            = (const float*)d_in[0];
  const float* conv_w       = (const float*)d_in[1];
  const float* conv_b       = (const float*)d_in[2];
  const float* gn_g         = (const float*)d_in[3];
  const float* gn_b         = (const float*)d_in[4];
  const float* intra_norm_g = (const float*)d_in[5];
  const float* intra_norm_b = (const float*)d_in[6];
  const float* intra_wih    = (const float*)d_in[7];
  const float* intra_whh    = (const float*)d_in[8];
  const float* intra_bih    = (const float*)d_in[9];
  const float* intra_bhh    = (const float*)d_in[10];
  const float* intra_lin_w  = (const float*)d_in[11];
  const float* intra_lin_b  = (const float*)d_in[12];
  const float* inter_norm_g = (const float*)d_in[13];
  const float* inter_norm_b = (const float*)d_in[14];
  const float* inter_wih    = (const float*)d_in[15];
  const float* inter_whh    = (const float*)d_in[16];
  const float* inter_bih    = (const float*)d_in[17];
  const float* inter_bhh    = (const float*)d_in[18];
  const float* inter_lin_w  = (const float*)d_in[19];
  const float* inter_lin_b  = (const float*)d_in[20];
  const float* q_w    = (const float*)d_in[21];
  const float* q_b    = (const float*)d_in[22];
  const float* q_a    = (const float*)d_in[23];
  const float* q_g    = (const float*)d_in[24];
  const float* q_beta = (const float*)d_in[25];
  const float* k_w    = (const float*)d_in[26];
  const float* k_b    = (const float*)d_in[27];
  const float* k_a    = (const float*)d_in[28];
  const float* k_g    = (const float*)d_in[29];
  const float* k_beta = (const float*)d_in[30];
  const float* v_w    = (const float*)d_in[31];
  const float* v_b    = (const float*)d_in[32];
  const float* v_a    = (const float*)d_in[33];
  const float* v_g    = (const float*)d_in[34];
  const float* v_beta = (const float*)d_in[35];
  const float* proj_w    = (const float*)d_in[36];
  const float* proj_b    = (const float*)d_in[37];
  const float* proj_a    = (const float*)d_in[38];
  const float* proj_g    = (const float*)d_in[39];
  const float* proj_beta = (const float*)d_in[40];
  const float* deconv_w  = (const float*)d_in[41];
  const float* deconv_b  = (const float*)d_in[42];

  // workspace: 256 B fp32 stats + bf16 arena of 129,153,024 elems = 246.3 MiB total.
  // Liveness-based aliasing:
  //   A act(21.676M)  B tmp(21.676M)  C hbuf(43.352M)  D res(21.676M)  E interc(20.773M)
  //   conv-out->E, qbuf->A, kbuf->B, vbuf->D, obuf->C (all dead at point of reuse)
  //   LSTM weight blobs overlay dead regions: intra blob -> D (dead until fold0),
  //   inter blob -> E (dead until fold1). Zero extra workspace.
  float* stats = (float*)d_ws;
  bf16* arena  = (bf16*)((char*)d_ws + 256);
  bf16* act    = arena;                  // A
  bf16* tmp    = arena + 21676032;       // B
  bf16* hbuf   = arena + 43352064;       // C
  bf16* res    = arena + 86704128;       // D
  bf16* interc = arena + 108380160;      // E  (end: 129,153,024)
  bf16* convout = interc;
  bf16* qbuf = act;
  bf16* kbuf = tmp;
  bf16* vbuf = res;
  bf16* obuf = hbuf;
  bf16* blob_intra = res;                // 2 x 524,288 bf16 = 2 MiB, dead until fold0
  bf16* blob_inter = interc;             // 524,288 bf16 = 1 MiB, dead until fold1

  hipMemsetAsync(stats, 0, 64 * sizeof(float), stream);
  conv_in_k<<<4032, 192, 0, stream>>>(x, conv_w, conv_b, convout);
  gn_reduce_k<<<512, 256, 0, stream>>>(convout, stats);
  gn_apply_k<<<84672, 256, 0, stream>>>(convout, stats, gn_g, gn_b, act);

  for (int l = 0; l < 4; l++) {
    lstm_prep_k<<<dim3(256, 2), 256, 0, stream>>>(
        intra_wih + (size_t)l * 524288, intra_whh + (size_t)l * 524288, blob_intra);
    ln_unfold_k<<<4032, 256, 0, stream>>>(act, intra_norm_g + l * 32, intra_norm_b + l * 32, tmp);
    lstm_mfma_k<<<dim3(252, 2), 512, 65536, stream>>>(
        tmp, blob_intra, intra_bih + l * 2048, intra_bhh + l * 2048, hbuf, N1, LFi, 512, 1);
    fold_gemm_k<<<dim3(4, 1323), 256, 0, stream>>>(
        hbuf, intra_lin_w + (size_t)l * 131072, intra_lin_b + l * 32, act, res, 512, 0);
    lstm_prep_k<<<dim3(256, 1), 256, 0, stream>>>(
        inter_wih + (size_t)l * 262144, inter_whh + (size_t)l * 262144, blob_inter);
    ln_unfold8_k<<<dim3(LTi, BB), 256, 0, stream>>>(res, inter_norm_g + l * 32, inter_norm_b + l * 32, tmp);
    lstm_mfma_k<<<dim3(84, 1), 512, 65536, stream>>>(
        tmp, blob_inter, inter_bih + l * 1024, inter_bhh + l * 1024, hbuf, N2, LTi, 256, 0);
    fold_gemm_k<<<dim3(4, 1323), 256, 0, stream>>>(
        hbuf, inter_lin_w + (size_t)l * 65536, inter_lin_b + l * 32, res, interc, 256, 1);
    qkv_k<<<dim3(4032, 4), 256, 0, stream>>>(interc,
        q_w + l * 512, q_b + l * 16, q_a + l * 4, q_g + l * 2576, q_beta + l * 2576,
        k_w + l * 512, k_b + l * 16, k_a + l * 4, k_g + l * 2576, k_beta + l * 2576,
        v_w + l * 1024, v_b + l * 32, v_a + l * 4, v_g + l * 5152, v_beta + l * 5152,
        qbuf, kbuf, vbuf);
    attn_k<<<dim3(504, 32), 256, 0, stream>>>(qbuf, kbuf, vbuf, obuf);
    proj_k<<<4032, 256, 0, stream>>>(obuf, proj_w + l * 1024, proj_b + l * 32, proj_a + l,
                                     proj_g + l * 5152, proj_beta + l * 5152, interc, act);
  }
  deconv_k<<<4032, 256, 0, stream>>>(act, deconv_w, deconv_b, (float*)d_out);
}